// Round 7
// baseline (620.953 us; speedup 1.0000x reference)
//
#include <hip/hip_runtime.h>
#include <math.h>

typedef float f32x4 __attribute__((ext_vector_type(4)));
typedef short s16x8 __attribute__((ext_vector_type(8)));
typedef unsigned short u16;
typedef unsigned int u32;

#define MFMA16(a,b,c) __builtin_amdgcn_mfma_f32_16x16x32_bf16((a),(b),(c),0,0,0)
#define AS1 __attribute__((address_space(1)))
#define AS3 __attribute__((address_space(3)))

__device__ __forceinline__ void dma16(const u16* g, u16* l){
  __builtin_amdgcn_global_load_lds((const AS1 u32*)g, (AS3 u32*)l, 16, 0, 0);
}

__device__ __forceinline__ float bf2f(u16 u){
  union { unsigned int i; float f; } v; v.i = ((unsigned int)u)<<16; return v.f;
}
__device__ __forceinline__ u16 f2bf(float f){
  union { float f; unsigned int i; } v; v.f = f;
  unsigned int x = v.i;
  return (u16)((x + 0x7fffu + ((x>>16)&1u))>>16);
}

enum { EPI_QKV=0, EPI_BIAS_GELU=3 };

// ---------------------------------------------------------------------------
// kgemm2: BM=128, BN=128, BK=32, 4x4 frags/wave; DMA staging + swizzle.
// ---------------------------------------------------------------------------
template<int EPI>
__global__ __launch_bounds__(256)
void kgemm2(const u16* __restrict__ A, const u16* __restrict__ BT, int K, int lda, int ldb,
            const float* __restrict__ bias, u16* __restrict__ outb, int ldc,
            u16* __restrict__ qo, u16* __restrict__ ko, u16* __restrict__ vo,
            u16* __restrict__ qlm, u16* __restrict__ klm)
{
  __shared__ __align__(16) u16 As[128*32];
  __shared__ __align__(16) u16 Bs[128*32];
  const int tid = threadIdx.x;
  const int w = tid>>6, wy = w>>1, wx = w&1, l = tid&63, q = l>>4, ln = l&15;
  const int m0 = blockIdx.x*128, n0 = blockIdx.y*128;
  const int lrow = l>>2, lch = l&3;

  f32x4 acc[4][4];
  #pragma unroll
  for (int i=0;i<4;i++)
    #pragma unroll
    for (int j=0;j<4;j++){ acc[i][j][0]=0.f; acc[i][j][1]=0.f; acc[i][j][2]=0.f; acc[i][j][3]=0.f; }

  for (int k0=0; k0<K; k0+=32){
    #pragma unroll
    for (int c=0;c<2;c++){
      int row = 32*w + 16*c + lrow;
      int gch = lch ^ ((row>>1)&3);
      dma16(A + (long)(m0+row)*lda + k0 + gch*8, &As[(32*w+16*c)*32]);
      dma16(BT + (long)(n0+row)*ldb + k0 + gch*8, &Bs[(32*w+16*c)*32]);
    }
    __syncthreads();
    s16x8 af[4], bfr[4];
    #pragma unroll
    for (int mt=0;mt<4;mt++){
      int row = wy*64 + mt*16 + ln;
      af[mt] = *(const s16x8*)&As[row*32 + ((q ^ ((row>>1)&3))<<3)];
    }
    #pragma unroll
    for (int nt=0;nt<4;nt++){
      int row = wx*64 + nt*16 + ln;
      bfr[nt] = *(const s16x8*)&Bs[row*32 + ((q ^ ((row>>1)&3))<<3)];
    }
    #pragma unroll
    for (int mt=0;mt<4;mt++)
      #pragma unroll
      for (int nt=0;nt<4;nt++)
        acc[mt][nt] = MFMA16(af[mt], bfr[nt], acc[mt][nt]);
    __syncthreads();
  }

  #pragma unroll
  for (int mt=0;mt<4;mt++)
  #pragma unroll
  for (int nt=0;nt<4;nt++){
    int ncol = n0 + wx*64 + nt*16 + ln;
    if (EPI==EPI_QKV){
      int sel = ncol>>8, hd = ncol&255, h = hd>>5, d = hd&31;
      u16* dst = sel==0 ? qo : (sel==1 ? ko : vo);
      float sc2 = (sel==0) ? 0.17677669529663689f : 1.f;   // dh^-0.5 on q
      float s = 0.f;
      #pragma unroll
      for (int r=0;r<4;r++){
        int mrow = m0 + wy*64 + mt*16 + q*4 + r;
        int b = mrow>>12, n = mrow&4095;
        float v = acc[mt][nt][r]*sc2;
        dst[(((long)(b*8+h)*4096 + n)<<5) + d] = f2bf(v);
        s += v;
      }
      if (sel < 2){
        s += __shfl_xor(s, 16);
        s += __shfl_xor(s, 32);
        if (q == 0){
          int mrow0 = m0 + wy*64 + mt*16;
          int b = mrow0>>12, grp = (mrow0&4095)>>4;
          u16* ldst = (sel==0) ? qlm : klm;
          ldst[(((long)(b*8+h)*256 + grp)<<5) + d] = f2bf(s*(1.0f/16.0f));
        }
      }
    } else { // EPI_BIAS_GELU
      #pragma unroll
      for (int r=0;r<4;r++){
        int mrow = m0 + wy*64 + mt*16 + q*4 + r;
        float x = acc[mt][nt][r] + bias[ncol];
        float g = 0.5f*x*(1.0f + erff(x*0.70710678118654752f));
        outb[(long)mrow*ldc + ncol] = f2bf(g);
      }
    }
  }
}

// ---------------------------------------------------------------------------
// kgemmLN: BM=64, BN=256 (full rows per block, 256 blocks = full GPU),
// 4x4 frags/wave; residual+bias, then in-register LayerNorm with cross-wave
// combine -> writes y (f32) AND xn=LN(y) (bf16).
// ---------------------------------------------------------------------------
__global__ __launch_bounds__(256)
void kgemmLN(const u16* __restrict__ A, const u16* __restrict__ BT, int K,
             const float* __restrict__ bias, const float* __restrict__ base,
             float* __restrict__ yout,
             const float* __restrict__ lng, const float* __restrict__ lnb,
             u16* __restrict__ xnout)
{
  __shared__ __align__(16) u16 As[64*32];
  __shared__ __align__(16) u16 Bs[256*32];
  __shared__ float red[64][4];
  const int tid = threadIdx.x;
  const int w = tid>>6, l = tid&63, q = l>>4, ln = l&15;
  const int m0 = blockIdx.x*64;

  f32x4 acc[4][4];   // row = mt*16+q*4+r, col = w*64+nt*16+ln
  #pragma unroll
  for (int i=0;i<4;i++)
    #pragma unroll
    for (int j=0;j<4;j++){ acc[i][j][0]=0.f; acc[i][j][1]=0.f; acc[i][j][2]=0.f; acc[i][j][3]=0.f; }

  for (int k0=0; k0<K; k0+=32){
    {
      int row = w*16 + (l>>2);
      int gch = (l&3) ^ ((row>>1)&3);
      dma16(A + (long)(m0+row)*K + k0 + gch*8, &As[(w*16)*32]);
    }
    #pragma unroll
    for (int c=0;c<4;c++){
      int row = c*64 + w*16 + (l>>2);
      int gch = (l&3) ^ ((row>>1)&3);
      dma16(BT + (long)row*K + k0 + gch*8, &Bs[(c*64+w*16)*32]);
    }
    __syncthreads();
    s16x8 af[4], bfr[4];
    #pragma unroll
    for (int mt=0;mt<4;mt++){
      int row = mt*16 + ln;
      af[mt] = *(const s16x8*)&As[row*32 + ((q ^ ((row>>1)&3))<<3)];
    }
    #pragma unroll
    for (int nt=0;nt<4;nt++){
      int row = w*64 + nt*16 + ln;
      bfr[nt] = *(const s16x8*)&Bs[row*32 + ((q ^ ((row>>1)&3))<<3)];
    }
    #pragma unroll
    for (int mt=0;mt<4;mt++)
      #pragma unroll
      for (int nt=0;nt<4;nt++)
        acc[mt][nt] = MFMA16(af[mt], bfr[nt], acc[mt][nt]);
    __syncthreads();
  }

  // residual + bias, write y
  float rb[4];
  #pragma unroll
  for (int nt=0;nt<4;nt++) rb[nt] = bias[w*64 + nt*16 + ln];
  #pragma unroll
  for (int mt=0;mt<4;mt++)
  #pragma unroll
  for (int r=0;r<4;r++){
    long rowb = (long)(m0 + mt*16 + q*4 + r)*256;
    #pragma unroll
    for (int nt=0;nt<4;nt++){
      int col = w*64 + nt*16 + ln;
      float v = base[rowb + col] + acc[mt][nt][r] + rb[nt];
      acc[mt][nt][r] = v;
      yout[rowb + col] = v;
    }
  }
  // mean: per-lane over 4 nt, 16-lane shuffle, cross-wave via red
  #pragma unroll
  for (int mt=0;mt<4;mt++)
  #pragma unroll
  for (int r=0;r<4;r++){
    float s = acc[mt][0][r]+acc[mt][1][r]+acc[mt][2][r]+acc[mt][3][r];
    s += __shfl_xor(s,1); s += __shfl_xor(s,2); s += __shfl_xor(s,4); s += __shfl_xor(s,8);
    if (ln==0) red[mt*16+q*4+r][w] = s;
  }
  __syncthreads();
  float mu[4][4];
  #pragma unroll
  for (int mt=0;mt<4;mt++)
  #pragma unroll
  for (int r=0;r<4;r++){
    int row = mt*16+q*4+r;
    mu[mt][r] = (red[row][0]+red[row][1]+red[row][2]+red[row][3])*(1.0f/256.0f);
  }
  __syncthreads();
  #pragma unroll
  for (int mt=0;mt<4;mt++)
  #pragma unroll
  for (int r=0;r<4;r++){
    float vs = 0.f;
    #pragma unroll
    for (int nt=0;nt<4;nt++){ float d = acc[mt][nt][r]-mu[mt][r]; vs += d*d; }
    vs += __shfl_xor(vs,1); vs += __shfl_xor(vs,2); vs += __shfl_xor(vs,4); vs += __shfl_xor(vs,8);
    if (ln==0) red[mt*16+q*4+r][w] = vs;
  }
  __syncthreads();
  float rg[4], rbb[4];
  #pragma unroll
  for (int nt=0;nt<4;nt++){ int col = w*64+nt*16+ln; rg[nt]=lng[col]; rbb[nt]=lnb[col]; }
  #pragma unroll
  for (int mt=0;mt<4;mt++)
  #pragma unroll
  for (int r=0;r<4;r++){
    int row = mt*16+q*4+r;
    float rs = rsqrtf((red[row][0]+red[row][1]+red[row][2]+red[row][3])*(1.0f/256.0f) + 1e-5f);
    long rowb = (long)(m0 + row)*256;
    #pragma unroll
    for (int nt=0;nt<4;nt++){
      int col = w*64 + nt*16 + ln;
      float d = acc[mt][nt][r]-mu[mt][r];
      xnout[rowb + col] = f2bf(d*rs*rg[nt] + rbb[nt]);
    }
  }
}

// ---------------------------------------------------------------------------
// Fused pinv (round-5 proven): full 256x256 W staged in LDS via coalesced
// global_load_lds + reg-cached B frags read once from LDS.
// 512 threads (8 waves). W' = 0.25(13W -15W^2 +7W^3 -W^4) per 32-row slab;
// h rows split across slab0 (rows 0-15) and slab4 (rows 16-31).
// ---------------------------------------------------------------------------
__device__ __forceinline__ int swidx(int row, int col){
  int cc = col>>3;
  int sl = (cc&24)|((cc&7)^((row>>1)&7));
  return row*256 + sl*8 + (col&7);
}
__device__ __forceinline__ int slot8(int ca, int row){
  return ((ca&24)|((ca&7)^((row>>1)&7)))<<3;
}

// stage 256x256 bf16 (131072B), 8 waves
__device__ __forceinline__ void stage256(const u16* __restrict__ g, u16* lds, int w, int l){
  const int drow = l>>5, dch = l&31;
  #pragma unroll
  for (int c=0;c<16;c++){
    int base = (c*8 + w)*2;
    int row = base + drow;
    int gch = (dch&24) | ((dch&7) ^ ((row>>1)&7));
    dma16(g + (long)row*256 + gch*8, &lds[base*256]);
  }
}
// stage 32x256 (16KB), 8 waves
__device__ __forceinline__ void stage32(const u16* __restrict__ g, u16* lds, int w, int l){
  const int drow = l>>5, dch = l&31;
  #pragma unroll
  for (int c=0;c<2;c++){
    int base = (c*8 + w)*2;
    int row = base + drow;
    int gch = (dch&24) | ((dch&7) ^ ((row>>1)&7));
    dma16(g + (long)row*256 + gch*8, &lds[base*256]);
  }
}
// stage 16x256 (8KB), 8 waves (2 rows/wave)
__device__ __forceinline__ void stage16(const u16* __restrict__ g, u16* lds, int w, int l){
  const int drow = l>>5, dch = l&31;
  int row = w*2 + drow;
  int gch = (dch&24) | ((dch&7) ^ ((row>>1)&7));
  dma16(g + (long)row*256 + gch*8, &lds[(w*2)*256]);
}

// preload this wave's 32 B-columns (rows wn0..+31 of bL) across K into regs
__device__ __forceinline__ void loadBf(const u16* bL, int w, int l, s16x8 (&bw)[2][8]){
  const int q=l>>4, ln=l&15, wn0=w*32;
  #pragma unroll
  for (int nt=0;nt<2;nt++)
    #pragma unroll
    for (int kq=0;kq<8;kq++){
      int n = wn0 + nt*16 + ln, ca = kq*4+q;
      bw[nt][kq] = *(const s16x8*)&bL[n*256 + slot8(ca, n)];
    }
}

// acc = A(rows arow0..+31 of aL) @ B(regs), K=256
__device__ __forceinline__ void multAr(const u16* aL, int arow0, const s16x8 (&bw)[2][8],
                                       int l, f32x4 (&acc)[2][2]){
  const int q=l>>4, ln=l&15;
  #pragma unroll
  for (int mt=0;mt<2;mt++)
    #pragma unroll
    for (int nt=0;nt<2;nt++){ acc[mt][nt][0]=0.f; acc[mt][nt][1]=0.f; acc[mt][nt][2]=0.f; acc[mt][nt][3]=0.f; }
  #pragma unroll
  for (int kq=0;kq<8;kq++){
    int ca = kq*4+q;
    s16x8 af[2];
    #pragma unroll
    for (int mt=0;mt<2;mt++){
      int r = arow0 + mt*16 + ln;
      af[mt] = *(const s16x8*)&aL[r*256 + slot8(ca, r)];
    }
    #pragma unroll
    for (int mt=0;mt<2;mt++)
      #pragma unroll
      for (int nt=0;nt<2;nt++)
        acc[mt][nt] = MFMA16(af[mt], bw[nt][kq], acc[mt][nt]);
  }
}

// hacc = H(16 rows of hL) @ B(regs)
__device__ __forceinline__ void multHr(const u16* hL, const s16x8 (&bw)[2][8],
                                       int l, f32x4 (&hacc)[2]){
  const int q=l>>4, ln=l&15;
  hacc[0][0]=0.f; hacc[0][1]=0.f; hacc[0][2]=0.f; hacc[0][3]=0.f;
  hacc[1][0]=0.f; hacc[1][1]=0.f; hacc[1][2]=0.f; hacc[1][3]=0.f;
  #pragma unroll
  for (int kq=0;kq<8;kq++){
    int ca = kq*4+q;
    s16x8 af = *(const s16x8*)&hL[ln*256 + slot8(ca, ln)];
    hacc[0] = MFMA16(af, bw[0][kq], hacc[0]);
    hacc[1] = MFMA16(af, bw[1][kq], hacc[1]);
  }
}

__device__ __forceinline__ void polyinit13(const u16* aL, int arow0, int w, int l, f32x4 (&poly)[2][2]){
  const int q=l>>4, ln=l&15, wn0=w*32;
  #pragma unroll
  for (int mt=0;mt<2;mt++)
  #pragma unroll
  for (int nt=0;nt<2;nt++)
  #pragma unroll
  for (int r=0;r<4;r++){
    int row = arow0 + mt*16 + q*4 + r;
    int col = wn0 + nt*16 + ln;
    poly[mt][nt][r] = 13.f*bf2f(aL[swidx(row,col)]);
  }
}
__device__ __forceinline__ void init13H(const u16* hL, int w, int l, f32x4 (&hpoly)[2]){
  const int q=l>>4, ln=l&15, wn0=w*32;
  #pragma unroll
  for (int nt=0;nt<2;nt++)
  #pragma unroll
  for (int r=0;r<4;r++)
    hpoly[nt][r] = 13.f*bf2f(hL[swidx(q*4+r, wn0+nt*16+ln)]);
}
__device__ __forceinline__ void polyaxpy(f32x4 (&poly)[2][2], const f32x4 (&acc)[2][2], float sc){
  #pragma unroll
  for (int mt=0;mt<2;mt++)
    #pragma unroll
    for (int nt=0;nt<2;nt++)
      #pragma unroll
      for (int r=0;r<4;r++) poly[mt][nt][r] += sc*acc[mt][nt][r];
}
__device__ __forceinline__ void axpyH(f32x4 (&hpoly)[2], const f32x4 (&hacc)[2], float sc){
  #pragma unroll
  for (int nt=0;nt<2;nt++)
    #pragma unroll
    for (int r=0;r<4;r++) hpoly[nt][r] += sc*hacc[nt][r];
}
__device__ __forceinline__ void writeT(u16* Ts, const f32x4 (&acc)[2][2], int w, int l, float sc){
  const int q=l>>4, ln=l&15, wn0=w*32;
  #pragma unroll
  for (int mt=0;mt<2;mt++)
  #pragma unroll
  for (int nt=0;nt<2;nt++)
  #pragma unroll
  for (int r=0;r<4;r++){
    int row = mt*16 + q*4 + r;
    int col = wn0 + nt*16 + ln;
    Ts[swidx(row,col)] = f2bf(sc*acc[mt][nt][r]);
  }
}
__device__ __forceinline__ void writeH(u16* Hs, const f32x4 (&hacc)[2], int w, int l){
  const int q=l>>4, ln=l&15, wn0=w*32;
  #pragma unroll
  for (int nt=0;nt<2;nt++)
  #pragma unroll
  for (int r=0;r<4;r++)
    Hs[swidx(q*4+r, wn0+nt*16+ln)] = f2bf(hacc[nt][r]);
}
__device__ __forceinline__ void epi_poly(u16* __restrict__ out, int rowbase,
                                         const f32x4 (&poly)[2][2], int w, int l, float sc){
  const int q=l>>4, ln=l&15, wn0=w*32;
  #pragma unroll
  for (int mt=0;mt<2;mt++)
  #pragma unroll
  for (int nt=0;nt<2;nt++)
  #pragma unroll
  for (int r=0;r<4;r++){
    int row = rowbase + mt*16 + q*4 + r;
    int col = wn0 + nt*16 + ln;
    out[(long)row*256 + col] = f2bf(sc*poly[mt][nt][r]);
  }
}
__device__ __forceinline__ void epiH(u16* __restrict__ out, const f32x4 (&hpoly)[2],
                                     int w, int l, float sc){
  const int q=l>>4, ln=l&15, wn0=w*32;
  #pragma unroll
  for (int nt=0;nt<2;nt++)
  #pragma unroll
  for (int r=0;r<4;r++)
    out[(long)(q*4+r)*256 + wn0+nt*16+ln] = f2bf(sc*hpoly[nt][r]);
}

// legacy LDS-B mult (kw0 only: single phase, preload is neutral)
__device__ __forceinline__ void mult32(const u16* aL, int arow0, const u16* bL,
                                       int w, int l, f32x4 (&acc)[2][2]){
  const int q=l>>4, ln=l&15, wn0=w*32;
  #pragma unroll
  for (int mt=0;mt<2;mt++)
    #pragma unroll
    for (int nt=0;nt<2;nt++){ acc[mt][nt][0]=0.f; acc[mt][nt][1]=0.f; acc[mt][nt][2]=0.f; acc[mt][nt][3]=0.f; }
  #pragma unroll
  for (int kq=0;kq<8;kq++){
    int ca = kq*4+q;
    s16x8 af[2];
    #pragma unroll
    for (int mt=0;mt<2;mt++){
      int r = arow0 + mt*16 + ln;
      af[mt] = *(const s16x8*)&aL[r*256 + slot8(ca,r)];
    }
    #pragma unroll
    for (int nt=0;nt<2;nt++){
      int n = wn0 + nt*16 + ln;
      s16x8 bfr = *(const s16x8*)&bL[n*256 + slot8(ca,n)];
      acc[0][nt] = MFMA16(af[0], bfr, acc[0][nt]);
      acc[1][nt] = MFMA16(af[1], bfr, acc[1][nt]);
    }
  }
}

// kw0: W0 = s0*X@X^T slab; self-computed s0 from cs_p; slab0 also preps h0
__global__ __launch_bounds__(512)
void kw0(const float* __restrict__ cs_p, float* __restrict__ scal,
         const float* __restrict__ num_p, const float* __restrict__ den_p,
         const u16* __restrict__ X, u16* __restrict__ W0, u16* __restrict__ h0)
{
  __shared__ __align__(16) u16 Wf[65536];
  __shared__ __align__(16) u16 Ts[8192];
  const int tid=threadIdx.x, w=tid>>6, l=tid&63;
  const int bid=blockIdx.x, xcd=bid&7, j=bid>>3;
  const int batch = xcd*4 + (j>>3), slab = j&7;

  stage256(X + (long)batch*65536, Wf, w, l);   // dma in flight during reduce

  float* red = (float*)Ts;
  float mx = 0.f;
  for (int i=tid;i<8192;i+=512){
    float s = 0.f;
    #pragma unroll
    for (int c=0;c<8;c++) s += cs_p[(long)c*8192 + i];
    mx = fmaxf(mx, s);
  }
  red[tid] = mx; __syncthreads();
  for (int s=256;s>0;s>>=1){ if (tid<s) red[tid] = fmaxf(red[tid], red[tid+s]); __syncthreads(); }
  float s0 = 1.0f/red[0];
  if (bid==0 && tid==0) scal[0] = s0;

  f32x4 acc[2][2];
  mult32(Wf, slab*32, Wf, w, l, acc);
  {
    const int q=l>>4, ln=l&15, wn0=w*32;
    u16* ob = W0 + (long)batch*65536;
    #pragma unroll
    for (int mt=0;mt<2;mt++)
    #pragma unroll
    for (int nt=0;nt<2;nt++)
    #pragma unroll
    for (int r=0;r<4;r++){
      int row = slab*32 + mt*16 + q*4 + r;
      int col = wn0 + nt*16 + ln;
      ob[(long)row*256 + col] = f2bf(acc[mt][nt][r]*s0);
    }
  }

  if (slab==0){
    __syncthreads();
    float (*lt)[257] = (float(*)[257])Wf;
    for (int i=tid;i<8192;i+=512){
      int m = i>>5, d = i&31;
      float sn = 0.f, sd = 0.f;
      #pragma unroll
      for (int c=0;c<8;c++){
        sn += num_p[((long)(c*32+batch))*8192 + i];
        sd += den_p[(c*32+batch)*256 + m];
      }
      lt[d][m] = sn/sd;
    }
    __syncthreads();
    u16* o = h0 + (long)batch*8192;
    for (int j2=tid;j2<8192;j2+=512){
      int d = j2>>8, m = j2&255;
      o[j2] = f2bf(lt[d][m]);
    }
  }
}

// kiter: one Newton iteration. 256 blocks x 512 thr; slab0/slab4 advance h halves.
__global__ __launch_bounds__(512)
void kiter(const u16* __restrict__ Win, u16* __restrict__ Wout,
           const u16* __restrict__ hin, u16* __restrict__ hout)
{
  __shared__ __align__(16) u16 Wf[65536];
  __shared__ __align__(16) u16 Ts[8192];
  __shared__ __align__(16) u16 Hs[4096];
  const int tid=threadIdx.x, w=tid>>6, l=tid&63;
  const int bid=blockIdx.x, xcd=bid&7, j=bid>>3;
  const int batch = xcd*4 + (j>>3), slab = j&7;
  const bool hrole = (slab&3)==0;              // slabs 0 and 4
  const int hr0 = (slab>>2)*16;

  stage256(Win + (long)batch*65536, Wf, w, l);
  if (hrole) stage16(hin + (long)batch*8192 + hr0*256, Hs, w, l);
  __syncthreads();

  s16x8 bw[2][8];
  loadBf(Wf, w, l, bw);

  f32x4 acc[2][2], poly[2][2];
  f32x4 hacc[2], hpoly[2];

  polyinit13(Wf, slab*32, w, l, poly);
  multAr(Wf, slab*32, bw, l, acc);             // t1 = Wslab@W
  polyaxpy(poly, acc, -15.f);
  if (hrole){
    init13H(Hs, w, l, hpoly);
    multHr(Hs, bw, l, hacc);                   // h@W
    axpyH(hpoly, hacc, -15.f);
  }
  __syncthreads();
  writeT(Ts, acc, w, l, 1.f);
  if (hrole) writeH(Hs, hacc, w, l);
  __syncthreads();
  multAr(Ts, 0, bw, l, acc);                   // t2
  polyaxpy(poly, acc, 7.f);
  if (hrole){ multHr(Hs, bw, l, hacc); axpyH(hpoly, hacc, 7.f); }
  __syncthreads();
  writeT(Ts, acc, w, l, 1.f);
  if (hrole) writeH(Hs, hacc, w, l);
  __syncthreads();
  multAr(Ts, 0, bw, l, acc);                   // t3
  polyaxpy(poly, acc, -1.f);
  epi_poly(Wout + (long)batch*65536, slab*32, poly, w, l, 0.25f);
  if (hrole){
    multHr(Hs, bw, l, hacc);
    axpyH(hpoly, hacc, -1.f);
    epiH(hout + (long)batch*8192 + hr0*256, hpoly, w, l, 0.25f);
  }
}

// ktail: g1 chain in-LDS (reg-B), then u = s0*g1@X (via XT restage)
__global__ __launch_bounds__(512)
void ktail(const u16* __restrict__ W5, const u16* __restrict__ h5,
           const u16* __restrict__ XT, const float* __restrict__ scal,
           u16* __restrict__ uT)
{
  __shared__ __align__(16) u16 Wf[65536];
  __shared__ __align__(16) u16 Ts[8192];
  const int tid=threadIdx.x, w=tid>>6, l=tid&63;
  const int batch = blockIdx.x;

  stage256(W5 + (long)batch*65536, Wf, w, l);
  stage32(h5 + (long)batch*8192, Ts, w, l);
  __syncthreads();

  s16x8 bw[2][8];
  loadBf(Wf, w, l, bw);

  f32x4 acc[2][2], poly[2][2];
  polyinit13(Ts, 0, w, l, poly);
  multAr(Ts, 0, bw, l, acc);                   // a = h5@W5
  polyaxpy(poly, acc, -15.f);
  __syncthreads(); writeT(Ts, acc, w, l, 1.f); __syncthreads();
  multAr(Ts, 0, bw, l, acc);                   // b
  polyaxpy(poly, acc, 7.f);
  __syncthreads(); writeT(Ts, acc, w, l, 1.f); __syncthreads();
  multAr(Ts, 0, bw, l, acc);                   // c
  polyaxpy(poly, acc, -1.f);
  __syncthreads();
  writeT(Ts, poly, w, l, 0.25f);               // g1 -> Ts
  stage256(XT + (long)batch*65536, Wf, w, l);  // X^T over W5
  __syncthreads();
  loadBf(Wf, w, l, bw);
  multAr(Ts, 0, bw, l, acc);                   // u = g1@X
  const float s0 = scal[0];
  {
    const int q=l>>4, ln=l&15, wn0=w*32;
    u16* ob = uT + (long)batch*8192;
    #pragma unroll
    for (int mt=0;mt<2;mt++)
    #pragma unroll
    for (int nt=0;nt<2;nt++)
    #pragma unroll
    for (int r=0;r<4;r++){
      int row = mt*16 + q*4 + r;
      int col = wn0 + nt*16 + ln;
      ob[(long)row*256 + col] = f2bf(acc[mt][nt][r]*s0);
    }
  }
}

// ---------------------------------------------------------------------------
// Merged attn2 + attn3v (independent; grid (16,32): x<8 attn2, x>=8 attn3v)
// attn3v: double-buffered vT, 1 barrier per step, hoisted q-frags.
// ---------------------------------------------------------------------------
__global__ __launch_bounds__(256)
void kattn23(const u16* __restrict__ ql, const u16* __restrict__ kl,
             u16* __restrict__ X, u16* __restrict__ XT, float* __restrict__ cs_p,
             const u16* __restrict__ kk, const u16* __restrict__ vv,
             float* __restrict__ num_p, float* __restrict__ den_p)
{
  __shared__ __align__(16) u16 Pbuf[4][64][40];
  __shared__ __align__(16) u16 vT2[2][32][40];
  __shared__ float qrow[32][33];
  __shared__ float psum[32][4];
  __shared__ float rsum[32];
  int bh = blockIdx.y;
  int tid = threadIdx.x, w = tid>>6, l = tid&63, q = l>>4, ln = l&15;

  if (blockIdx.x < 8){
    int r0 = blockIdx.x*32;
    int c = tid;
    #pragma unroll
    for (int i=0;i<4;i++){
      int e = c*4+i; int rr = e>>5, dd = e&31;
      qrow[rr][dd] = bf2f(ql[((long)bh*256 + r0+rr)*32 + dd]);
    }
    float kc[32];
    {
      const u16* kp = kl + ((long)bh*256 + c)*32;
      #pragma unroll
      for (int d=0;d<32;d++) kc[d] = bf2f(kp[d]);
    }
    __syncthreads();
    float er[32]; float colacc = 0.f;
    for (int r=0;r<32;r++){
      float s = 0.f;
      #pragma unroll
      for (int d=0;d<32;d++) s += qrow[r][d]*kc[d];
      float e = __expf(s);
      er[r] = e;
      float wsum = e;
      #pragma unroll
      for (int m=1;m<64;m<<=1) wsum += __shfl_xor(wsum, m);
      if (l==0) psum[r][w] = wsum;
    }
    __syncthreads();
    if (c<32) rsum[c] = psum[c][0]+psum[c][1]+psum[c][2]+psum[c][3];
    __syncthreads();
    for (int r=0;r<32;r++){
      float x = er[r]/rsum[r];
      u16 xb = f2bf(x);
      X [((long)bh*256 + r0+r)*256 + c] = xb;
      XT[((long)bh*256 + c)*256 + r0+r] = xb;
      colacc += x;
    }
    cs_p[(long)blockIdx.x*8192 + bh*256 + c] = colacc;
    return;
  }

  int chunk = blockIdx.x - 8;
  f32x4 z4; z4[0]=0.f; z4[1]=0.f; z4[2]=0.f; z4[3]=0.f;
  f32x4 acc[4][2]; f32x4 dacc[4];
  #pragma unroll
  for (int mt=0;mt<4;mt++){ dacc[mt]=z4; acc[mt][0]=z4; acc[mt][1]=z4; }
  const u16* qlb = ql + (long)bh*8192;
  const u16* kb  = kk + (long)bh*131072;
  const u16* vb  = vv + (long)bh*131072;
  s16x8 aq[4];
  #pragma unroll
  for (int mt=0;mt<4;mt++) aq[mt] = *(const s16x8*)(qlb + (long)(w*64 + mt*16 + ln)*32 + q*8);
  int vn = tid>>3, vd = (tid&7)*4;
  {
    ushort4 vx = *(const ushort4*)(vb + (long)(chunk*512+vn)*32 + vd);
    vT2[0][vd+0][vn]=vx.x; vT2[0][vd+1][vn]=vx.y; vT2[0][vd+2][vn]=vx.z; vT2[0][vd+3][vn]=vx.w;
  }
  __syncthreads();
  for (int s=0;s<16;s++){
    int cur = s&1;
    ushort4 vnx;
    if (s<15) vnx = *(const ushort4*)(vb + (long)(chunk*512+(s+1)*32+vn)*32 + vd);
    int n0 = chunk*512 + s*32;
    s16x8 bk[2];
    #pragma unroll
    for (int nt=0;nt<2;nt++) bk[nt] = *(const s16x8*)(kb + (long)(n0 + nt*16 + ln)*32 + q*8);
    #pragma unroll
    for (int mt=0;mt<4;mt++){
      #pragma unroll
      for (int nt=0;nt<2;nt++){
        f32x4 sf = MFMA16(aq[mt], bk[nt], z4);
        f32x4 ef;
        #pragma unroll
        for (int r=0;r<4;r++) ef[r] = __expf(sf[r]);
        dacc[mt] += ef;
        #pragma unroll
        for (int r=0;r<4;r++) Pbuf[w][mt*16 + q*4 + r][nt*16 + ln] = f2bf(ef[r]);
      }
    }
    #pragma unroll
    for (int mt=0;mt<4;mt++){
      s16x8 ap = *(const s16x8*)&Pbuf[w][mt*16 + ln][q*8];
      #pragma unroll
      for (int nt=0;nt<2;nt++){
        s16x8 bv = *(const s16x8*)&vT2[cur][nt*16 + ln][q*8];
        acc[mt][nt] = MFMA16(ap, bv, acc[mt][nt]);
      }
    }
    if (s<15){
      int nxt = cur^1;
      vT2[nxt][vd+0][vn]=vnx.x; vT2[nxt][vd+1][vn]=vnx.y; vT2[nxt][vd+2][vn]=vnx.z; vT2[nxt][vd+3][vn]=vnx.w;
    }
    __syncthreads();
  }
  #pragma unroll
  for (int mt=0;mt<4;mt++)
    #pragma unroll
    for (int r=0;r<4;r++){
      float x = dacc[mt][r];
      x += __shfl_xor(x,1); x += __shfl_xor(x,2); x += __shfl_xor(x,4); x += __shfl_xor(x,8);
      dacc[mt][r] = x;
    }
  long pbase = (long)(chunk*32 + bh);
  #pragma unroll
  for (int mt=0;mt<4;mt++)
    #pragma unroll
    for (int nt=0;nt<2;nt++)
      #pragma unroll
      for (int r=0;r<4;r++){
        int mg = w*64 + mt*16 + q*4 + r;
        num_p[pbase*8192 + (long)mg*32 + nt*16 + ln] = acc[mt][nt][r];
      }
  if (ln==0){
    #pragma unroll
    for (int mt=0;mt<4;mt++)
      #pragma unroll
      for (int r=0;r<4;r++)
        den_p[pbase*256 + w*64 + mt*16 + q*4 + r] = dacc[mt][r];
  }
}

// ---------------------------------------------------------------------------
// attn1 fused + depthwise residual conv (transposed vtile, vector conv reads)
// ---------------------------------------------------------------------------
__global__ __launch_bounds__(256)
void kattn1u(const u16* __restrict__ qq, const u16* __restrict__ kl, const u16* __restrict__ uT,
             const u16* __restrict__ vv, const float* __restrict__ rw,
             u16* __restrict__ aoutb)
{
  int nch = blockIdx.x, bh = blockIdx.y;
  int b = bh>>3, h = bh&7;
  int tid = threadIdx.x, w = tid>>6, l = tid&63, q = l>>4, ln = l&15;
  __shared__ __align__(16) u16 Pbuf[4][32][40];
  __shared__ __align__(16) u16 vtileT[32][164];
  int r0g = nch*128;
  const u16* vb = vv + (long)bh*131072;
  #pragma unroll
  for (int it=0; it<5; it++){
    int slot = tid + it*256;
    int rr = slot>>3, c = (slot&7)*4;
    int s = r0g - 16 + rr;
    ushort4 val; val.x=0; val.y=0; val.z=0; val.w=0;
    if (s>=0 && s<4096) val = *(const ushort4*)(vb + (long)s*32 + c);
    vtileT[c+0][rr]=val.x; vtileT[c+1][rr]=val.y; vtileT[c+2][rr]=val.z; vtileT[c+3][rr]=val.w;
  }
  __syncthreads();

  f32x4 z4; z4[0]=0.f; z4[1]=0.f; z4[2]=0.f; z4[3]=0.f;
  f32x4 acc[2][2]; f32x4 dacc[2];
  #pragma unroll
  for (int mt=0;mt<2;mt++){ dacc[mt]=z4; acc[mt][0]=z4; acc[mt][1]=z4; }
  const u16* qb  = qq + (long)bh*131072;
  const u16* klb = kl + (long)bh*8192;
  const u16* ub  = uT + (long)bh*8192;
  int r0 = r0g + w*32;
  s16x8 aq[2];
  #pragma unroll
  for (int mt=0;mt<2;mt++) aq[mt] = *(const s16x8*)(qb + (long)(r0 + mt*16 + ln)*32 + q*8);
  for (int s=0;s<8;s++){
    s16x8 bk[2];
    #pragma unroll
    for (int nt=0;nt<2;nt++) bk[nt] = *(const s16x8*)(klb + (long)(s*32 + nt*16 + ln)*32 + q*8);
    #pragma unroll
    for (int mt=0;mt<2;mt++){
      #pragma unroll
      for (int nt=0;nt<2;nt++){
        f32x4 sf = MFMA16(aq[mt], bk[nt], z4);
        f32x4 ef;
        #pragma unroll
        for (int r=0;r<4;r++) ef[r] = __expf(sf[r]);
        dacc[mt] += ef;
        #pragma unroll
        for (int r=0;r<4;r++) Pbuf[w][mt*16 + q*4 + r][nt*16 + ln] = f2bf(ef[r]);
      }
    }
    #pragma unroll
    for (int mt=0;mt<2;mt++){
      s16x8 ap = *(const s16x8*)&Pbuf[w][mt*16 + ln][q*8];
      #pragma unroll
      for (int nt=0;nt<2;nt++){
        s16x8 bu = *(const s16x8*)(ub + (long)(nt*16 + ln)*256 + s*32 + q*8);
        acc[mt][nt] = MFMA16(ap, bu, acc[mt][nt]);
      }
    }
  }
  #pragma unroll
  for (int mt=0;mt<2;mt++)
    #pragma unroll
    for (int r=0;r<4;r++){
      float x = dacc[mt][r];
      x += __shfl_xor(x,1); x += __shfl_xor(x,2); x += __shfl_xor(x,4); x += __shfl_xor(x,8);
      dacc[mt][r] = x;
    }

  const float* wp = rw + h*33;
  float w_[33];
  #pragma unroll
  for (int j=0;j<33;j++) w_[j] = wp[j];

  #pragma unroll
  for (int mt=0;mt<2;mt++){
    int nl = w*32 + mt*16 + q*4;
    #pragma unroll
    for (int nt=0;nt<2;nt++){
      int d = nt*16 + ln;
      float vvv[36];
      const u16* vp = &vtileT[d][nl];        // nl%4==0 -> 8B aligned
      #pragma unroll
      for (int jj=0;jj<9;jj++){
        ushort4 vq = *(const ushort4*)(vp + jj*4);
        vvv[jj*4+0]=bf2f(vq.x); vvv[jj*4+1]=bf2f(vq.y);
        vvv[jj*4+2]=bf2f(vq.z); vvv[jj*4+3]=bf2f(vq.w);
      }
      #pragma unroll
      for (int r=0;r<4;r++){
        float cv = 0.f;
        #pragma unroll
        for (int j=0;j<33;j++) cv += w_[j]*vvv[r+j];
        int n = r0 + mt*16 + q*4 + r;
        long oidx = ((long)b*4096 + n)*256 + h*32 + d;
        aoutb[oidx] = f2bf(acc[mt][nt][r]/dacc[mt][r] + cv);
      }
    }
  }
}

// ---------------------------------------------------------------------------
// Merged: LN(x) (blocks 0..4095) + weight transpose/cast (blocks 4096..5119)
// ---------------------------------------------------------------------------
__global__ __launch_bounds__(256)
void kcvtln(const float* __restrict__ xin, const float* __restrict__ lg, const float* __restrict__ lb,
            u16* __restrict__ xn,
            const float* __restrict__ wqkv, const float* __restrict__ wout,
            const float* __restrict__ w1, const float* __restrict__ w2,
            u16* __restrict__ wqkvT, u16* __restrict__ woutT,
            u16* __restrict__ w1T, u16* __restrict__ w2T)
{
  __shared__ float t[32][33];
  int z = blockIdx.x;
  if (z < 4096){
    int w = threadIdx.x>>6, l = threadIdx.x&63;
    long row = (long)z*4 + w;
    float4 v = ((const float4*)(xin + row*256))[l];
    float s = v.x+v.y+v.z+v.w;
    #pragma unroll
    for (int m=1;m<64;m<<=1) s += __shfl_xor(s, m);
    float mu = s*(1.0f/256.0f);
    float dx=v.x-mu, dy=v.y-mu, dz=v.z-mu, dw=v.w-mu;
    float s2 = dx*dx+dy*dy+dz*dz+dw*dw;
    #pragma unroll
    for (int m=1;m<64;m<<=1) s2 += __shfl_xor(s2, m);
    float rs = rsqrtf(s2*(1.0f/256.0f) + 1e-5f);
    float4 gg = ((const float4*)lg)[l];
    float4 bb = ((const float4*)lb)[l];
    ushort4 o;
    o.x = f2bf(dx*rs*gg.x + bb.x);
    o.y = f2bf(dy*rs*gg.y + bb.y);
    o.z = f2bf(dz*rs*gg.z + bb.z);
    o.w = f2bf(dw*rs*gg.w + bb.w);
    *(ushort4*)(xn + row*256 + l*4) = o;
    return;
  }
  z -= 4096;
  const float* src; u16* dst; int K, Nn, bx, by;
  if (z < 384){      int i=z/192, r=z%192; src=wqkv+(long)i*196608; dst=wqkvT+(long)i*196608; K=256; Nn=768; bx=r%24; by=r/24; }
  else if (z < 512){ int zz=z-384; int i=zz/64, r=zz%64; src=wout+(long)i*65536; dst=woutT+(long)i*65536; K=256; Nn=256; bx=r%8; by=r/8; }
  else if (z < 768){ int zz=z-512; int i=zz/128, r=zz%128; src=w1+(long)i*131072; dst=w1T+(long)i*131072; K=256; Nn=512; bx=r%16; by=r/16; }
  else {             int zz=z-768; int i=zz/128, r=zz%128; src=w2+(long)i*131072; dst=w2T+(long)i*131072; K=512; Nn=256; bx=r%8; by=r/8; }
  int n0 = bx*32, k0 = by*32;
  int tx = threadIdx.x&31, ty = threadIdx.x>>5;
  #pragma unroll
  for (int i=0;i<4;i++) t[ty+i*8][tx] = src[(long)(k0+ty+i*8)*Nn + n0+tx];
  __syncthreads();
  #pragma unroll
  for (int i=0;i<4;i++) dst[(long)(n0+ty+i*8)*K + k0+tx] = f2bf(t[tx][ty+i*8]);
}

// ---------------------------------------------------------------------------
extern "C" void kernel_launch(void* const* d_in, const int* in_sizes, int n_in,
                              void* d_out, int out_size, void* d_ws, size_t ws_size,
                              hipStream_t stream)
{
  const float* x    = (const float*)d_in[0];
  const float* ln1g = (const float*)d_in[1];
  const float* ln1b = (const float*)d_in[2];
  const float* wqkv = (const float*)d_in[3];
  const float* wout = (const float*)d_in[4];
  const float* bout = (const float*)d_in[5];
  const float* resw = (const float*)d_in[6];
  const float* ln2g = (const float*)d_in[7];
  const float* ln2b = (const float*)d_in[8];
  const float* w1   = (const float*)d_in[9];
  const float* b1   = (const float*)d_in[10];
  const float* w2   = (const float*)d_in[11];
  const float* b2   = (const float*)d_in[12];
  float* y = (float*)d_out;
  char* ws = (char*)d_ws;

  u16* xn    = (u16*)(ws + 0);
  u16* qb    = (u16*)(ws + 8388608);
  u16* kb    = (u16*)(ws + 16777216);
  u16* vb    = (u16*)(ws + 25165824);
  u16* ql    = (u16*)(ws + 33554432);
  u16* kl    = (u16*)(ws + 34078720);
  u16* X     = (u16*)(ws + 34603008);
  u16* XT    = (u16*)(ws + 38797312);     // X^T (B-operand of final U GEMM)
  u16* h0b   = (u16*)(ws + 42991616);     // h0 [32][32][256] bf16 (512 KB)
  // pinv work region
  u16* WA    = (u16*)(ws + 51380224);
  u16* WB    = (u16*)(ws + 55574528);
  u16* hA    = (u16*)(ws + 68157440);     // thin h buffers [32][32][256]
  u16* hB    = (u16*)(ws + 72351744);
  float* num_p = (float*)(ws + 76546048);  // 8 MB
  float* den_p = (float*)(ws + 84934656);
  float* cs_p  = (float*)(ws + 85196800);
  float* scal  = (float*)(ws + 85458944);
  u16* uT    = (u16*)(ws + 85459200);
  u16* aoutb = (u16*)(ws + 85983488);
  u16* wqkvT = (u16*)(ws + 94372096);
  u16* woutT = (u16*)(ws + 95158528);
  u16* w1T   = (u16*)(ws + 95420672);
  u16* w2T   = (u16*)(ws + 95944960);
  u16* hdn   = (u16*)(ws + 51380224);      // overlays WA/WB (dead by FFN)

  (void)in_sizes; (void)n_in; (void)out_size; (void)ws_size;

  // LN(x) + weight cvt in one launch
  kcvtln<<<5120,256,0,stream>>>(x, ln1g, ln1b, xn,
      wqkv, wout, w1, w2, wqkvT, woutT, w1T, w2T);

  for (int i=0;i<2;i++){
    // xn: i==0 from kcvtln; i==1 from previous FFN2's fused LN epilogue
    kgemm2<EPI_QKV><<<dim3(128,6),256,0,stream>>>(xn, wqkvT + (long)i*196608, 256, 256, 256,
        nullptr, nullptr, 0, qb,kb,vb, ql,kl);
    kattn23<<<dim3(16,32),256,0,stream>>>(ql, kl, X, XT, cs_p, kb, vb, num_p, den_p);

    // ---- pinv: kw0 (scal + W0 + h0) -> 5x kiter -> ktail (g1 chain + U) ----
    kw0<<<256,512,0,stream>>>(cs_p, scal, num_p, den_p, X, WA, h0b);
    u16 *Wi = WA, *Wo = WB, *hi = h0b, *ho = hA;
    for (int it=0; it<5; it++){
      kiter<<<256,512,0,stream>>>(Wi, Wo, hi, ho);
      u16* t = Wi; Wi = Wo; Wo = t;
      hi = ho; ho = (ho == hA) ? hB : hA;
    }
    ktail<<<32,512,0,stream>>>(Wi, hi, XT, scal, uT);

    kattn1u<<<dim3(32,32),256,0,stream>>>(qb, kl, uT, vb, resw + i*264, aoutb);
    // wout GEMM + residual + LN2 fused -> y (f32) + xn (bf16 for FFN1)
    kgemmLN<<<256,256,0,stream>>>(aoutb, woutT + (long)i*65536, 256,
        bout + i*256, i==0 ? x : y, y, ln2g + i*256, ln2b + i*256, xn);
    kgemm2<EPI_BIAS_GELU><<<dim3(128,4),256,0,stream>>>(xn, w1T + (long)i*131072, 256, 256, 256,
        b1 + i*512, hdn, 512, nullptr,nullptr,nullptr, nullptr,nullptr);
    // FFN2 GEMM + residual + LN1(next) fused -> y + xn (for next QKV; dead on i==1)
    kgemmLN<<<256,256,0,stream>>>(hdn, w2T + (long)i*131072, 512,
        b2 + i*256, y, y, ln1g + 256, ln1b + 256, xn);
  }
}

// Round 8
// 500.013 us; speedup vs baseline: 1.2419x; 1.2419x over previous
//
#include <hip/hip_runtime.h>
#include <math.h>

typedef float f32x4 __attribute__((ext_vector_type(4)));
typedef short s16x8 __attribute__((ext_vector_type(8)));
typedef unsigned short u16;
typedef unsigned int u32;

#define MFMA16(a,b,c) __builtin_amdgcn_mfma_f32_16x16x32_bf16((a),(b),(c),0,0,0)
#define AS1 __attribute__((address_space(1)))
#define AS3 __attribute__((address_space(3)))

__device__ __forceinline__ void dma16(const u16* g, u16* l){
  __builtin_amdgcn_global_load_lds((const AS1 u32*)g, (AS3 u32*)l, 16, 0, 0);
}

__device__ __forceinline__ float bf2f(u16 u){
  union { unsigned int i; float f; } v; v.i = ((unsigned int)u)<<16; return v.f;
}
__device__ __forceinline__ u16 f2bf(float f){
  union { float f; unsigned int i; } v; v.f = f;
  unsigned int x = v.i;
  return (u16)((x + 0x7fffu + ((x>>16)&1u))>>16);
}

enum { EPI_QKV=0, EPI_BIAS_GELU=3 };

// ---------------------------------------------------------------------------
// kgemm2: BM=128, BN=128, BK=32, 4x4 frags/wave; DMA staging + swizzle.
// ---------------------------------------------------------------------------
template<int EPI>
__global__ __launch_bounds__(256)
void kgemm2(const u16* __restrict__ A, const u16* __restrict__ BT, int K, int lda, int ldb,
            const float* __restrict__ bias, u16* __restrict__ outb, int ldc,
            u16* __restrict__ qo, u16* __restrict__ ko, u16* __restrict__ vo,
            u16* __restrict__ qlm, u16* __restrict__ klm)
{
  __shared__ __align__(16) u16 As[128*32];
  __shared__ __align__(16) u16 Bs[128*32];
  const int tid = threadIdx.x;
  const int w = tid>>6, wy = w>>1, wx = w&1, l = tid&63, q = l>>4, ln = l&15;
  const int m0 = blockIdx.x*128, n0 = blockIdx.y*128;
  const int lrow = l>>2, lch = l&3;

  f32x4 acc[4][4];
  #pragma unroll
  for (int i=0;i<4;i++)
    #pragma unroll
    for (int j=0;j<4;j++){ acc[i][j][0]=0.f; acc[i][j][1]=0.f; acc[i][j][2]=0.f; acc[i][j][3]=0.f; }

  for (int k0=0; k0<K; k0+=32){
    #pragma unroll
    for (int c=0;c<2;c++){
      int row = 32*w + 16*c + lrow;
      int gch = lch ^ ((row>>1)&3);
      dma16(A + (long)(m0+row)*lda + k0 + gch*8, &As[(32*w+16*c)*32]);
      dma16(BT + (long)(n0+row)*ldb + k0 + gch*8, &Bs[(32*w+16*c)*32]);
    }
    __syncthreads();
    s16x8 af[4], bfr[4];
    #pragma unroll
    for (int mt=0;mt<4;mt++){
      int row = wy*64 + mt*16 + ln;
      af[mt] = *(const s16x8*)&As[row*32 + ((q ^ ((row>>1)&3))<<3)];
    }
    #pragma unroll
    for (int nt=0;nt<4;nt++){
      int row = wx*64 + nt*16 + ln;
      bfr[nt] = *(const s16x8*)&Bs[row*32 + ((q ^ ((row>>1)&3))<<3)];
    }
    #pragma unroll
    for (int mt=0;mt<4;mt++)
      #pragma unroll
      for (int nt=0;nt<4;nt++)
        acc[mt][nt] = MFMA16(af[mt], bfr[nt], acc[mt][nt]);
    __syncthreads();
  }

  #pragma unroll
  for (int mt=0;mt<4;mt++)
  #pragma unroll
  for (int nt=0;nt<4;nt++){
    int ncol = n0 + wx*64 + nt*16 + ln;
    if (EPI==EPI_QKV){
      int sel = ncol>>8, hd = ncol&255, h = hd>>5, d = hd&31;
      u16* dst = sel==0 ? qo : (sel==1 ? ko : vo);
      float sc2 = (sel==0) ? 0.17677669529663689f : 1.f;   // dh^-0.5 on q
      float s = 0.f;
      #pragma unroll
      for (int r=0;r<4;r++){
        int mrow = m0 + wy*64 + mt*16 + q*4 + r;
        int b = mrow>>12, n = mrow&4095;
        float v = acc[mt][nt][r]*sc2;
        dst[(((long)(b*8+h)*4096 + n)<<5) + d] = f2bf(v);
        s += v;
      }
      if (sel < 2){
        s += __shfl_xor(s, 16);
        s += __shfl_xor(s, 32);
        if (q == 0){
          int mrow0 = m0 + wy*64 + mt*16;
          int b = mrow0>>12, grp = (mrow0&4095)>>4;
          u16* ldst = (sel==0) ? qlm : klm;
          ldst[(((long)(b*8+h)*256 + grp)<<5) + d] = f2bf(s*(1.0f/16.0f));
        }
      }
    } else { // EPI_BIAS_GELU
      #pragma unroll
      for (int r=0;r<4;r++){
        int mrow = m0 + wy*64 + mt*16 + q*4 + r;
        float x = acc[mt][nt][r] + bias[ncol];
        float g = 0.5f*x*(1.0f + erff(x*0.70710678118654752f));
        outb[(long)mrow*ldc + ncol] = f2bf(g);
      }
    }
  }
}

// ---------------------------------------------------------------------------
// kgemmLN: BM=64, BN=256 (full rows per block, 256 blocks = full GPU),
// 4x4 frags/wave; residual+bias, then in-register LayerNorm with cross-wave
// combine -> writes y (f32) AND xn=LN(y) (bf16).
// ---------------------------------------------------------------------------
__global__ __launch_bounds__(256)
void kgemmLN(const u16* __restrict__ A, const u16* __restrict__ BT, int K,
             const float* __restrict__ bias, const float* __restrict__ base,
             float* __restrict__ yout,
             const float* __restrict__ lng, const float* __restrict__ lnb,
             u16* __restrict__ xnout)
{
  __shared__ __align__(16) u16 As[64*32];
  __shared__ __align__(16) u16 Bs[256*32];
  __shared__ float red[64][4];
  const int tid = threadIdx.x;
  const int w = tid>>6, l = tid&63, q = l>>4, ln = l&15;
  const int m0 = blockIdx.x*64;

  f32x4 acc[4][4];   // row = mt*16+q*4+r, col = w*64+nt*16+ln
  #pragma unroll
  for (int i=0;i<4;i++)
    #pragma unroll
    for (int j=0;j<4;j++){ acc[i][j][0]=0.f; acc[i][j][1]=0.f; acc[i][j][2]=0.f; acc[i][j][3]=0.f; }

  for (int k0=0; k0<K; k0+=32){
    {
      int row = w*16 + (l>>2);
      int gch = (l&3) ^ ((row>>1)&3);
      dma16(A + (long)(m0+row)*K + k0 + gch*8, &As[(w*16)*32]);
    }
    #pragma unroll
    for (int c=0;c<4;c++){
      int row = c*64 + w*16 + (l>>2);
      int gch = (l&3) ^ ((row>>1)&3);
      dma16(BT + (long)row*K + k0 + gch*8, &Bs[(c*64+w*16)*32]);
    }
    __syncthreads();
    s16x8 af[4], bfr[4];
    #pragma unroll
    for (int mt=0;mt<4;mt++){
      int row = mt*16 + ln;
      af[mt] = *(const s16x8*)&As[row*32 + ((q ^ ((row>>1)&3))<<3)];
    }
    #pragma unroll
    for (int nt=0;nt<4;nt++){
      int row = w*64 + nt*16 + ln;
      bfr[nt] = *(const s16x8*)&Bs[row*32 + ((q ^ ((row>>1)&3))<<3)];
    }
    #pragma unroll
    for (int mt=0;mt<4;mt++)
      #pragma unroll
      for (int nt=0;nt<4;nt++)
        acc[mt][nt] = MFMA16(af[mt], bfr[nt], acc[mt][nt]);
    __syncthreads();
  }

  // residual + bias, write y
  float rb[4];
  #pragma unroll
  for (int nt=0;nt<4;nt++) rb[nt] = bias[w*64 + nt*16 + ln];
  #pragma unroll
  for (int mt=0;mt<4;mt++)
  #pragma unroll
  for (int r=0;r<4;r++){
    long rowb = (long)(m0 + mt*16 + q*4 + r)*256;
    #pragma unroll
    for (int nt=0;nt<4;nt++){
      int col = w*64 + nt*16 + ln;
      float v = base[rowb + col] + acc[mt][nt][r] + rb[nt];
      acc[mt][nt][r] = v;
      yout[rowb + col] = v;
    }
  }
  // mean: per-lane over 4 nt, 16-lane shuffle, cross-wave via red
  #pragma unroll
  for (int mt=0;mt<4;mt++)
  #pragma unroll
  for (int r=0;r<4;r++){
    float s = acc[mt][0][r]+acc[mt][1][r]+acc[mt][2][r]+acc[mt][3][r];
    s += __shfl_xor(s,1); s += __shfl_xor(s,2); s += __shfl_xor(s,4); s += __shfl_xor(s,8);
    if (ln==0) red[mt*16+q*4+r][w] = s;
  }
  __syncthreads();
  float mu[4][4];
  #pragma unroll
  for (int mt=0;mt<4;mt++)
  #pragma unroll
  for (int r=0;r<4;r++){
    int row = mt*16+q*4+r;
    mu[mt][r] = (red[row][0]+red[row][1]+red[row][2]+red[row][3])*(1.0f/256.0f);
  }
  __syncthreads();
  #pragma unroll
  for (int mt=0;mt<4;mt++)
  #pragma unroll
  for (int r=0;r<4;r++){
    float vs = 0.f;
    #pragma unroll
    for (int nt=0;nt<4;nt++){ float d = acc[mt][nt][r]-mu[mt][r]; vs += d*d; }
    vs += __shfl_xor(vs,1); vs += __shfl_xor(vs,2); vs += __shfl_xor(vs,4); vs += __shfl_xor(vs,8);
    if (ln==0) red[mt*16+q*4+r][w] = vs;
  }
  __syncthreads();
  float rg[4], rbb[4];
  #pragma unroll
  for (int nt=0;nt<4;nt++){ int col = w*64+nt*16+ln; rg[nt]=lng[col]; rbb[nt]=lnb[col]; }
  #pragma unroll
  for (int mt=0;mt<4;mt++)
  #pragma unroll
  for (int r=0;r<4;r++){
    int row = mt*16+q*4+r;
    float rs = rsqrtf((red[row][0]+red[row][1]+red[row][2]+red[row][3])*(1.0f/256.0f) + 1e-5f);
    long rowb = (long)(m0 + row)*256;
    #pragma unroll
    for (int nt=0;nt<4;nt++){
      int col = w*64 + nt*16 + ln;
      float d = acc[mt][nt][r]-mu[mt][r];
      xnout[rowb + col] = f2bf(d*rs*rg[nt] + rbb[nt]);
    }
  }
}

// ---------------------------------------------------------------------------
// Fused pinv: full 256x256 W resident in LDS + reg-cached B frags.
// 512 threads (8 waves). W' = 0.25(13W -15W^2 +7W^3 -W^4) per 32-row slab;
// h rows split across slab0 (rows 0-15) and slab4 (rows 16-31).
// ---------------------------------------------------------------------------
__device__ __forceinline__ int swidx(int row, int col){
  int cc = col>>3;
  int sl = (cc&24)|((cc&7)^((row>>1)&7));
  return row*256 + sl*8 + (col&7);
}
__device__ __forceinline__ int slot8(int ca, int row){
  return ((ca&24)|((ca&7)^((row>>1)&7)))<<3;
}

// stage 256x256 bf16 (131072B), 8 waves
__device__ __forceinline__ void stage256(const u16* __restrict__ g, u16* lds, int w, int l){
  const int drow = l>>5, dch = l&31;
  #pragma unroll
  for (int c=0;c<16;c++){
    int base = (c*8 + w)*2;
    int row = base + drow;
    int gch = (dch&24) | ((dch&7) ^ ((row>>1)&7));
    dma16(g + (long)row*256 + gch*8, &lds[base*256]);
  }
}
// stage 32x256 (16KB), 8 waves
__device__ __forceinline__ void stage32(const u16* __restrict__ g, u16* lds, int w, int l){
  const int drow = l>>5, dch = l&31;
  #pragma unroll
  for (int c=0;c<2;c++){
    int base = (c*8 + w)*2;
    int row = base + drow;
    int gch = (dch&24) | ((dch&7) ^ ((row>>1)&7));
    dma16(g + (long)row*256 + gch*8, &lds[base*256]);
  }
}
// stage 16x256 (8KB), 8 waves (2 rows/wave)
__device__ __forceinline__ void stage16(const u16* __restrict__ g, u16* lds, int w, int l){
  const int drow = l>>5, dch = l&31;
  int row = w*2 + drow;
  int gch = (dch&24) | ((dch&7) ^ ((row>>1)&7));
  dma16(g + (long)row*256 + gch*8, &lds[(w*2)*256]);
}

// preload this wave's 32 B-columns (rows wn0..+31 of bL) across K into regs
__device__ __forceinline__ void loadBf(const u16* bL, int w, int l, s16x8 (&bw)[2][8]){
  const int q=l>>4, ln=l&15, wn0=w*32;
  #pragma unroll
  for (int nt=0;nt<2;nt++)
    #pragma unroll
    for (int kq=0;kq<8;kq++){
      int n = wn0 + nt*16 + ln, ca = kq*4+q;
      bw[nt][kq] = *(const s16x8*)&bL[n*256 + slot8(ca, n)];
    }
}

// acc = A(rows arow0..+31 of aL) @ B(regs), K=256
__device__ __forceinline__ void multAr(const u16* aL, int arow0, const s16x8 (&bw)[2][8],
                                       int l, f32x4 (&acc)[2][2]){
  const int q=l>>4, ln=l&15;
  #pragma unroll
  for (int mt=0;mt<2;mt++)
    #pragma unroll
    for (int nt=0;nt<2;nt++){ acc[mt][nt][0]=0.f; acc[mt][nt][1]=0.f; acc[mt][nt][2]=0.f; acc[mt][nt][3]=0.f; }
  #pragma unroll
  for (int kq=0;kq<8;kq++){
    int ca = kq*4+q;
    s16x8 af[2];
    #pragma unroll
    for (int mt=0;mt<2;mt++){
      int r = arow0 + mt*16 + ln;
      af[mt] = *(const s16x8*)&aL[r*256 + slot8(ca, r)];
    }
    #pragma unroll
    for (int mt=0;mt<2;mt++)
      #pragma unroll
      for (int nt=0;nt<2;nt++)
        acc[mt][nt] = MFMA16(af[mt], bw[nt][kq], acc[mt][nt]);
  }
}

// hacc = H(16 rows of hL) @ B(regs)
__device__ __forceinline__ void multHr(const u16* hL, const s16x8 (&bw)[2][8],
                                       int l, f32x4 (&hacc)[2]){
  const int q=l>>4, ln=l&15;
  hacc[0][0]=0.f; hacc[0][1]=0.f; hacc[0][2]=0.f; hacc[0][3]=0.f;
  hacc[1][0]=0.f; hacc[1][1]=0.f; hacc[1][2]=0.f; hacc[1][3]=0.f;
  #pragma unroll
  for (int kq=0;kq<8;kq++){
    int ca = kq*4+q;
    s16x8 af = *(const s16x8*)&hL[ln*256 + slot8(ca, ln)];
    hacc[0] = MFMA16(af, bw[0][kq], hacc[0]);
    hacc[1] = MFMA16(af, bw[1][kq], hacc[1]);
  }
}

__device__ __forceinline__ void polyinit13(const u16* aL, int arow0, int w, int l, f32x4 (&poly)[2][2]){
  const int q=l>>4, ln=l&15, wn0=w*32;
  #pragma unroll
  for (int mt=0;mt<2;mt++)
  #pragma unroll
  for (int nt=0;nt<2;nt++)
  #pragma unroll
  for (int r=0;r<4;r++){
    int row = arow0 + mt*16 + q*4 + r;
    int col = wn0 + nt*16 + ln;
    poly[mt][nt][r] = 13.f*bf2f(aL[swidx(row,col)]);
  }
}
__device__ __forceinline__ void init13H(const u16* hL, int w, int l, f32x4 (&hpoly)[2]){
  const int q=l>>4, ln=l&15, wn0=w*32;
  #pragma unroll
  for (int nt=0;nt<2;nt++)
  #pragma unroll
  for (int r=0;r<4;r++)
    hpoly[nt][r] = 13.f*bf2f(hL[swidx(q*4+r, wn0+nt*16+ln)]);
}
__device__ __forceinline__ void polyaxpy(f32x4 (&poly)[2][2], const f32x4 (&acc)[2][2], float sc){
  #pragma unroll
  for (int mt=0;mt<2;mt++)
    #pragma unroll
    for (int nt=0;nt<2;nt++)
      #pragma unroll
      for (int r=0;r<4;r++) poly[mt][nt][r] += sc*acc[mt][nt][r];
}
__device__ __forceinline__ void axpyH(f32x4 (&hpoly)[2], const f32x4 (&hacc)[2], float sc){
  #pragma unroll
  for (int nt=0;nt<2;nt++)
    #pragma unroll
    for (int r=0;r<4;r++) hpoly[nt][r] += sc*hacc[nt][r];
}
__device__ __forceinline__ void writeT(u16* Ts, const f32x4 (&acc)[2][2], int w, int l, float sc){
  const int q=l>>4, ln=l&15, wn0=w*32;
  #pragma unroll
  for (int mt=0;mt<2;mt++)
  #pragma unroll
  for (int nt=0;nt<2;nt++)
  #pragma unroll
  for (int r=0;r<4;r++){
    int row = mt*16 + q*4 + r;
    int col = wn0 + nt*16 + ln;
    Ts[swidx(row,col)] = f2bf(sc*acc[mt][nt][r]);
  }
}
__device__ __forceinline__ void writeH(u16* Hs, const f32x4 (&hacc)[2], int w, int l){
  const int q=l>>4, ln=l&15, wn0=w*32;
  #pragma unroll
  for (int nt=0;nt<2;nt++)
  #pragma unroll
  for (int r=0;r<4;r++)
    Hs[swidx(q*4+r, wn0+nt*16+ln)] = f2bf(hacc[nt][r]);
}
__device__ __forceinline__ void epi_poly(u16* __restrict__ out, int rowbase,
                                         const f32x4 (&poly)[2][2], int w, int l, float sc){
  const int q=l>>4, ln=l&15, wn0=w*32;
  #pragma unroll
  for (int mt=0;mt<2;mt++)
  #pragma unroll
  for (int nt=0;nt<2;nt++)
  #pragma unroll
  for (int r=0;r<4;r++){
    int row = rowbase + mt*16 + q*4 + r;
    int col = wn0 + nt*16 + ln;
    out[(long)row*256 + col] = f2bf(sc*poly[mt][nt][r]);
  }
}
__device__ __forceinline__ void epiH(u16* __restrict__ out, const f32x4 (&hpoly)[2],
                                     int w, int l, float sc){
  const int q=l>>4, ln=l&15, wn0=w*32;
  #pragma unroll
  for (int nt=0;nt<2;nt++)
  #pragma unroll
  for (int r=0;r<4;r++)
    out[(long)(q*4+r)*256 + wn0+nt*16+ln] = f2bf(sc*hpoly[nt][r]);
}

// legacy LDS-B mult (kw0 only: single phase, preload is neutral)
__device__ __forceinline__ void mult32(const u16* aL, int arow0, const u16* bL,
                                       int w, int l, f32x4 (&acc)[2][2]){
  const int q=l>>4, ln=l&15, wn0=w*32;
  #pragma unroll
  for (int mt=0;mt<2;mt++)
    #pragma unroll
    for (int nt=0;nt<2;nt++){ acc[mt][nt][0]=0.f; acc[mt][nt][1]=0.f; acc[mt][nt][2]=0.f; acc[mt][nt][3]=0.f; }
  #pragma unroll
  for (int kq=0;kq<8;kq++){
    int ca = kq*4+q;
    s16x8 af[2];
    #pragma unroll
    for (int mt=0;mt<2;mt++){
      int r = arow0 + mt*16 + ln;
      af[mt] = *(const s16x8*)&aL[r*256 + slot8(ca,r)];
    }
    #pragma unroll
    for (int nt=0;nt<2;nt++){
      int n = wn0 + nt*16 + ln;
      s16x8 bfr = *(const s16x8*)&bL[n*256 + slot8(ca,n)];
      acc[0][nt] = MFMA16(af[0], bfr, acc[0][nt]);
      acc[1][nt] = MFMA16(af[1], bfr, acc[1][nt]);
    }
  }
}

// kw0: W0 = s0*X@X^T slab; self-computed s0 from cs_p; slab0 also preps h0
__global__ __launch_bounds__(512)
void kw0(const float* __restrict__ cs_p, float* __restrict__ scal,
         const float* __restrict__ num_p, const float* __restrict__ den_p,
         const u16* __restrict__ X, u16* __restrict__ W0, u16* __restrict__ h0)
{
  __shared__ __align__(16) u16 Wf[65536];
  __shared__ __align__(16) u16 Ts[8192];
  const int tid=threadIdx.x, w=tid>>6, l=tid&63;
  const int bid=blockIdx.x, xcd=bid&7, j=bid>>3;
  const int batch = xcd*4 + (j>>3), slab = j&7;

  stage256(X + (long)batch*65536, Wf, w, l);   // dma in flight during reduce

  float* red = (float*)Ts;
  float mx = 0.f;
  for (int i=tid;i<8192;i+=512){
    float s = 0.f;
    #pragma unroll
    for (int c=0;c<8;c++) s += cs_p[(long)c*8192 + i];
    mx = fmaxf(mx, s);
  }
  red[tid] = mx; __syncthreads();
  for (int s=256;s>0;s>>=1){ if (tid<s) red[tid] = fmaxf(red[tid], red[tid+s]); __syncthreads(); }
  float s0 = 1.0f/red[0];
  if (bid==0 && tid==0) scal[0] = s0;

  f32x4 acc[2][2];
  mult32(Wf, slab*32, Wf, w, l, acc);
  {
    const int q=l>>4, ln=l&15, wn0=w*32;
    u16* ob = W0 + (long)batch*65536;
    #pragma unroll
    for (int mt=0;mt<2;mt++)
    #pragma unroll
    for (int nt=0;nt<2;nt++)
    #pragma unroll
    for (int r=0;r<4;r++){
      int row = slab*32 + mt*16 + q*4 + r;
      int col = wn0 + nt*16 + ln;
      ob[(long)row*256 + col] = f2bf(acc[mt][nt][r]*s0);
    }
  }

  if (slab==0){
    __syncthreads();
    float (*lt)[257] = (float(*)[257])Wf;
    for (int i=tid;i<8192;i+=512){
      int m = i>>5, d = i&31;
      float sn = 0.f, sd = 0.f;
      #pragma unroll
      for (int c=0;c<8;c++){
        sn += num_p[((long)(c*32+batch))*8192 + i];
        sd += den_p[(c*32+batch)*256 + m];
      }
      lt[d][m] = sn/sd;
    }
    __syncthreads();
    u16* o = h0 + (long)batch*8192;
    for (int j2=tid;j2<8192;j2+=512){
      int d = j2>>8, m = j2&255;
      o[j2] = f2bf(lt[d][m]);
    }
  }
}

// kiter: one Newton iteration. 256 blocks x 512 thr; slab0/slab4 advance h halves.
__global__ __launch_bounds__(512)
void kiter(const u16* __restrict__ Win, u16* __restrict__ Wout,
           const u16* __restrict__ hin, u16* __restrict__ hout)
{
  __shared__ __align__(16) u16 Wf[65536];
  __shared__ __align__(16) u16 Ts[8192];
  __shared__ __align__(16) u16 Hs[4096];
  const int tid=threadIdx.x, w=tid>>6, l=tid&63;
  const int bid=blockIdx.x, xcd=bid&7, j=bid>>3;
  const int batch = xcd*4 + (j>>3), slab = j&7;
  const bool hrole = (slab&3)==0;              // slabs 0 and 4
  const int hr0 = (slab>>2)*16;

  stage256(Win + (long)batch*65536, Wf, w, l);
  if (hrole) stage16(hin + (long)batch*8192 + hr0*256, Hs, w, l);
  __syncthreads();

  s16x8 bw[2][8];
  loadBf(Wf, w, l, bw);

  f32x4 acc[2][2], poly[2][2];
  f32x4 hacc[2], hpoly[2];

  polyinit13(Wf, slab*32, w, l, poly);
  multAr(Wf, slab*32, bw, l, acc);             // t1 = Wslab@W
  polyaxpy(poly, acc, -15.f);
  if (hrole){
    init13H(Hs, w, l, hpoly);
    multHr(Hs, bw, l, hacc);                   // h@W
    axpyH(hpoly, hacc, -15.f);
  }
  __syncthreads();
  writeT(Ts, acc, w, l, 1.f);
  if (hrole) writeH(Hs, hacc, w, l);
  __syncthreads();
  multAr(Ts, 0, bw, l, acc);                   // t2
  polyaxpy(poly, acc, 7.f);
  if (hrole){ multHr(Hs, bw, l, hacc); axpyH(hpoly, hacc, 7.f); }
  __syncthreads();
  writeT(Ts, acc, w, l, 1.f);
  if (hrole) writeH(Hs, hacc, w, l);
  __syncthreads();
  multAr(Ts, 0, bw, l, acc);                   // t3
  polyaxpy(poly, acc, -1.f);
  epi_poly(Wout + (long)batch*65536, slab*32, poly, w, l, 0.25f);
  if (hrole){
    multHr(Hs, bw, l, hacc);
    axpyH(hpoly, hacc, -1.f);
    epiH(hout + (long)batch*8192 + hr0*256, hpoly, w, l, 0.25f);
  }
}

// ktail: g1 chain in-LDS (reg-B), then u = s0*g1@X (via XT restage)
__global__ __launch_bounds__(512)
void ktail(const u16* __restrict__ W5, const u16* __restrict__ h5,
           const u16* __restrict__ XT, const float* __restrict__ scal,
           u16* __restrict__ uT)
{
  __shared__ __align__(16) u16 Wf[65536];
  __shared__ __align__(16) u16 Ts[8192];
  const int tid=threadIdx.x, w=tid>>6, l=tid&63;
  const int batch = blockIdx.x;

  stage256(W5 + (long)batch*65536, Wf, w, l);
  stage32(h5 + (long)batch*8192, Ts, w, l);
  __syncthreads();

  s16x8 bw[2][8];
  loadBf(Wf, w, l, bw);

  f32x4 acc[2][2], poly[2][2];
  polyinit13(Ts, 0, w, l, poly);
  multAr(Ts, 0, bw, l, acc);                   // a = h5@W5
  polyaxpy(poly, acc, -15.f);
  __syncthreads(); writeT(Ts, acc, w, l, 1.f); __syncthreads();
  multAr(Ts, 0, bw, l, acc);                   // b
  polyaxpy(poly, acc, 7.f);
  __syncthreads(); writeT(Ts, acc, w, l, 1.f); __syncthreads();
  multAr(Ts, 0, bw, l, acc);                   // c
  polyaxpy(poly, acc, -1.f);
  __syncthreads();
  writeT(Ts, poly, w, l, 0.25f);               // g1 -> Ts
  stage256(XT + (long)batch*65536, Wf, w, l);  // X^T over W5
  __syncthreads();
  loadBf(Wf, w, l, bw);
  multAr(Ts, 0, bw, l, acc);                   // u = g1@X
  const float s0 = scal[0];
  {
    const int q=l>>4, ln=l&15, wn0=w*32;
    u16* ob = uT + (long)batch*8192;
    #pragma unroll
    for (int mt=0;mt<2;mt++)
    #pragma unroll
    for (int nt=0;nt<2;nt++)
    #pragma unroll
    for (int r=0;r<4;r++){
      int row = mt*16 + q*4 + r;
      int col = wn0 + nt*16 + ln;
      ob[(long)row*256 + col] = f2bf(acc[mt][nt][r]*s0);
    }
  }
}

// ---------------------------------------------------------------------------
// Merged attn2 + attn3v (independent; grid (16,32): x<8 attn2, x>=8 attn3v)
// ---------------------------------------------------------------------------
__global__ __launch_bounds__(256)
void kattn23(const u16* __restrict__ ql, const u16* __restrict__ kl,
             u16* __restrict__ X, u16* __restrict__ XT, float* __restrict__ cs_p,
             const u16* __restrict__ kk, const u16* __restrict__ vv,
             float* __restrict__ num_p, float* __restrict__ den_p)
{
  __shared__ __align__(16) u16 Pbuf[4][64][40];
  __shared__ __align__(16) u16 vT[32][40];
  __shared__ float qrow[32][33];
  __shared__ float psum[32][4];
  __shared__ float rsum[32];
  int bh = blockIdx.y;
  int tid = threadIdx.x, w = tid>>6, l = tid&63, q = l>>4, ln = l&15;

  if (blockIdx.x < 8){
    int r0 = blockIdx.x*32;
    int c = tid;
    #pragma unroll
    for (int i=0;i<4;i++){
      int e = c*4+i; int rr = e>>5, dd = e&31;
      qrow[rr][dd] = bf2f(ql[((long)bh*256 + r0+rr)*32 + dd]);
    }
    float kc[32];
    {
      const u16* kp = kl + ((long)bh*256 + c)*32;
      #pragma unroll
      for (int d=0;d<32;d++) kc[d] = bf2f(kp[d]);
    }
    __syncthreads();
    float er[32]; float colacc = 0.f;
    for (int r=0;r<32;r++){
      float s = 0.f;
      #pragma unroll
      for (int d=0;d<32;d++) s += qrow[r][d]*kc[d];
      float e = __expf(s);
      er[r] = e;
      float wsum = e;
      #pragma unroll
      for (int m=1;m<64;m<<=1) wsum += __shfl_xor(wsum, m);
      if (l==0) psum[r][w] = wsum;
    }
    __syncthreads();
    if (c<32) rsum[c] = psum[c][0]+psum[c][1]+psum[c][2]+psum[c][3];
    __syncthreads();
    for (int r=0;r<32;r++){
      float x = er[r]/rsum[r];
      u16 xb = f2bf(x);
      X [((long)bh*256 + r0+r)*256 + c] = xb;
      XT[((long)bh*256 + c)*256 + r0+r] = xb;
      colacc += x;
    }
    cs_p[(long)blockIdx.x*8192 + bh*256 + c] = colacc;
    return;
  }

  int chunk = blockIdx.x - 8;
  f32x4 z4; z4[0]=0.f; z4[1]=0.f; z4[2]=0.f; z4[3]=0.f;
  f32x4 acc[4][2]; f32x4 dacc[4];
  #pragma unroll
  for (int mt=0;mt<4;mt++){ dacc[mt]=z4; acc[mt][0]=z4; acc[mt][1]=z4; }
  const u16* qlb = ql + (long)bh*8192;
  const u16* kb  = kk + (long)bh*131072;
  const u16* vb  = vv + (long)bh*131072;
  int vn = tid>>3, vd = (tid&7)*4;
  for (int s=0;s<16;s++){
    int n0 = chunk*512 + s*32;
    ushort4 vx = *(const ushort4*)(vb + (long)(n0+vn)*32 + vd);
    vT[vd+0][vn]=vx.x; vT[vd+1][vn]=vx.y; vT[vd+2][vn]=vx.z; vT[vd+3][vn]=vx.w;
    __syncthreads();
    s16x8 bk[2];
    #pragma unroll
    for (int nt=0;nt<2;nt++) bk[nt] = *(const s16x8*)(kb + (long)(n0 + nt*16 + ln)*32 + q*8);
    #pragma unroll
    for (int mt=0;mt<4;mt++){
      s16x8 aq = *(const s16x8*)(qlb + (long)(w*64 + mt*16 + ln)*32 + q*8);
      #pragma unroll
      for (int nt=0;nt<2;nt++){
        f32x4 sf = MFMA16(aq, bk[nt], z4);
        f32x4 ef;
        #pragma unroll
        for (int r=0;r<4;r++) ef[r] = __expf(sf[r]);
        dacc[mt] += ef;
        #pragma unroll
        for (int r=0;r<4;r++) Pbuf[w][mt*16 + q*4 + r][nt*16 + ln] = f2bf(ef[r]);
      }
    }
    #pragma unroll
    for (int mt=0;mt<4;mt++){
      s16x8 ap = *(const s16x8*)&Pbuf[w][mt*16 + ln][q*8];
      #pragma unroll
      for (int nt=0;nt<2;nt++){
        s16x8 bv = *(const s16x8*)&vT[nt*16 + ln][q*8];
        acc[mt][nt] = MFMA16(ap, bv, acc[mt][nt]);
      }
    }
    __syncthreads();
  }
  #pragma unroll
  for (int mt=0;mt<4;mt++)
    #pragma unroll
    for (int r=0;r<4;r++){
      float x = dacc[mt][r];
      x += __shfl_xor(x,1); x += __shfl_xor(x,2); x += __shfl_xor(x,4); x += __shfl_xor(x,8);
      dacc[mt][r] = x;
    }
  long pbase = (long)(chunk*32 + bh);
  #pragma unroll
  for (int mt=0;mt<4;mt++)
    #pragma unroll
    for (int nt=0;nt<2;nt++)
      #pragma unroll
      for (int r=0;r<4;r++){
        int mg = w*64 + mt*16 + q*4 + r;
        num_p[pbase*8192 + (long)mg*32 + nt*16 + ln] = acc[mt][nt][r];
      }
  if (ln==0){
    #pragma unroll
    for (int mt=0;mt<4;mt++)
      #pragma unroll
      for (int r=0;r<4;r++)
        den_p[pbase*256 + w*64 + mt*16 + q*4 + r] = dacc[mt][r];
  }
}

// ---------------------------------------------------------------------------
// attn1 fused + depthwise residual conv
// ---------------------------------------------------------------------------
__global__ __launch_bounds__(256)
void kattn1u(const u16* __restrict__ qq, const u16* __restrict__ kl, const u16* __restrict__ uT,
             const u16* __restrict__ vv, const float* __restrict__ rw,
             u16* __restrict__ aoutb)
{
  int nch = blockIdx.x, bh = blockIdx.y;
  int b = bh>>3, h = bh&7;
  int tid = threadIdx.x, w = tid>>6, l = tid&63, q = l>>4, ln = l&15;
  __shared__ __align__(16) u16 Pbuf[4][32][40];
  __shared__ __align__(16) u16 vtile[160][36];
  int r0g = nch*128;
  const u16* vb = vv + (long)bh*131072;
  #pragma unroll
  for (int it=0; it<5; it++){
    int slot = tid + it*256;
    int rr = slot>>3, c = (slot&7)*4;
    int s = r0g - 16 + rr;
    ushort4 val; val.x=0; val.y=0; val.z=0; val.w=0;
    if (s>=0 && s<4096) val = *(const ushort4*)(vb + (long)s*32 + c);
    *(ushort4*)&vtile[rr][c] = val;
  }
  __syncthreads();

  f32x4 z4; z4[0]=0.f; z4[1]=0.f; z4[2]=0.f; z4[3]=0.f;
  f32x4 acc[2][2]; f32x4 dacc[2];
  #pragma unroll
  for (int mt=0;mt<2;mt++){ dacc[mt]=z4; acc[mt][0]=z4; acc[mt][1]=z4; }
  const u16* qb  = qq + (long)bh*131072;
  const u16* klb = kl + (long)bh*8192;
  const u16* ub  = uT + (long)bh*8192;
  int r0 = r0g + w*32;
  for (int s=0;s<8;s++){
    s16x8 bk[2];
    #pragma unroll
    for (int nt=0;nt<2;nt++) bk[nt] = *(const s16x8*)(klb + (long)(s*32 + nt*16 + ln)*32 + q*8);
    #pragma unroll
    for (int mt=0;mt<2;mt++){
      s16x8 aq = *(const s16x8*)(qb + (long)(r0 + mt*16 + ln)*32 + q*8);
      #pragma unroll
      for (int nt=0;nt<2;nt++){
        f32x4 sf = MFMA16(aq, bk[nt], z4);
        f32x4 ef;
        #pragma unroll
        for (int r=0;r<4;r++) ef[r] = __expf(sf[r]);
        dacc[mt] += ef;
        #pragma unroll
        for (int r=0;r<4;r++) Pbuf[w][mt*16 + q*4 + r][nt*16 + ln] = f2bf(ef[r]);
      }
    }
    #pragma unroll
    for (int mt=0;mt<2;mt++){
      s16x8 ap = *(const s16x8*)&Pbuf[w][mt*16 + ln][q*8];
      #pragma unroll
      for (int nt=0;nt<2;nt++){
        s16x8 bu = *(const s16x8*)(ub + (long)(nt*16 + ln)*256 + s*32 + q*8);
        acc[mt][nt] = MFMA16(ap, bu, acc[mt][nt]);
      }
    }
  }
  #pragma unroll
  for (int mt=0;mt<2;mt++)
    #pragma unroll
    for (int r=0;r<4;r++){
      float x = dacc[mt][r];
      x += __shfl_xor(x,1); x += __shfl_xor(x,2); x += __shfl_xor(x,4); x += __shfl_xor(x,8);
      dacc[mt][r] = x;
    }

  const float* wp = rw + h*33;
  float w_[33];
  #pragma unroll
  for (int j=0;j<33;j++) w_[j] = wp[j];

  #pragma unroll
  for (int mt=0;mt<2;mt++){
    int nl = w*32 + mt*16 + q*4;
    #pragma unroll
    for (int nt=0;nt<2;nt++){
      int d = nt*16 + ln;
      float vvv[36];
      #pragma unroll
      for (int j=0;j<36;j++) vvv[j] = bf2f(vtile[nl + j][d]);
      #pragma unroll
      for (int r=0;r<4;r++){
        float cv = 0.f;
        #pragma unroll
        for (int j=0;j<33;j++) cv += w_[j]*vvv[r+j];
        int n = r0 + mt*16 + q*4 + r;
        long oidx = ((long)b*4096 + n)*256 + h*32 + d;
        aoutb[oidx] = f2bf(acc[mt][nt][r]/dacc[mt][r] + cv);
      }
    }
  }
}

// ---------------------------------------------------------------------------
// Merged: LN(x) (blocks 0..4095) + weight transpose/cast (blocks 4096..5119)
// ---------------------------------------------------------------------------
__global__ __launch_bounds__(256)
void kcvtln(const float* __restrict__ xin, const float* __restrict__ lg, const float* __restrict__ lb,
            u16* __restrict__ xn,
            const float* __restrict__ wqkv, const float* __restrict__ wout,
            const float* __restrict__ w1, const float* __restrict__ w2,
            u16* __restrict__ wqkvT, u16* __restrict__ woutT,
            u16* __restrict__ w1T, u16* __restrict__ w2T)
{
  __shared__ float t[32][33];
  int z = blockIdx.x;
  if (z < 4096){
    int w = threadIdx.x>>6, l = threadIdx.x&63;
    long row = (long)z*4 + w;
    float4 v = ((const float4*)(xin + row*256))[l];
    float s = v.x+v.y+v.z+v.w;
    #pragma unroll
    for (int m=1;m<64;m<<=1) s += __shfl_xor(s, m);
    float mu = s*(1.0f/256.0f);
    float dx=v.x-mu, dy=v.y-mu, dz=v.z-mu, dw=v.w-mu;
    float s2 = dx*dx+dy*dy+dz*dz+dw*dw;
    #pragma unroll
    for (int m=1;m<64;m<<=1) s2 += __shfl_xor(s2, m);
    float rs = rsqrtf(s2*(1.0f/256.0f) + 1e-5f);
    float4 gg = ((const float4*)lg)[l];
    float4 bb = ((const float4*)lb)[l];
    ushort4 o;
    o.x = f2bf(dx*rs*gg.x + bb.x);
    o.y = f2bf(dy*rs*gg.y + bb.y);
    o.z = f2bf(dz*rs*gg.z + bb.z);
    o.w = f2bf(dw*rs*gg.w + bb.w);
    *(ushort4*)(xn + row*256 + l*4) = o;
    return;
  }
  z -= 4096;
  const float* src; u16* dst; int K, Nn, bx, by;
  if (z < 384){      int i=z/192, r=z%192; src=wqkv+(long)i*196608; dst=wqkvT+(long)i*196608; K=256; Nn=768; bx=r%24; by=r/24; }
  else if (z < 512){ int zz=z-384; int i=zz/64, r=zz%64; src=wout+(long)i*65536; dst=woutT+(long)i*65536; K=256; Nn=256; bx=r%8; by=r/8; }
  else if (z < 768){ int zz=z-512; int i=zz/128, r=zz%128; src=w1+(long)i*131072; dst=w1T+(long)i*131072; K=256; Nn=512; bx=r%16; by=r/16; }
  else {             int zz=z-768; int i=zz/128, r=zz%128; src=w2+(long)i*131072; dst=w2T+(long)i*131072; K=512; Nn=256; bx=r%8; by=r/8; }
  int n0 = bx*32, k0 = by*32;
  int tx = threadIdx.x&31, ty = threadIdx.x>>5;
  #pragma unroll
  for (int i=0;i<4;i++) t[ty+i*8][tx] = src[(long)(k0+ty+i*8)*Nn + n0+tx];
  __syncthreads();
  #pragma unroll
  for (int i=0;i<4;i++) dst[(long)(n0+ty+i*8)*K + k0+tx] = f2bf(t[tx][ty+i*8]);
}

// ---------------------------------------------------------------------------
extern "C" void kernel_launch(void* const* d_in, const int* in_sizes, int n_in,
                              void* d_out, int out_size, void* d_ws, size_t ws_size,
                              hipStream_t stream)
{
  const float* x    = (const float*)d_in[0];
  const float* ln1g = (const float*)d_in[1];
  const float* ln1b = (const float*)d_in[2];
  const float* wqkv = (const float*)d_in[3];
  const float* wout = (const float*)d_in[4];
  const float* bout = (const float*)d_in[5];
  const float* resw = (const float*)d_in[6];
  const float* ln2g = (const float*)d_in[7];
  const float* ln2b = (const float*)d_in[8];
  const float* w1   = (const float*)d_in[9];
  const float* b1   = (const float*)d_in[10];
  const float* w2   = (const float*)d_in[11];
  const float* b2   = (const float*)d_in[12];
  float* y = (float*)d_out;
  char* ws = (char*)d_ws;

  u16* xn    = (u16*)(ws + 0);
  u16* qb    = (u16*)(ws + 8388608);
  u16* kb    = (u16*)(ws + 16777216);
  u16* vb    = (u16*)(ws + 25165824);
  u16* ql    = (u16*)(ws + 33554432);
  u16* kl    = (u16*)(ws + 34078720);
  u16* X     = (u16*)(ws + 34603008);
  u16* XT    = (u16*)(ws + 38797312);     // X^T (B-operand of final U GEMM)
  u16* h0b   = (u16*)(ws + 42991616);     // h0 [32][32][256] bf16 (512 KB)
  // pinv work region
  u16* WA    = (u16*)(ws + 51380224);
  u16* WB    = (u16*)(ws + 55574528);
  u16* hA    = (u16*)(ws + 68157440);     // thin h buffers [32][32][256]
  u16* hB    = (u16*)(ws + 72351744);
  float* num_p = (float*)(ws + 76546048);  // 8 MB
  float* den_p = (float*)(ws + 84934656);
  float* cs_p  = (float*)(ws + 85196800);
  float* scal  = (float*)(ws + 85458944);
  u16* uT    = (u16*)(ws + 85459200);
  u16* aoutb = (u16*)(ws + 85983488);
  u16* wqkvT = (u16*)(ws + 94372096);
  u16* woutT = (u16*)(ws + 95158528);
  u16* w1T   = (u16*)(ws + 95420672);
  u16* w2T   = (u16*)(ws + 95944960);
  u16* hdn   = (u16*)(ws + 51380224);      // overlays WA/WB (dead by FFN)

  (void)in_sizes; (void)n_in; (void)out_size; (void)ws_size;

  // LN(x) + weight cvt in one launch
  kcvtln<<<5120,256,0,stream>>>(x, ln1g, ln1b, xn,
      wqkv, wout, w1, w2, wqkvT, woutT, w1T, w2T);

  for (int i=0;i<2;i++){
    // xn: i==0 from kcvtln; i==1 from previous FFN2's fused LN epilogue
    kgemm2<EPI_QKV><<<dim3(128,6),256,0,stream>>>(xn, wqkvT + (long)i*196608, 256, 256, 256,
        nullptr, nullptr, 0, qb,kb,vb, ql,kl);
    kattn23<<<dim3(16,32),256,0,stream>>>(ql, kl, X, XT, cs_p, kb, vb, num_p, den_p);

    // ---- pinv: kw0 (scal + W0 + h0) -> 5x kiter -> ktail (g1 chain + U) ----
    kw0<<<256,512,0,stream>>>(cs_p, scal, num_p, den_p, X, WA, h0b);
    u16 *Wi = WA, *Wo = WB, *hi = h0b, *ho = hA;
    for (int it=0; it<5; it++){
      kiter<<<256,512,0,stream>>>(Wi, Wo, hi, ho);
      u16* t = Wi; Wi = Wo; Wo = t;
      hi = ho; ho = (ho == hA) ? hB : hA;
    }
    ktail<<<32,512,0,stream>>>(Wi, hi, XT, scal, uT);

    kattn1u<<<dim3(32,32),256,0,stream>>>(qb, kl, uT, vb, resw + i*264, aoutb);
    // wout GEMM + residual + LN2 fused -> y (f32) + xn (bf16 for FFN1)
    kgemmLN<<<256,256,0,stream>>>(aoutb, woutT + (long)i*65536, 256,
        bout + i*256, i==0 ? x : y, y, ln2g + i*256, ln2b + i*256, xn);
    kgemm2<EPI_BIAS_GELU><<<dim3(128,4),256,0,stream>>>(xn, w1T + (long)i*131072, 256, 256, 256,
        b1 + i*512, hdn, 512, nullptr,nullptr,nullptr, nullptr,nullptr);
    // FFN2 GEMM + residual + LN1(next) fused -> y + xn (for next QKV; dead on i==1)
    kgemmLN<<<256,256,0,stream>>>(hdn, w2T + (long)i*131072, 512,
        b2 + i*256, y, y, ln1g + 256, ln1b + 256, xn);
  }
}

// Round 9
// 493.308 us; speedup vs baseline: 1.2588x; 1.0136x over previous
//
#include <hip/hip_runtime.h>
#include <math.h>

typedef float f32x4 __attribute__((ext_vector_type(4)));
typedef short s16x8 __attribute__((ext_vector_type(8)));
typedef unsigned short u16;
typedef unsigned int u32;

#define MFMA16(a,b,c) __builtin_amdgcn_mfma_f32_16x16x32_bf16((a),(b),(c),0,0,0)
#define AS1 __attribute__((address_space(1)))
#define AS3 __attribute__((address_space(3)))

__device__ __forceinline__ void dma16(const u16* g, u16* l){
  __builtin_amdgcn_global_load_lds((const AS1 u32*)g, (AS3 u32*)l, 16, 0, 0);
}

__device__ __forceinline__ float bf2f(u16 u){
  union { unsigned int i; float f; } v; v.i = ((unsigned int)u)<<16; return v.f;
}
__device__ __forceinline__ u16 f2bf(float f){
  union { float f; unsigned int i; } v; v.f = f;
  unsigned int x = v.i;
  return (u16)((x + 0x7fffu + ((x>>16)&1u))>>16);
}

enum { EPI_QKV=0, EPI_BIAS_GELU=3 };

// ---------------------------------------------------------------------------
// kgemm2: BM=128, BN=128, BK=32, 4x4 frags/wave; DMA staging + swizzle.
// ---------------------------------------------------------------------------
template<int EPI>
__global__ __launch_bounds__(256)
void kgemm2(const u16* __restrict__ A, const u16* __restrict__ BT, int K, int lda, int ldb,
            const float* __restrict__ bias, u16* __restrict__ outb, int ldc,
            u16* __restrict__ qo, u16* __restrict__ ko, u16* __restrict__ vo,
            u16* __restrict__ qlm, u16* __restrict__ klm)
{
  __shared__ __align__(16) u16 As[128*32];
  __shared__ __align__(16) u16 Bs[128*32];
  const int tid = threadIdx.x;
  const int w = tid>>6, wy = w>>1, wx = w&1, l = tid&63, q = l>>4, ln = l&15;
  const int m0 = blockIdx.x*128, n0 = blockIdx.y*128;
  const int lrow = l>>2, lch = l&3;

  f32x4 acc[4][4];
  #pragma unroll
  for (int i=0;i<4;i++)
    #pragma unroll
    for (int j=0;j<4;j++){ acc[i][j][0]=0.f; acc[i][j][1]=0.f; acc[i][j][2]=0.f; acc[i][j][3]=0.f; }

  for (int k0=0; k0<K; k0+=32){
    #pragma unroll
    for (int c=0;c<2;c++){
      int row = 32*w + 16*c + lrow;
      int gch = lch ^ ((row>>1)&3);
      dma16(A + (long)(m0+row)*lda + k0 + gch*8, &As[(32*w+16*c)*32]);
      dma16(BT + (long)(n0+row)*ldb + k0 + gch*8, &Bs[(32*w+16*c)*32]);
    }
    __syncthreads();
    s16x8 af[4], bfr[4];
    #pragma unroll
    for (int mt=0;mt<4;mt++){
      int row = wy*64 + mt*16 + ln;
      af[mt] = *(const s16x8*)&As[row*32 + ((q ^ ((row>>1)&3))<<3)];
    }
    #pragma unroll
    for (int nt=0;nt<4;nt++){
      int row = wx*64 + nt*16 + ln;
      bfr[nt] = *(const s16x8*)&Bs[row*32 + ((q ^ ((row>>1)&3))<<3)];
    }
    #pragma unroll
    for (int mt=0;mt<4;mt++)
      #pragma unroll
      for (int nt=0;nt<4;nt++)
        acc[mt][nt] = MFMA16(af[mt], bfr[nt], acc[mt][nt]);
    __syncthreads();
  }

  #pragma unroll
  for (int mt=0;mt<4;mt++)
  #pragma unroll
  for (int nt=0;nt<4;nt++){
    int ncol = n0 + wx*64 + nt*16 + ln;
    if (EPI==EPI_QKV){
      int sel = ncol>>8, hd = ncol&255, h = hd>>5, d = hd&31;
      u16* dst = sel==0 ? qo : (sel==1 ? ko : vo);
      float sc2 = (sel==0) ? 0.17677669529663689f : 1.f;   // dh^-0.5 on q
      float s = 0.f;
      #pragma unroll
      for (int r=0;r<4;r++){
        int mrow = m0 + wy*64 + mt*16 + q*4 + r;
        int b = mrow>>12, n = mrow&4095;
        float v = acc[mt][nt][r]*sc2;
        dst[(((long)(b*8+h)*4096 + n)<<5) + d] = f2bf(v);
        s += v;
      }
      if (sel < 2){
        s += __shfl_xor(s, 16);
        s += __shfl_xor(s, 32);
        if (q == 0){
          int mrow0 = m0 + wy*64 + mt*16;
          int b = mrow0>>12, grp = (mrow0&4095)>>4;
          u16* ldst = (sel==0) ? qlm : klm;
          ldst[(((long)(b*8+h)*256 + grp)<<5) + d] = f2bf(s*(1.0f/16.0f));
        }
      }
    } else { // EPI_BIAS_GELU
      #pragma unroll
      for (int r=0;r<4;r++){
        int mrow = m0 + wy*64 + mt*16 + q*4 + r;
        float x = acc[mt][nt][r] + bias[ncol];
        float g = 0.5f*x*(1.0f + erff(x*0.70710678118654752f));
        outb[(long)mrow*ldc + ncol] = f2bf(g);
      }
    }
  }
}

// ---------------------------------------------------------------------------
// kgemmLN: BM=64, BN=256 (full rows per block, 256 blocks = full GPU),
// 4x4 frags/wave; residual+bias, then in-register LayerNorm with cross-wave
// combine -> writes y (f32) AND xn=LN(y) (bf16).
// ---------------------------------------------------------------------------
__global__ __launch_bounds__(256)
void kgemmLN(const u16* __restrict__ A, const u16* __restrict__ BT, int K,
             const float* __restrict__ bias, const float* __restrict__ base,
             float* __restrict__ yout,
             const float* __restrict__ lng, const float* __restrict__ lnb,
             u16* __restrict__ xnout)
{
  __shared__ __align__(16) u16 As[64*32];
  __shared__ __align__(16) u16 Bs[256*32];
  __shared__ float red[64][4];
  const int tid = threadIdx.x;
  const int w = tid>>6, l = tid&63, q = l>>4, ln = l&15;
  const int m0 = blockIdx.x*64;

  f32x4 acc[4][4];   // row = mt*16+q*4+r, col = w*64+nt*16+ln
  #pragma unroll
  for (int i=0;i<4;i++)
    #pragma unroll
    for (int j=0;j<4;j++){ acc[i][j][0]=0.f; acc[i][j][1]=0.f; acc[i][j][2]=0.f; acc[i][j][3]=0.f; }

  for (int k0=0; k0<K; k0+=32){
    {
      int row = w*16 + (l>>2);
      int gch = (l&3) ^ ((row>>1)&3);
      dma16(A + (long)(m0+row)*K + k0 + gch*8, &As[(w*16)*32]);
    }
    #pragma unroll
    for (int c=0;c<4;c++){
      int row = c*64 + w*16 + (l>>2);
      int gch = (l&3) ^ ((row>>1)&3);
      dma16(BT + (long)row*K + k0 + gch*8, &Bs[(c*64+w*16)*32]);
    }
    __syncthreads();
    s16x8 af[4], bfr[4];
    #pragma unroll
    for (int mt=0;mt<4;mt++){
      int row = mt*16 + ln;
      af[mt] = *(const s16x8*)&As[row*32 + ((q ^ ((row>>1)&3))<<3)];
    }
    #pragma unroll
    for (int nt=0;nt<4;nt++){
      int row = w*64 + nt*16 + ln;
      bfr[nt] = *(const s16x8*)&Bs[row*32 + ((q ^ ((row>>1)&3))<<3)];
    }
    #pragma unroll
    for (int mt=0;mt<4;mt++)
      #pragma unroll
      for (int nt=0;nt<4;nt++)
        acc[mt][nt] = MFMA16(af[mt], bfr[nt], acc[mt][nt]);
    __syncthreads();
  }

  // residual + bias, write y
  float rb[4];
  #pragma unroll
  for (int nt=0;nt<4;nt++) rb[nt] = bias[w*64 + nt*16 + ln];
  #pragma unroll
  for (int mt=0;mt<4;mt++)
  #pragma unroll
  for (int r=0;r<4;r++){
    long rowb = (long)(m0 + mt*16 + q*4 + r)*256;
    #pragma unroll
    for (int nt=0;nt<4;nt++){
      int col = w*64 + nt*16 + ln;
      float v = base[rowb + col] + acc[mt][nt][r] + rb[nt];
      acc[mt][nt][r] = v;
      yout[rowb + col] = v;
    }
  }
  // mean: per-lane over 4 nt, 16-lane shuffle, cross-wave via red
  #pragma unroll
  for (int mt=0;mt<4;mt++)
  #pragma unroll
  for (int r=0;r<4;r++){
    float s = acc[mt][0][r]+acc[mt][1][r]+acc[mt][2][r]+acc[mt][3][r];
    s += __shfl_xor(s,1); s += __shfl_xor(s,2); s += __shfl_xor(s,4); s += __shfl_xor(s,8);
    if (ln==0) red[mt*16+q*4+r][w] = s;
  }
  __syncthreads();
  float mu[4][4];
  #pragma unroll
  for (int mt=0;mt<4;mt++)
  #pragma unroll
  for (int r=0;r<4;r++){
    int row = mt*16+q*4+r;
    mu[mt][r] = (red[row][0]+red[row][1]+red[row][2]+red[row][3])*(1.0f/256.0f);
  }
  __syncthreads();
  #pragma unroll
  for (int mt=0;mt<4;mt++)
  #pragma unroll
  for (int r=0;r<4;r++){
    float vs = 0.f;
    #pragma unroll
    for (int nt=0;nt<4;nt++){ float d = acc[mt][nt][r]-mu[mt][r]; vs += d*d; }
    vs += __shfl_xor(vs,1); vs += __shfl_xor(vs,2); vs += __shfl_xor(vs,4); vs += __shfl_xor(vs,8);
    if (ln==0) red[mt*16+q*4+r][w] = vs;
  }
  __syncthreads();
  float rg[4], rbb[4];
  #pragma unroll
  for (int nt=0;nt<4;nt++){ int col = w*64+nt*16+ln; rg[nt]=lng[col]; rbb[nt]=lnb[col]; }
  #pragma unroll
  for (int mt=0;mt<4;mt++)
  #pragma unroll
  for (int r=0;r<4;r++){
    int row = mt*16+q*4+r;
    float rs = rsqrtf((red[row][0]+red[row][1]+red[row][2]+red[row][3])*(1.0f/256.0f) + 1e-5f);
    long rowb = (long)(m0 + row)*256;
    #pragma unroll
    for (int nt=0;nt<4;nt++){
      int col = w*64 + nt*16 + ln;
      float d = acc[mt][nt][r]-mu[mt][r];
      xnout[rowb + col] = f2bf(d*rs*rg[nt] + rbb[nt]);
    }
  }
}

// ---------------------------------------------------------------------------
// Fused pinv: full 256x256 W resident in LDS + reg-cached B frags.
// 512 threads (8 waves). W' = 0.25(13W -15W^2 +7W^3 -W^4) per 32-row slab;
// h rows split across slab0 (rows 0-15) and slab4 (rows 16-31).
// Iteration 5's W-update is dead (tail re-expressed via W4), so the last
// iteration + tail fuse into ktail2.
// ---------------------------------------------------------------------------
__device__ __forceinline__ int swidx(int row, int col){
  int cc = col>>3;
  int sl = (cc&24)|((cc&7)^((row>>1)&7));
  return row*256 + sl*8 + (col&7);
}
__device__ __forceinline__ int slot8(int ca, int row){
  return ((ca&24)|((ca&7)^((row>>1)&7)))<<3;
}

// stage 256x256 bf16 (131072B), 8 waves
__device__ __forceinline__ void stage256(const u16* __restrict__ g, u16* lds, int w, int l){
  const int drow = l>>5, dch = l&31;
  #pragma unroll
  for (int c=0;c<16;c++){
    int base = (c*8 + w)*2;
    int row = base + drow;
    int gch = (dch&24) | ((dch&7) ^ ((row>>1)&7));
    dma16(g + (long)row*256 + gch*8, &lds[base*256]);
  }
}
// stage 16x256 (8KB), 8 waves (2 rows/wave)
__device__ __forceinline__ void stage16(const u16* __restrict__ g, u16* lds, int w, int l){
  const int drow = l>>5, dch = l&31;
  int row = w*2 + drow;
  int gch = (dch&24) | ((dch&7) ^ ((row>>1)&7));
  dma16(g + (long)row*256 + gch*8, &lds[(w*2)*256]);
}

// preload this wave's 32 B-columns (rows wn0..+31 of bL) across K into regs
__device__ __forceinline__ void loadBf(const u16* bL, int w, int l, s16x8 (&bw)[2][8]){
  const int q=l>>4, ln=l&15, wn0=w*32;
  #pragma unroll
  for (int nt=0;nt<2;nt++)
    #pragma unroll
    for (int kq=0;kq<8;kq++){
      int n = wn0 + nt*16 + ln, ca = kq*4+q;
      bw[nt][kq] = *(const s16x8*)&bL[n*256 + slot8(ca, n)];
    }
}

// acc = A(rows arow0..+31 of aL) @ B(regs), K=256
__device__ __forceinline__ void multAr(const u16* aL, int arow0, const s16x8 (&bw)[2][8],
                                       int l, f32x4 (&acc)[2][2]){
  const int q=l>>4, ln=l&15;
  #pragma unroll
  for (int mt=0;mt<2;mt++)
    #pragma unroll
    for (int nt=0;nt<2;nt++){ acc[mt][nt][0]=0.f; acc[mt][nt][1]=0.f; acc[mt][nt][2]=0.f; acc[mt][nt][3]=0.f; }
  #pragma unroll
  for (int kq=0;kq<8;kq++){
    int ca = kq*4+q;
    s16x8 af[2];
    #pragma unroll
    for (int mt=0;mt<2;mt++){
      int r = arow0 + mt*16 + ln;
      af[mt] = *(const s16x8*)&aL[r*256 + slot8(ca, r)];
    }
    #pragma unroll
    for (int mt=0;mt<2;mt++)
      #pragma unroll
      for (int nt=0;nt<2;nt++)
        acc[mt][nt] = MFMA16(af[mt], bw[nt][kq], acc[mt][nt]);
  }
}

// hacc = H(16 rows of hL) @ B(regs)
__device__ __forceinline__ void multHr(const u16* hL, const s16x8 (&bw)[2][8],
                                       int l, f32x4 (&hacc)[2]){
  const int q=l>>4, ln=l&15;
  hacc[0][0]=0.f; hacc[0][1]=0.f; hacc[0][2]=0.f; hacc[0][3]=0.f;
  hacc[1][0]=0.f; hacc[1][1]=0.f; hacc[1][2]=0.f; hacc[1][3]=0.f;
  #pragma unroll
  for (int kq=0;kq<8;kq++){
    int ca = kq*4+q;
    s16x8 af = *(const s16x8*)&hL[ln*256 + slot8(ca, ln)];
    hacc[0] = MFMA16(af, bw[0][kq], hacc[0]);
    hacc[1] = MFMA16(af, bw[1][kq], hacc[1]);
  }
}

__device__ __forceinline__ void polyinit13(const u16* aL, int arow0, int w, int l, f32x4 (&poly)[2][2]){
  const int q=l>>4, ln=l&15, wn0=w*32;
  #pragma unroll
  for (int mt=0;mt<2;mt++)
  #pragma unroll
  for (int nt=0;nt<2;nt++)
  #pragma unroll
  for (int r=0;r<4;r++){
    int row = arow0 + mt*16 + q*4 + r;
    int col = wn0 + nt*16 + ln;
    poly[mt][nt][r] = 13.f*bf2f(aL[swidx(row,col)]);
  }
}
__device__ __forceinline__ void init13H(const u16* hL, int w, int l, f32x4 (&hpoly)[2]){
  const int q=l>>4, ln=l&15, wn0=w*32;
  #pragma unroll
  for (int nt=0;nt<2;nt++)
  #pragma unroll
  for (int r=0;r<4;r++)
    hpoly[nt][r] = 13.f*bf2f(hL[swidx(q*4+r, wn0+nt*16+ln)]);
}
__device__ __forceinline__ void polyaxpy(f32x4 (&poly)[2][2], const f32x4 (&acc)[2][2], float sc){
  #pragma unroll
  for (int mt=0;mt<2;mt++)
    #pragma unroll
    for (int nt=0;nt<2;nt++)
      #pragma unroll
      for (int r=0;r<4;r++) poly[mt][nt][r] += sc*acc[mt][nt][r];
}
__device__ __forceinline__ void axpyH(f32x4 (&hpoly)[2], const f32x4 (&hacc)[2], float sc){
  #pragma unroll
  for (int nt=0;nt<2;nt++)
    #pragma unroll
    for (int r=0;r<4;r++) hpoly[nt][r] += sc*hacc[nt][r];
}
__device__ __forceinline__ void zeroH(f32x4 (&p)[2]){
  p[0][0]=0.f; p[0][1]=0.f; p[0][2]=0.f; p[0][3]=0.f;
  p[1][0]=0.f; p[1][1]=0.f; p[1][2]=0.f; p[1][3]=0.f;
}
__device__ __forceinline__ void writeT(u16* Ts, const f32x4 (&acc)[2][2], int w, int l, float sc){
  const int q=l>>4, ln=l&15, wn0=w*32;
  #pragma unroll
  for (int mt=0;mt<2;mt++)
  #pragma unroll
  for (int nt=0;nt<2;nt++)
  #pragma unroll
  for (int r=0;r<4;r++){
    int row = mt*16 + q*4 + r;
    int col = wn0 + nt*16 + ln;
    Ts[swidx(row,col)] = f2bf(sc*acc[mt][nt][r]);
  }
}
__device__ __forceinline__ void writeH(u16* Hs, const f32x4 (&hacc)[2], int w, int l){
  const int q=l>>4, ln=l&15, wn0=w*32;
  #pragma unroll
  for (int nt=0;nt<2;nt++)
  #pragma unroll
  for (int r=0;r<4;r++)
    Hs[swidx(q*4+r, wn0+nt*16+ln)] = f2bf(hacc[nt][r]);
}
__device__ __forceinline__ void writeHsc(u16* Hs, const f32x4 (&v)[2], int w, int l, float sc){
  const int q=l>>4, ln=l&15, wn0=w*32;
  #pragma unroll
  for (int nt=0;nt<2;nt++)
  #pragma unroll
  for (int r=0;r<4;r++)
    Hs[swidx(q*4+r, wn0+nt*16+ln)] = f2bf(sc*v[nt][r]);
}
__device__ __forceinline__ void epi_poly(u16* __restrict__ out, int rowbase,
                                         const f32x4 (&poly)[2][2], int w, int l, float sc){
  const int q=l>>4, ln=l&15, wn0=w*32;
  #pragma unroll
  for (int mt=0;mt<2;mt++)
  #pragma unroll
  for (int nt=0;nt<2;nt++)
  #pragma unroll
  for (int r=0;r<4;r++){
    int row = rowbase + mt*16 + q*4 + r;
    int col = wn0 + nt*16 + ln;
    out[(long)row*256 + col] = f2bf(sc*poly[mt][nt][r]);
  }
}
__device__ __forceinline__ void epiH(u16* __restrict__ out, const f32x4 (&hpoly)[2],
                                     int w, int l, float sc){
  const int q=l>>4, ln=l&15, wn0=w*32;
  #pragma unroll
  for (int nt=0;nt<2;nt++)
  #pragma unroll
  for (int r=0;r<4;r++)
    out[(long)(q*4+r)*256 + wn0+nt*16+ln] = f2bf(sc*hpoly[nt][r]);
}

// legacy LDS-B mult (kw0 only: single phase, preload is neutral)
__device__ __forceinline__ void mult32(const u16* aL, int arow0, const u16* bL,
                                       int w, int l, f32x4 (&acc)[2][2]){
  const int q=l>>4, ln=l&15, wn0=w*32;
  #pragma unroll
  for (int mt=0;mt<2;mt++)
    #pragma unroll
    for (int nt=0;nt<2;nt++){ acc[mt][nt][0]=0.f; acc[mt][nt][1]=0.f; acc[mt][nt][2]=0.f; acc[mt][nt][3]=0.f; }
  #pragma unroll
  for (int kq=0;kq<8;kq++){
    int ca = kq*4+q;
    s16x8 af[2];
    #pragma unroll
    for (int mt=0;mt<2;mt++){
      int r = arow0 + mt*16 + ln;
      af[mt] = *(const s16x8*)&aL[r*256 + slot8(ca,r)];
    }
    #pragma unroll
    for (int nt=0;nt<2;nt++){
      int n = wn0 + nt*16 + ln;
      s16x8 bfr = *(const s16x8*)&bL[n*256 + slot8(ca,n)];
      acc[0][nt] = MFMA16(af[0], bfr, acc[0][nt]);
      acc[1][nt] = MFMA16(af[1], bfr, acc[1][nt]);
    }
  }
}

// kw0: W0 = s0*X@X^T slab; self-computed s0 from cs_p; slab0 also preps h0
__global__ __launch_bounds__(512)
void kw0(const float* __restrict__ cs_p, float* __restrict__ scal,
         const float* __restrict__ num_p, const float* __restrict__ den_p,
         const u16* __restrict__ X, u16* __restrict__ W0, u16* __restrict__ h0)
{
  __shared__ __align__(16) u16 Wf[65536];
  __shared__ __align__(16) u16 Ts[8192];
  const int tid=threadIdx.x, w=tid>>6, l=tid&63;
  const int bid=blockIdx.x, xcd=bid&7, j=bid>>3;
  const int batch = xcd*4 + (j>>3), slab = j&7;

  stage256(X + (long)batch*65536, Wf, w, l);   // dma in flight during reduce

  float* red = (float*)Ts;
  float mx = 0.f;
  for (int i=tid;i<8192;i+=512){
    float s = 0.f;
    #pragma unroll
    for (int c=0;c<8;c++) s += cs_p[(long)c*8192 + i];
    mx = fmaxf(mx, s);
  }
  red[tid] = mx; __syncthreads();
  for (int s=256;s>0;s>>=1){ if (tid<s) red[tid] = fmaxf(red[tid], red[tid+s]); __syncthreads(); }
  float s0 = 1.0f/red[0];
  if (bid==0 && tid==0) scal[0] = s0;

  f32x4 acc[2][2];
  mult32(Wf, slab*32, Wf, w, l, acc);
  {
    const int q=l>>4, ln=l&15, wn0=w*32;
    u16* ob = W0 + (long)batch*65536;
    #pragma unroll
    for (int mt=0;mt<2;mt++)
    #pragma unroll
    for (int nt=0;nt<2;nt++)
    #pragma unroll
    for (int r=0;r<4;r++){
      int row = slab*32 + mt*16 + q*4 + r;
      int col = wn0 + nt*16 + ln;
      ob[(long)row*256 + col] = f2bf(acc[mt][nt][r]*s0);
    }
  }

  if (slab==0){
    __syncthreads();
    float (*lt)[257] = (float(*)[257])Wf;
    for (int i=tid;i<8192;i+=512){
      int m = i>>5, d = i&31;
      float sn = 0.f, sd = 0.f;
      #pragma unroll
      for (int c=0;c<8;c++){
        sn += num_p[((long)(c*32+batch))*8192 + i];
        sd += den_p[(c*32+batch)*256 + m];
      }
      lt[d][m] = sn/sd;
    }
    __syncthreads();
    u16* o = h0 + (long)batch*8192;
    for (int j2=tid;j2<8192;j2+=512){
      int d = j2>>8, m = j2&255;
      o[j2] = f2bf(lt[d][m]);
    }
  }
}

// kiter: one Newton iteration. 256 blocks x 512 thr; slab0/slab4 advance h halves.
__global__ __launch_bounds__(512)
void kiter(const u16* __restrict__ Win, u16* __restrict__ Wout,
           const u16* __restrict__ hin, u16* __restrict__ hout)
{
  __shared__ __align__(16) u16 Wf[65536];
  __shared__ __align__(16) u16 Ts[8192];
  __shared__ __align__(16) u16 Hs[4096];
  const int tid=threadIdx.x, w=tid>>6, l=tid&63;
  const int bid=blockIdx.x, xcd=bid&7, j=bid>>3;
  const int batch = xcd*4 + (j>>3), slab = j&7;
  const bool hrole = (slab&3)==0;              // slabs 0 and 4
  const int hr0 = (slab>>2)*16;

  stage256(Win + (long)batch*65536, Wf, w, l);
  if (hrole) stage16(hin + (long)batch*8192 + hr0*256, Hs, w, l);
  __syncthreads();

  s16x8 bw[2][8];
  loadBf(Wf, w, l, bw);

  f32x4 acc[2][2], poly[2][2];
  f32x4 hacc[2], hpoly[2];

  polyinit13(Wf, slab*32, w, l, poly);
  multAr(Wf, slab*32, bw, l, acc);             // t1 = Wslab@W
  polyaxpy(poly, acc, -15.f);
  if (hrole){
    init13H(Hs, w, l, hpoly);
    multHr(Hs, bw, l, hacc);                   // h@W
    axpyH(hpoly, hacc, -15.f);
  }
  __syncthreads();
  writeT(Ts, acc, w, l, 1.f);
  if (hrole) writeH(Hs, hacc, w, l);
  __syncthreads();
  multAr(Ts, 0, bw, l, acc);                   // t2
  polyaxpy(poly, acc, 7.f);
  if (hrole){ multHr(Hs, bw, l, hacc); axpyH(hpoly, hacc, 7.f); }
  __syncthreads();
  writeT(Ts, acc, w, l, 1.f);
  if (hrole) writeH(Hs, hacc, w, l);
  __syncthreads();
  multAr(Ts, 0, bw, l, acc);                   // t3
  polyaxpy(poly, acc, -1.f);
  epi_poly(Wout + (long)batch*65536, slab*32, poly, w, l, 0.25f);
  if (hrole){
    multHr(Hs, bw, l, hacc);
    axpyH(hpoly, hacc, -1.f);
    epiH(hout + (long)batch*8192 + hr0*256, hpoly, w, l, 0.25f);
  }
}

// ---------------------------------------------------------------------------
// ktail2: fused {iteration 5 h-advance + tail} with W5 never materialized.
//   h5 = h4*Q(W4)                      (3 thin matmuls)
//   a  = h5@W5 = (h5@W4)*Q(W4)         (4)
//   b  = a@W5  = (a@W4)*Q(W4)          (4)
//   c  = b@W5  = (b@W4)*Q(W4)          (4)
//   g1 = 0.25(13h5 -15a +7b -c); u = s0*g1@X   (1)
// Rows are independent (all right-mults) -> grid 64 = 32 batches x 2 halves
// of 16 rows. W4 staged once (proven stage256+loadBf path); XT prefetched
// into Wf during the chain (Wf dead after loadBf). One barrier per phase
// (strict Ha/Hb ping-pong: read src, write other).
// ---------------------------------------------------------------------------
__global__ __launch_bounds__(512)
void ktail2(const u16* __restrict__ W4, const u16* __restrict__ h4,
            const u16* __restrict__ XT, const float* __restrict__ scal,
            u16* __restrict__ uT)
{
  __shared__ __align__(16) u16 Wf[65536];
  __shared__ __align__(16) u16 Ha[4096];
  __shared__ __align__(16) u16 Hb[4096];
  const int tid=threadIdx.x, w=tid>>6, l=tid&63;
  const int batch = blockIdx.x>>1, half = blockIdx.x&1;

  stage256(W4 + (long)batch*65536, Wf, w, l);
  stage16(h4 + (long)batch*8192 + half*4096, Ha, w, l);
  __syncthreads();

  s16x8 bw[2][8];
  loadBf(Wf, w, l, bw);
  __syncthreads();                              // all W4 reads from Wf done
  stage256(XT + (long)batch*65536, Wf, w, l);   // async; drained by later barriers

  f32x4 acc[2], poly[2], gpoly[2];

  // ---- h5 = 0.25(13h4 -15 h4W +7 h4W^2 - h4W^3) ----
  init13H(Ha, w, l, poly);
  multHr(Ha, bw, l, acc); axpyH(poly, acc, -15.f);
  writeH(Hb, acc, w, l); __syncthreads();
  multHr(Hb, bw, l, acc); axpyH(poly, acc, 7.f);
  writeH(Ha, acc, w, l); __syncthreads();
  multHr(Ha, bw, l, acc); axpyH(poly, acc, -1.f);
  zeroH(gpoly); axpyH(gpoly, poly, 3.25f);      // gpoly = 13*h5
  writeHsc(Hb, poly, w, l, 0.25f); __syncthreads();   // Hb = r(h5)

  // ---- a = (h5@W4)*Q(W4) ----
  multHr(Hb, bw, l, acc); zeroH(poly); axpyH(poly, acc, 13.f);
  writeH(Ha, acc, w, l); __syncthreads();
  multHr(Ha, bw, l, acc); axpyH(poly, acc, -15.f);
  writeH(Hb, acc, w, l); __syncthreads();
  multHr(Hb, bw, l, acc); axpyH(poly, acc, 7.f);
  writeH(Ha, acc, w, l); __syncthreads();
  multHr(Ha, bw, l, acc); axpyH(poly, acc, -1.f);
  axpyH(gpoly, poly, -3.75f);                   // gpoly += -15*a
  writeHsc(Hb, poly, w, l, 0.25f); __syncthreads();   // Hb = r(a)

  // ---- b = (a@W4)*Q(W4) ----
  multHr(Hb, bw, l, acc); zeroH(poly); axpyH(poly, acc, 13.f);
  writeH(Ha, acc, w, l); __syncthreads();
  multHr(Ha, bw, l, acc); axpyH(poly, acc, -15.f);
  writeH(Hb, acc, w, l); __syncthreads();
  multHr(Hb, bw, l, acc); axpyH(poly, acc, 7.f);
  writeH(Ha, acc, w, l); __syncthreads();
  multHr(Ha, bw, l, acc); axpyH(poly, acc, -1.f);
  axpyH(gpoly, poly, 1.75f);                    // gpoly += 7*b
  writeHsc(Hb, poly, w, l, 0.25f); __syncthreads();   // Hb = r(b)

  // ---- c = (b@W4)*Q(W4) ----
  multHr(Hb, bw, l, acc); zeroH(poly); axpyH(poly, acc, 13.f);
  writeH(Ha, acc, w, l); __syncthreads();
  multHr(Ha, bw, l, acc); axpyH(poly, acc, -15.f);
  writeH(Hb, acc, w, l); __syncthreads();
  multHr(Hb, bw, l, acc); axpyH(poly, acc, 7.f);
  writeH(Ha, acc, w, l); __syncthreads();
  multHr(Ha, bw, l, acc); axpyH(poly, acc, -1.f);
  axpyH(gpoly, poly, -0.25f);                   // gpoly += -c
  writeHsc(Hb, gpoly, w, l, 0.25f); __syncthreads();  // Hb = r(g1)

  // ---- u = s0 * g1 @ X  (B-frags from XT, now resident in Wf) ----
  loadBf(Wf, w, l, bw);
  multHr(Hb, bw, l, acc);
  epiH(uT + (long)batch*8192 + half*4096, acc, w, l, scal[0]);
}

// ---------------------------------------------------------------------------
// Merged attn2 + attn3v (independent; grid (16,32): x<8 attn2, x>=8 attn3v)
// ---------------------------------------------------------------------------
__global__ __launch_bounds__(256)
void kattn23(const u16* __restrict__ ql, const u16* __restrict__ kl,
             u16* __restrict__ X, u16* __restrict__ XT, float* __restrict__ cs_p,
             const u16* __restrict__ kk, const u16* __restrict__ vv,
             float* __restrict__ num_p, float* __restrict__ den_p)
{
  __shared__ __align__(16) u16 Pbuf[4][64][40];
  __shared__ __align__(16) u16 vT[32][40];
  __shared__ float qrow[32][33];
  __shared__ float psum[32][4];
  __shared__ float rsum[32];
  int bh = blockIdx.y;
  int tid = threadIdx.x, w = tid>>6, l = tid&63, q = l>>4, ln = l&15;

  if (blockIdx.x < 8){
    int r0 = blockIdx.x*32;
    int c = tid;
    #pragma unroll
    for (int i=0;i<4;i++){
      int e = c*4+i; int rr = e>>5, dd = e&31;
      qrow[rr][dd] = bf2f(ql[((long)bh*256 + r0+rr)*32 + dd]);
    }
    float kc[32];
    {
      const u16* kp = kl + ((long)bh*256 + c)*32;
      #pragma unroll
      for (int d=0;d<32;d++) kc[d] = bf2f(kp[d]);
    }
    __syncthreads();
    float er[32]; float colacc = 0.f;
    for (int r=0;r<32;r++){
      float s = 0.f;
      #pragma unroll
      for (int d=0;d<32;d++) s += qrow[r][d]*kc[d];
      float e = __expf(s);
      er[r] = e;
      float wsum = e;
      #pragma unroll
      for (int m=1;m<64;m<<=1) wsum += __shfl_xor(wsum, m);
      if (l==0) psum[r][w] = wsum;
    }
    __syncthreads();
    if (c<32) rsum[c] = psum[c][0]+psum[c][1]+psum[c][2]+psum[c][3];
    __syncthreads();
    for (int r=0;r<32;r++){
      float x = er[r]/rsum[r];
      u16 xb = f2bf(x);
      X [((long)bh*256 + r0+r)*256 + c] = xb;
      XT[((long)bh*256 + c)*256 + r0+r] = xb;
      colacc += x;
    }
    cs_p[(long)blockIdx.x*8192 + bh*256 + c] = colacc;
    return;
  }

  int chunk = blockIdx.x - 8;
  f32x4 z4; z4[0]=0.f; z4[1]=0.f; z4[2]=0.f; z4[3]=0.f;
  f32x4 acc[4][2]; f32x4 dacc[4];
  #pragma unroll
  for (int mt=0;mt<4;mt++){ dacc[mt]=z4; acc[mt][0]=z4; acc[mt][1]=z4; }
  const u16* qlb = ql + (long)bh*8192;
  const u16* kb  = kk + (long)bh*131072;
  const u16* vb  = vv + (long)bh*131072;
  int vn = tid>>3, vd = (tid&7)*4;
  for (int s=0;s<16;s++){
    int n0 = chunk*512 + s*32;
    ushort4 vx = *(const ushort4*)(vb + (long)(n0+vn)*32 + vd);
    vT[vd+0][vn]=vx.x; vT[vd+1][vn]=vx.y; vT[vd+2][vn]=vx.z; vT[vd+3][vn]=vx.w;
    __syncthreads();
    s16x8 bk[2];
    #pragma unroll
    for (int nt=0;nt<2;nt++) bk[nt] = *(const s16x8*)(kb + (long)(n0 + nt*16 + ln)*32 + q*8);
    #pragma unroll
    for (int mt=0;mt<4;mt++){
      s16x8 aq = *(const s16x8*)(qlb + (long)(w*64 + mt*16 + ln)*32 + q*8);
      #pragma unroll
      for (int nt=0;nt<2;nt++){
        f32x4 sf = MFMA16(aq, bk[nt], z4);
        f32x4 ef;
        #pragma unroll
        for (int r=0;r<4;r++) ef[r] = __expf(sf[r]);
        dacc[mt] += ef;
        #pragma unroll
        for (int r=0;r<4;r++) Pbuf[w][mt*16 + q*4 + r][nt*16 + ln] = f2bf(ef[r]);
      }
    }
    #pragma unroll
    for (int mt=0;mt<4;mt++){
      s16x8 ap = *(const s16x8*)&Pbuf[w][mt*16 + ln][q*8];
      #pragma unroll
      for (int nt=0;nt<2;nt++){
        s16x8 bv = *(const s16x8*)&vT[nt*16 + ln][q*8];
        acc[mt][nt] = MFMA16(ap, bv, acc[mt][nt]);
      }
    }
    __syncthreads();
  }
  #pragma unroll
  for (int mt=0;mt<4;mt++)
    #pragma unroll
    for (int r=0;r<4;r++){
      float x = dacc[mt][r];
      x += __shfl_xor(x,1); x += __shfl_xor(x,2); x += __shfl_xor(x,4); x += __shfl_xor(x,8);
      dacc[mt][r] = x;
    }
  long pbase = (long)(chunk*32 + bh);
  #pragma unroll
  for (int mt=0;mt<4;mt++)
    #pragma unroll
    for (int nt=0;nt<2;nt++)
      #pragma unroll
      for (int r=0;r<4;r++){
        int mg = w*64 + mt*16 + q*4 + r;
        num_p[pbase*8192 + (long)mg*32 + nt*16 + ln] = acc[mt][nt][r];
      }
  if (ln==0){
    #pragma unroll
    for (int mt=0;mt<4;mt++)
      #pragma unroll
      for (int r=0;r<4;r++)
        den_p[pbase*256 + w*64 + mt*16 + q*4 + r] = dacc[mt][r];
  }
}

// ---------------------------------------------------------------------------
// attn1 fused + depthwise residual conv
// ---------------------------------------------------------------------------
__global__ __launch_bounds__(256)
void kattn1u(const u16* __restrict__ qq, const u16* __restrict__ kl, const u16* __restrict__ uT,
             const u16* __restrict__ vv, const float* __restrict__ rw,
             u16* __restrict__ aoutb)
{
  int nch = blockIdx.x, bh = blockIdx.y;
  int b = bh>>3, h = bh&7;
  int tid = threadIdx.x, w = tid>>6, l = tid&63, q = l>>4, ln = l&15;
  __shared__ __align__(16) u16 Pbuf[4][32][40];
  __shared__ __align__(16) u16 vtile[160][36];
  int r0g = nch*128;
  const u16* vb = vv + (long)bh*131072;
  #pragma unroll
  for (int it=0; it<5; it++){
    int slot = tid + it*256;
    int rr = slot>>3, c = (slot&7)*4;
    int s = r0g - 16 + rr;
    ushort4 val; val.x=0; val.y=0; val.z=0; val.w=0;
    if (s>=0 && s<4096) val = *(const ushort4*)(vb + (long)s*32 + c);
    *(ushort4*)&vtile[rr][c] = val;
  }
  __syncthreads();

  f32x4 z4; z4[0]=0.f; z4[1]=0.f; z4[2]=0.f; z4[3]=0.f;
  f32x4 acc[2][2]; f32x4 dacc[2];
  #pragma unroll
  for (int mt=0;mt<2;mt++){ dacc[mt]=z4; acc[mt][0]=z4; acc[mt][1]=z4; }
  const u16* qb  = qq + (long)bh*131072;
  const u16* klb = kl + (long)bh*8192;
  const u16* ub  = uT + (long)bh*8192;
  int r0 = r0g + w*32;
  for (int s=0;s<8;s++){
    s16x8 bk[2];
    #pragma unroll
    for (int nt=0;nt<2;nt++) bk[nt] = *(const s16x8*)(klb + (long)(s*32 + nt*16 + ln)*32 + q*8);
    #pragma unroll
    for (int mt=0;mt<2;mt++){
      s16x8 aq = *(const s16x8*)(qb + (long)(r0 + mt*16 + ln)*32 + q*8);
      #pragma unroll
      for (int nt=0;nt<2;nt++){
        f32x4 sf = MFMA16(aq, bk[nt], z4);
        f32x4 ef;
        #pragma unroll
        for (int r=0;r<4;r++) ef[r] = __expf(sf[r]);
        dacc[mt] += ef;
        #pragma unroll
        for (int r=0;r<4;r++) Pbuf[w][mt*16 + q*4 + r][nt*16 + ln] = f2bf(ef[r]);
      }
    }
    #pragma unroll
    for (int mt=0;mt<2;mt++){
      s16x8 ap = *(const s16x8*)&Pbuf[w][mt*16 + ln][q*8];
      #pragma unroll
      for (int nt=0;nt<2;nt++){
        s16x8 bu = *(const s16x8*)(ub + (long)(nt*16 + ln)*256 + s*32 + q*8);
        acc[mt][nt] = MFMA16(ap, bu, acc[mt][nt]);
      }
    }
  }
  #pragma unroll
  for (int mt=0;mt<2;mt++)
    #pragma unroll
    for (int r=0;r<4;r++){
      float x = dacc[mt][r];
      x += __shfl_xor(x,1); x += __shfl_xor(x,2); x += __shfl_xor(x,4); x += __shfl_xor(x,8);
      dacc[mt][r] = x;
    }

  const float* wp = rw + h*33;
  float w_[33];
  #pragma unroll
  for (int j=0;j<33;j++) w_[j] = wp[j];

  #pragma unroll
  for (int mt=0;mt<2;mt++){
    int nl = w*32 + mt*16 + q*4;
    #pragma unroll
    for (int nt=0;nt<2;nt++){
      int d = nt*16 + ln;
      float vvv[36];
      #pragma unroll
      for (int j=0;j<36;j++) vvv[j] = bf2f(vtile[nl + j][d]);
      #pragma unroll
      for (int r=0;r<4;r++){
        float cv = 0.f;
        #pragma unroll
        for (int j=0;j<33;j++) cv += w_[j]*vvv[r+j];
        int n = r0 + mt*16 + q*4 + r;
        long oidx = ((long)b*4096 + n)*256 + h*32 + d;
        aoutb[oidx] = f2bf(acc[mt][nt][r]/dacc[mt][r] + cv);
      }
    }
  }
}

// ---------------------------------------------------------------------------
// Merged: LN(x) (blocks 0..4095) + weight transpose/cast (blocks 4096..5119)
// ---------------------------------------------------------------------------
__global__ __launch_bounds__(256)
void kcvtln(const float* __restrict__ xin, const float* __restrict__ lg, const float* __restrict__ lb,
            u16* __restrict__ xn,
            const float* __restrict__ wqkv, const float* __restrict__ wout,
            const float* __restrict__ w1, const float* __restrict__ w2,
            u16* __restrict__ wqkvT, u16* __restrict__ woutT,
            u16* __restrict__ w1T, u16* __restrict__ w2T)
{
  __shared__ float t[32][33];
  int z = blockIdx.x;
  if (z < 4096){
    int w = threadIdx.x>>6, l = threadIdx.x&63;
    long row = (long)z*4 + w;
    float4 v = ((const float4*)(xin + row*256))[l];
    float s = v.x+v.y+v.z+v.w;
    #pragma unroll
    for (int m=1;m<64;m<<=1) s += __shfl_xor(s, m);
    float mu = s*(1.0f/256.0f);
    float dx=v.x-mu, dy=v.y-mu, dz=v.z-mu, dw=v.w-mu;
    float s2 = dx*dx+dy*dy+dz*dz+dw*dw;
    #pragma unroll
    for (int m=1;m<64;m<<=1) s2 += __shfl_xor(s2, m);
    float rs = rsqrtf(s2*(1.0f/256.0f) + 1e-5f);
    float4 gg = ((const float4*)lg)[l];
    float4 bb = ((const float4*)lb)[l];
    ushort4 o;
    o.x = f2bf(dx*rs*gg.x + bb.x);
    o.y = f2bf(dy*rs*gg.y + bb.y);
    o.z = f2bf(dz*rs*gg.z + bb.z);
    o.w = f2bf(dw*rs*gg.w + bb.w);
    *(ushort4*)(xn + row*256 + l*4) = o;
    return;
  }
  z -= 4096;
  const float* src; u16* dst; int K, Nn, bx, by;
  if (z < 384){      int i=z/192, r=z%192; src=wqkv+(long)i*196608; dst=wqkvT+(long)i*196608; K=256; Nn=768; bx=r%24; by=r/24; }
  else if (z < 512){ int zz=z-384; int i=zz/64, r=zz%64; src=wout+(long)i*65536; dst=woutT+(long)i*65536; K=256; Nn=256; bx=r%8; by=r/8; }
  else if (z < 768){ int zz=z-512; int i=zz/128, r=zz%128; src=w1+(long)i*131072; dst=w1T+(long)i*131072; K=256; Nn=512; bx=r%16; by=r/16; }
  else {             int zz=z-768; int i=zz/128, r=zz%128; src=w2+(long)i*131072; dst=w2T+(long)i*131072; K=512; Nn=256; bx=r%8; by=r/8; }
  int n0 = bx*32, k0 = by*32;
  int tx = threadIdx.x&31, ty = threadIdx.x>>5;
  #pragma unroll
  for (int i=0;i<4;i++) t[ty+i*8][tx] = src[(long)(k0+ty+i*8)*Nn + n0+tx];
  __syncthreads();
  #pragma unroll
  for (int i=0;i<4;i++) dst[(long)(n0+ty+i*8)*K + k0+tx] = f2bf(t[tx][ty+i*8]);
}

// ---------------------------------------------------------------------------
extern "C" void kernel_launch(void* const* d_in, const int* in_sizes, int n_in,
                              void* d_out, int out_size, void* d_ws, size_t ws_size,
                              hipStream_t stream)
{
  const float* x    = (const float*)d_in[0];
  const float* ln1g = (const float*)d_in[1];
  const float* ln1b = (const float*)d_in[2];
  const float* wqkv = (const float*)d_in[3];
  const float* wout = (const float*)d_in[4];
  const float* bout = (const float*)d_in[5];
  const float* resw = (const float*)d_in[6];
  const float* ln2g = (const float*)d_in[7];
  const float* ln2b = (const float*)d_in[8];
  const float* w1   = (const float*)d_in[9];
  const float* b1   = (const float*)d_in[10];
  const float* w2   = (const float*)d_in[11];
  const float* b2   = (const float*)d_in[12];
  float* y = (float*)d_out;
  char* ws = (char*)d_ws;

  u16* xn    = (u16*)(ws + 0);
  u16* qb    = (u16*)(ws + 8388608);
  u16* kb    = (u16*)(ws + 16777216);
  u16* vb    = (u16*)(ws + 25165824);
  u16* ql    = (u16*)(ws + 33554432);
  u16* kl    = (u16*)(ws + 34078720);
  u16* X     = (u16*)(ws + 34603008);
  u16* XT    = (u16*)(ws + 38797312);     // X^T (B-operand of final U GEMM)
  u16* h0b   = (u16*)(ws + 42991616);     // h0 [32][32][256] bf16 (512 KB)
  // pinv work region
  u16* WA    = (u16*)(ws + 51380224);
  u16* WB    = (u16*)(ws + 55574528);
  u16* hA    = (u16*)(ws + 68157440);     // thin h buffers [32][32][256]
  u16* hB    = (u16*)(ws + 72351744);
  float* num_p = (float*)(ws + 76546048);  // 8 MB
  float* den_p = (float*)(ws + 84934656);
  float* cs_p  = (float*)(ws + 85196800);
  float* scal  = (float*)(ws + 85458944);
  u16* uT    = (u16*)(ws + 85459200);
  u16* aoutb = (u16*)(ws + 85983488);
  u16* wqkvT = (u16*)(ws + 94372096);
  u16* woutT = (u16*)(ws + 95158528);
  u16* w1T   = (u16*)(ws + 95420672);
  u16* w2T   = (u16*)(ws + 95944960);
  u16* hdn   = (u16*)(ws + 51380224);      // overlays WA/WB (dead by FFN)

  (void)in_sizes; (void)n_in; (void)out_size; (void)ws_size;

  // LN(x) + weight cvt in one launch
  kcvtln<<<5120,256,0,stream>>>(x, ln1g, ln1b, xn,
      wqkv, wout, w1, w2, wqkvT, woutT, w1T, w2T);

  for (int i=0;i<2;i++){
    // xn: i==0 from kcvtln; i==1 from previous FFN2's fused LN epilogue
    kgemm2<EPI_QKV><<<dim3(128,6),256,0,stream>>>(xn, wqkvT + (long)i*196608, 256, 256, 256,
        nullptr, nullptr, 0, qb,kb,vb, ql,kl);
    kattn23<<<dim3(16,32),256,0,stream>>>(ql, kl, X, XT, cs_p, kb, vb, num_p, den_p);

    // ---- pinv: kw0 (scal + W0 + h0) -> 4x kiter -> ktail2 (iter5-h + tail) ----
    kw0<<<256,512,0,stream>>>(cs_p, scal, num_p, den_p, X, WA, h0b);
    u16 *Wi = WA, *Wo = WB, *hi = h0b, *ho = hA;
    for (int it=0; it<4; it++){
      kiter<<<256,512,0,stream>>>(Wi, Wo, hi, ho);
      u16* t = Wi; Wi = Wo; Wo = t;
      hi = ho; ho = (ho == hA) ? hB : hA;
    }
    ktail2<<<64,512,0,stream>>>(Wi, hi, XT, scal, uT);

    kattn1u<<<dim3(32,32),256,0,stream>>>(qb, kl, uT, vb, resw + i*264, aoutb);
    // wout GEMM + residual + LN2 fused -> y (f32) + xn (bf16 for FFN1)
    kgemmLN<<<256,256,0,stream>>>(aoutb, woutT + (long)i*65536, 256,
        bout + i*256, i==0 ? x : y, y, ln2g + i*256, ln2b + i*256, xn);
    kgemm2<EPI_BIAS_GELU><<<dim3(128,4),256,0,stream>>>(xn, w1T + (long)i*131072, 256, 256, 256,
        b1 + i*512, hdn, 512, nullptr,nullptr,nullptr, nullptr,nullptr);
    // FFN2 GEMM + residual + LN1(next) fused -> y + xn (for next QKV; dead on i==1)
    kgemmLN<<<256,256,0,stream>>>(hdn, w2T + (long)i*131072, 512,
        b2 + i*256, y, y, ln1g + 256, ln1b + 256, xn);
  }
}

// Round 10
// 492.789 us; speedup vs baseline: 1.2601x; 1.0011x over previous
//
#include <hip/hip_runtime.h>
#include <math.h>

typedef float f32x4 __attribute__((ext_vector_type(4)));
typedef short s16x8 __attribute__((ext_vector_type(8)));
typedef unsigned short u16;
typedef unsigned int u32;

#define MFMA16(a,b,c) __builtin_amdgcn_mfma_f32_16x16x32_bf16((a),(b),(c),0,0,0)
#define AS1 __attribute__((address_space(1)))
#define AS3 __attribute__((address_space(3)))

__device__ __forceinline__ void dma16(const u16* g, u16* l){
  __builtin_amdgcn_global_load_lds((const AS1 u32*)g, (AS3 u32*)l, 16, 0, 0);
}

__device__ __forceinline__ float bf2f(u16 u){
  union { unsigned int i; float f; } v; v.i = ((unsigned int)u)<<16; return v.f;
}
__device__ __forceinline__ u16 f2bf(float f){
  union { float f; unsigned int i; } v; v.f = f;
  unsigned int x = v.i;
  return (u16)((x + 0x7fffu + ((x>>16)&1u))>>16);
}

enum { EPI_QKV=0, EPI_BIAS_GELU=3 };

// ---------------------------------------------------------------------------
// kgemm2: BM=128, BN=128, BK=32, 4x4 frags/wave; DMA staging + swizzle.
// ---------------------------------------------------------------------------
template<int EPI>
__global__ __launch_bounds__(256)
void kgemm2(const u16* __restrict__ A, const u16* __restrict__ BT, int K, int lda, int ldb,
            const float* __restrict__ bias, u16* __restrict__ outb, int ldc,
            u16* __restrict__ qo, u16* __restrict__ ko, u16* __restrict__ vo,
            u16* __restrict__ qlm, u16* __restrict__ klm)
{
  __shared__ __align__(16) u16 As[128*32];
  __shared__ __align__(16) u16 Bs[128*32];
  const int tid = threadIdx.x;
  const int w = tid>>6, wy = w>>1, wx = w&1, l = tid&63, q = l>>4, ln = l&15;
  const int m0 = blockIdx.x*128, n0 = blockIdx.y*128;
  const int lrow = l>>2, lch = l&3;

  f32x4 acc[4][4];
  #pragma unroll
  for (int i=0;i<4;i++)
    #pragma unroll
    for (int j=0;j<4;j++){ acc[i][j][0]=0.f; acc[i][j][1]=0.f; acc[i][j][2]=0.f; acc[i][j][3]=0.f; }

  for (int k0=0; k0<K; k0+=32){
    #pragma unroll
    for (int c=0;c<2;c++){
      int row = 32*w + 16*c + lrow;
      int gch = lch ^ ((row>>1)&3);
      dma16(A + (long)(m0+row)*lda + k0 + gch*8, &As[(32*w+16*c)*32]);
      dma16(BT + (long)(n0+row)*ldb + k0 + gch*8, &Bs[(32*w+16*c)*32]);
    }
    __syncthreads();
    s16x8 af[4], bfr[4];
    #pragma unroll
    for (int mt=0;mt<4;mt++){
      int row = wy*64 + mt*16 + ln;
      af[mt] = *(const s16x8*)&As[row*32 + ((q ^ ((row>>1)&3))<<3)];
    }
    #pragma unroll
    for (int nt=0;nt<4;nt++){
      int row = wx*64 + nt*16 + ln;
      bfr[nt] = *(const s16x8*)&Bs[row*32 + ((q ^ ((row>>1)&3))<<3)];
    }
    #pragma unroll
    for (int mt=0;mt<4;mt++)
      #pragma unroll
      for (int nt=0;nt<4;nt++)
        acc[mt][nt] = MFMA16(af[mt], bfr[nt], acc[mt][nt]);
    __syncthreads();
  }

  #pragma unroll
  for (int mt=0;mt<4;mt++)
  #pragma unroll
  for (int nt=0;nt<4;nt++){
    int ncol = n0 + wx*64 + nt*16 + ln;
    if (EPI==EPI_QKV){
      int sel = ncol>>8, hd = ncol&255, h = hd>>5, d = hd&31;
      u16* dst = sel==0 ? qo : (sel==1 ? ko : vo);
      float sc2 = (sel==0) ? 0.17677669529663689f : 1.f;   // dh^-0.5 on q
      float s = 0.f;
      #pragma unroll
      for (int r=0;r<4;r++){
        int mrow = m0 + wy*64 + mt*16 + q*4 + r;
        int b = mrow>>12, n = mrow&4095;
        float v = acc[mt][nt][r]*sc2;
        dst[(((long)(b*8+h)*4096 + n)<<5) + d] = f2bf(v);
        s += v;
      }
      if (sel < 2){
        s += __shfl_xor(s, 16);
        s += __shfl_xor(s, 32);
        if (q == 0){
          int mrow0 = m0 + wy*64 + mt*16;
          int b = mrow0>>12, grp = (mrow0&4095)>>4;
          u16* ldst = (sel==0) ? qlm : klm;
          ldst[(((long)(b*8+h)*256 + grp)<<5) + d] = f2bf(s*(1.0f/16.0f));
        }
      }
    } else { // EPI_BIAS_GELU
      #pragma unroll
      for (int r=0;r<4;r++){
        int mrow = m0 + wy*64 + mt*16 + q*4 + r;
        float x = acc[mt][nt][r] + bias[ncol];
        float g = 0.5f*x*(1.0f + erff(x*0.70710678118654752f));
        outb[(long)mrow*ldc + ncol] = f2bf(g);
      }
    }
  }
}

// ---------------------------------------------------------------------------
// kgemmLN: BM=64, BN=256 (full rows per block, 256 blocks = full GPU),
// 4x4 frags/wave; residual+bias, then (if WXN) in-register LayerNorm with
// cross-wave combine -> writes y (f32) AND xn=LN(y) (bf16).
// WXN=0 skips the dead LN+xn on the final FFN2 call.
// ---------------------------------------------------------------------------
template<int WXN>
__global__ __launch_bounds__(256)
void kgemmLN(const u16* __restrict__ A, const u16* __restrict__ BT, int K,
             const float* __restrict__ bias, const float* __restrict__ base,
             float* __restrict__ yout,
             const float* __restrict__ lng, const float* __restrict__ lnb,
             u16* __restrict__ xnout)
{
  __shared__ __align__(16) u16 As[64*32];
  __shared__ __align__(16) u16 Bs[256*32];
  __shared__ float red[64][4];
  const int tid = threadIdx.x;
  const int w = tid>>6, l = tid&63, q = l>>4, ln = l&15;
  const int m0 = blockIdx.x*64;

  f32x4 acc[4][4];   // row = mt*16+q*4+r, col = w*64+nt*16+ln
  #pragma unroll
  for (int i=0;i<4;i++)
    #pragma unroll
    for (int j=0;j<4;j++){ acc[i][j][0]=0.f; acc[i][j][1]=0.f; acc[i][j][2]=0.f; acc[i][j][3]=0.f; }

  for (int k0=0; k0<K; k0+=32){
    {
      int row = w*16 + (l>>2);
      int gch = (l&3) ^ ((row>>1)&3);
      dma16(A + (long)(m0+row)*K + k0 + gch*8, &As[(w*16)*32]);
    }
    #pragma unroll
    for (int c=0;c<4;c++){
      int row = c*64 + w*16 + (l>>2);
      int gch = (l&3) ^ ((row>>1)&3);
      dma16(BT + (long)row*K + k0 + gch*8, &Bs[(c*64+w*16)*32]);
    }
    __syncthreads();
    s16x8 af[4], bfr[4];
    #pragma unroll
    for (int mt=0;mt<4;mt++){
      int row = mt*16 + ln;
      af[mt] = *(const s16x8*)&As[row*32 + ((q ^ ((row>>1)&3))<<3)];
    }
    #pragma unroll
    for (int nt=0;nt<4;nt++){
      int row = w*64 + nt*16 + ln;
      bfr[nt] = *(const s16x8*)&Bs[row*32 + ((q ^ ((row>>1)&3))<<3)];
    }
    #pragma unroll
    for (int mt=0;mt<4;mt++)
      #pragma unroll
      for (int nt=0;nt<4;nt++)
        acc[mt][nt] = MFMA16(af[mt], bfr[nt], acc[mt][nt]);
    __syncthreads();
  }

  // residual + bias, write y
  float rb[4];
  #pragma unroll
  for (int nt=0;nt<4;nt++) rb[nt] = bias[w*64 + nt*16 + ln];
  #pragma unroll
  for (int mt=0;mt<4;mt++)
  #pragma unroll
  for (int r=0;r<4;r++){
    long rowb = (long)(m0 + mt*16 + q*4 + r)*256;
    #pragma unroll
    for (int nt=0;nt<4;nt++){
      int col = w*64 + nt*16 + ln;
      float v = base[rowb + col] + acc[mt][nt][r] + rb[nt];
      acc[mt][nt][r] = v;
      yout[rowb + col] = v;
    }
  }
  if (!WXN) return;
  // mean: per-lane over 4 nt, 16-lane shuffle, cross-wave via red
  #pragma unroll
  for (int mt=0;mt<4;mt++)
  #pragma unroll
  for (int r=0;r<4;r++){
    float s = acc[mt][0][r]+acc[mt][1][r]+acc[mt][2][r]+acc[mt][3][r];
    s += __shfl_xor(s,1); s += __shfl_xor(s,2); s += __shfl_xor(s,4); s += __shfl_xor(s,8);
    if (ln==0) red[mt*16+q*4+r][w] = s;
  }
  __syncthreads();
  float mu[4][4];
  #pragma unroll
  for (int mt=0;mt<4;mt++)
  #pragma unroll
  for (int r=0;r<4;r++){
    int row = mt*16+q*4+r;
    mu[mt][r] = (red[row][0]+red[row][1]+red[row][2]+red[row][3])*(1.0f/256.0f);
  }
  __syncthreads();
  #pragma unroll
  for (int mt=0;mt<4;mt++)
  #pragma unroll
  for (int r=0;r<4;r++){
    float vs = 0.f;
    #pragma unroll
    for (int nt=0;nt<4;nt++){ float d = acc[mt][nt][r]-mu[mt][r]; vs += d*d; }
    vs += __shfl_xor(vs,1); vs += __shfl_xor(vs,2); vs += __shfl_xor(vs,4); vs += __shfl_xor(vs,8);
    if (ln==0) red[mt*16+q*4+r][w] = vs;
  }
  __syncthreads();
  float rg[4], rbb[4];
  #pragma unroll
  for (int nt=0;nt<4;nt++){ int col = w*64+nt*16+ln; rg[nt]=lng[col]; rbb[nt]=lnb[col]; }
  #pragma unroll
  for (int mt=0;mt<4;mt++)
  #pragma unroll
  for (int r=0;r<4;r++){
    int row = mt*16+q*4+r;
    float rs = rsqrtf((red[row][0]+red[row][1]+red[row][2]+red[row][3])*(1.0f/256.0f) + 1e-5f);
    long rowb = (long)(m0 + row)*256;
    #pragma unroll
    for (int nt=0;nt<4;nt++){
      int col = w*64 + nt*16 + ln;
      float d = acc[mt][nt][r]-mu[mt][r];
      xnout[rowb + col] = f2bf(d*rs*rg[nt] + rbb[nt]);
    }
  }
}

// ---------------------------------------------------------------------------
// Fused pinv: full 256x256 W resident in LDS + reg-cached B frags.
// 512 threads (8 waves). W' = 0.25(13W -15W^2 +7W^3 -W^4) per 32-row slab;
// h rows split across slab0 (rows 0-15) and slab4 (rows 16-31).
// Iteration 5's W-update is dead (tail re-expressed via W4) -> ktail2.
// ---------------------------------------------------------------------------
__device__ __forceinline__ int swidx(int row, int col){
  int cc = col>>3;
  int sl = (cc&24)|((cc&7)^((row>>1)&7));
  return row*256 + sl*8 + (col&7);
}
__device__ __forceinline__ int slot8(int ca, int row){
  return ((ca&24)|((ca&7)^((row>>1)&7)))<<3;
}

// stage 256x256 bf16 (131072B), 8 waves
__device__ __forceinline__ void stage256(const u16* __restrict__ g, u16* lds, int w, int l){
  const int drow = l>>5, dch = l&31;
  #pragma unroll
  for (int c=0;c<16;c++){
    int base = (c*8 + w)*2;
    int row = base + drow;
    int gch = (dch&24) | ((dch&7) ^ ((row>>1)&7));
    dma16(g + (long)row*256 + gch*8, &lds[base*256]);
  }
}
// stage 16x256 (8KB), 8 waves (2 rows/wave)
__device__ __forceinline__ void stage16(const u16* __restrict__ g, u16* lds, int w, int l){
  const int drow = l>>5, dch = l&31;
  int row = w*2 + drow;
  int gch = (dch&24) | ((dch&7) ^ ((row>>1)&7));
  dma16(g + (long)row*256 + gch*8, &lds[(w*2)*256]);
}

// preload this wave's 32 B-columns (rows wn0..+31 of bL) across K into regs
__device__ __forceinline__ void loadBf(const u16* bL, int w, int l, s16x8 (&bw)[2][8]){
  const int q=l>>4, ln=l&15, wn0=w*32;
  #pragma unroll
  for (int nt=0;nt<2;nt++)
    #pragma unroll
    for (int kq=0;kq<8;kq++){
      int n = wn0 + nt*16 + ln, ca = kq*4+q;
      bw[nt][kq] = *(const s16x8*)&bL[n*256 + slot8(ca, n)];
    }
}

// acc = A(rows arow0..+31 of aL) @ B(regs), K=256
__device__ __forceinline__ void multAr(const u16* aL, int arow0, const s16x8 (&bw)[2][8],
                                       int l, f32x4 (&acc)[2][2]){
  const int q=l>>4, ln=l&15;
  #pragma unroll
  for (int mt=0;mt<2;mt++)
    #pragma unroll
    for (int nt=0;nt<2;nt++){ acc[mt][nt][0]=0.f; acc[mt][nt][1]=0.f; acc[mt][nt][2]=0.f; acc[mt][nt][3]=0.f; }
  #pragma unroll
  for (int kq=0;kq<8;kq++){
    int ca = kq*4+q;
    s16x8 af[2];
    #pragma unroll
    for (int mt=0;mt<2;mt++){
      int r = arow0 + mt*16 + ln;
      af[mt] = *(const s16x8*)&aL[r*256 + slot8(ca, r)];
    }
    #pragma unroll
    for (int mt=0;mt<2;mt++)
      #pragma unroll
      for (int nt=0;nt<2;nt++)
        acc[mt][nt] = MFMA16(af[mt], bw[nt][kq], acc[mt][nt]);
  }
}

// hacc = H(16 rows of hL) @ B(regs)
__device__ __forceinline__ void multHr(const u16* hL, const s16x8 (&bw)[2][8],
                                       int l, f32x4 (&hacc)[2]){
  const int q=l>>4, ln=l&15;
  hacc[0][0]=0.f; hacc[0][1]=0.f; hacc[0][2]=0.f; hacc[0][3]=0.f;
  hacc[1][0]=0.f; hacc[1][1]=0.f; hacc[1][2]=0.f; hacc[1][3]=0.f;
  #pragma unroll
  for (int kq=0;kq<8;kq++){
    int ca = kq*4+q;
    s16x8 af = *(const s16x8*)&hL[ln*256 + slot8(ca, ln)];
    hacc[0] = MFMA16(af, bw[0][kq], hacc[0]);
    hacc[1] = MFMA16(af, bw[1][kq], hacc[1]);
  }
}

__device__ __forceinline__ void polyinit13(const u16* aL, int arow0, int w, int l, f32x4 (&poly)[2][2]){
  const int q=l>>4, ln=l&15, wn0=w*32;
  #pragma unroll
  for (int mt=0;mt<2;mt++)
  #pragma unroll
  for (int nt=0;nt<2;nt++)
  #pragma unroll
  for (int r=0;r<4;r++){
    int row = arow0 + mt*16 + q*4 + r;
    int col = wn0 + nt*16 + ln;
    poly[mt][nt][r] = 13.f*bf2f(aL[swidx(row,col)]);
  }
}
__device__ __forceinline__ void init13H(const u16* hL, int w, int l, f32x4 (&hpoly)[2]){
  const int q=l>>4, ln=l&15, wn0=w*32;
  #pragma unroll
  for (int nt=0;nt<2;nt++)
  #pragma unroll
  for (int r=0;r<4;r++)
    hpoly[nt][r] = 13.f*bf2f(hL[swidx(q*4+r, wn0+nt*16+ln)]);
}
__device__ __forceinline__ void polyaxpy(f32x4 (&poly)[2][2], const f32x4 (&acc)[2][2], float sc){
  #pragma unroll
  for (int mt=0;mt<2;mt++)
    #pragma unroll
    for (int nt=0;nt<2;nt++)
      #pragma unroll
      for (int r=0;r<4;r++) poly[mt][nt][r] += sc*acc[mt][nt][r];
}
__device__ __forceinline__ void axpyH(f32x4 (&hpoly)[2], const f32x4 (&hacc)[2], float sc){
  #pragma unroll
  for (int nt=0;nt<2;nt++)
    #pragma unroll
    for (int r=0;r<4;r++) hpoly[nt][r] += sc*hacc[nt][r];
}
__device__ __forceinline__ void zeroH(f32x4 (&p)[2]){
  p[0][0]=0.f; p[0][1]=0.f; p[0][2]=0.f; p[0][3]=0.f;
  p[1][0]=0.f; p[1][1]=0.f; p[1][2]=0.f; p[1][3]=0.f;
}
__device__ __forceinline__ void writeT(u16* Ts, const f32x4 (&acc)[2][2], int w, int l, float sc){
  const int q=l>>4, ln=l&15, wn0=w*32;
  #pragma unroll
  for (int mt=0;mt<2;mt++)
  #pragma unroll
  for (int nt=0;nt<2;nt++)
  #pragma unroll
  for (int r=0;r<4;r++){
    int row = mt*16 + q*4 + r;
    int col = wn0 + nt*16 + ln;
    Ts[swidx(row,col)] = f2bf(sc*acc[mt][nt][r]);
  }
}
__device__ __forceinline__ void writeH(u16* Hs, const f32x4 (&hacc)[2], int w, int l){
  const int q=l>>4, ln=l&15, wn0=w*32;
  #pragma unroll
  for (int nt=0;nt<2;nt++)
  #pragma unroll
  for (int r=0;r<4;r++)
    Hs[swidx(q*4+r, wn0+nt*16+ln)] = f2bf(hacc[nt][r]);
}
__device__ __forceinline__ void writeHsc(u16* Hs, const f32x4 (&v)[2], int w, int l, float sc){
  const int q=l>>4, ln=l&15, wn0=w*32;
  #pragma unroll
  for (int nt=0;nt<2;nt++)
  #pragma unroll
  for (int r=0;r<4;r++)
    Hs[swidx(q*4+r, wn0+nt*16+ln)] = f2bf(sc*v[nt][r]);
}
__device__ __forceinline__ void epi_poly(u16* __restrict__ out, int rowbase,
                                         const f32x4 (&poly)[2][2], int w, int l, float sc){
  const int q=l>>4, ln=l&15, wn0=w*32;
  #pragma unroll
  for (int mt=0;mt<2;mt++)
  #pragma unroll
  for (int nt=0;nt<2;nt++)
  #pragma unroll
  for (int r=0;r<4;r++){
    int row = rowbase + mt*16 + q*4 + r;
    int col = wn0 + nt*16 + ln;
    out[(long)row*256 + col] = f2bf(sc*poly[mt][nt][r]);
  }
}
__device__ __forceinline__ void epiH(u16* __restrict__ out, const f32x4 (&hpoly)[2],
                                     int w, int l, float sc){
  const int q=l>>4, ln=l&15, wn0=w*32;
  #pragma unroll
  for (int nt=0;nt<2;nt++)
  #pragma unroll
  for (int r=0;r<4;r++)
    out[(long)(q*4+r)*256 + wn0+nt*16+ln] = f2bf(sc*hpoly[nt][r]);
}

// legacy LDS-B mult (kw0 only: single phase, preload is neutral)
__device__ __forceinline__ void mult32(const u16* aL, int arow0, const u16* bL,
                                       int w, int l, f32x4 (&acc)[2][2]){
  const int q=l>>4, ln=l&15, wn0=w*32;
  #pragma unroll
  for (int mt=0;mt<2;mt++)
    #pragma unroll
    for (int nt=0;nt<2;nt++){ acc[mt][nt][0]=0.f; acc[mt][nt][1]=0.f; acc[mt][nt][2]=0.f; acc[mt][nt][3]=0.f; }
  #pragma unroll
  for (int kq=0;kq<8;kq++){
    int ca = kq*4+q;
    s16x8 af[2];
    #pragma unroll
    for (int mt=0;mt<2;mt++){
      int r = arow0 + mt*16 + ln;
      af[mt] = *(const s16x8*)&aL[r*256 + slot8(ca,r)];
    }
    #pragma unroll
    for (int nt=0;nt<2;nt++){
      int n = wn0 + nt*16 + ln;
      s16x8 bfr = *(const s16x8*)&bL[n*256 + slot8(ca,n)];
      acc[0][nt] = MFMA16(af[0], bfr, acc[0][nt]);
      acc[1][nt] = MFMA16(af[1], bfr, acc[1][nt]);
    }
  }
}

// kw0: W0 = s0*X@X^T slab; self-computed s0 from cs_p; slab0 also preps h0
__global__ __launch_bounds__(512)
void kw0(const float* __restrict__ cs_p, float* __restrict__ scal,
         const float* __restrict__ num_p, const float* __restrict__ den_p,
         const u16* __restrict__ X, u16* __restrict__ W0, u16* __restrict__ h0)
{
  __shared__ __align__(16) u16 Wf[65536];
  __shared__ __align__(16) u16 Ts[8192];
  const int tid=threadIdx.x, w=tid>>6, l=tid&63;
  const int bid=blockIdx.x, xcd=bid&7, j=bid>>3;
  const int batch = xcd*4 + (j>>3), slab = j&7;

  stage256(X + (long)batch*65536, Wf, w, l);   // dma in flight during reduce

  float* red = (float*)Ts;
  float mx = 0.f;
  for (int i=tid;i<8192;i+=512){
    float s = 0.f;
    #pragma unroll
    for (int c=0;c<8;c++) s += cs_p[(long)c*8192 + i];
    mx = fmaxf(mx, s);
  }
  red[tid] = mx; __syncthreads();
  for (int s=256;s>0;s>>=1){ if (tid<s) red[tid] = fmaxf(red[tid], red[tid+s]); __syncthreads(); }
  float s0 = 1.0f/red[0];
  if (bid==0 && tid==0) scal[0] = s0;

  f32x4 acc[2][2];
  mult32(Wf, slab*32, Wf, w, l, acc);
  {
    const int q=l>>4, ln=l&15, wn0=w*32;
    u16* ob = W0 + (long)batch*65536;
    #pragma unroll
    for (int mt=0;mt<2;mt++)
    #pragma unroll
    for (int nt=0;nt<2;nt++)
    #pragma unroll
    for (int r=0;r<4;r++){
      int row = slab*32 + mt*16 + q*4 + r;
      int col = wn0 + nt*16 + ln;
      ob[(long)row*256 + col] = f2bf(acc[mt][nt][r]*s0);
    }
  }

  if (slab==0){
    __syncthreads();
    float (*lt)[257] = (float(*)[257])Wf;
    for (int i=tid;i<8192;i+=512){
      int m = i>>5, d = i&31;
      float sn = 0.f, sd = 0.f;
      #pragma unroll
      for (int c=0;c<8;c++){
        sn += num_p[((long)(c*32+batch))*8192 + i];
        sd += den_p[(c*32+batch)*256 + m];
      }
      lt[d][m] = sn/sd;
    }
    __syncthreads();
    u16* o = h0 + (long)batch*8192;
    for (int j2=tid;j2<8192;j2+=512){
      int d = j2>>8, m = j2&255;
      o[j2] = f2bf(lt[d][m]);
    }
  }
}

// kiter: one Newton iteration. 256 blocks x 512 thr; slab0/slab4 advance h halves.
__global__ __launch_bounds__(512)
void kiter(const u16* __restrict__ Win, u16* __restrict__ Wout,
           const u16* __restrict__ hin, u16* __restrict__ hout)
{
  __shared__ __align__(16) u16 Wf[65536];
  __shared__ __align__(16) u16 Ts[8192];
  __shared__ __align__(16) u16 Hs[4096];
  const int tid=threadIdx.x, w=tid>>6, l=tid&63;
  const int bid=blockIdx.x, xcd=bid&7, j=bid>>3;
  const int batch = xcd*4 + (j>>3), slab = j&7;
  const bool hrole = (slab&3)==0;              // slabs 0 and 4
  const int hr0 = (slab>>2)*16;

  stage256(Win + (long)batch*65536, Wf, w, l);
  if (hrole) stage16(hin + (long)batch*8192 + hr0*256, Hs, w, l);
  __syncthreads();

  s16x8 bw[2][8];
  loadBf(Wf, w, l, bw);

  f32x4 acc[2][2], poly[2][2];
  f32x4 hacc[2], hpoly[2];

  polyinit13(Wf, slab*32, w, l, poly);
  multAr(Wf, slab*32, bw, l, acc);             // t1 = Wslab@W
  polyaxpy(poly, acc, -15.f);
  if (hrole){
    init13H(Hs, w, l, hpoly);
    multHr(Hs, bw, l, hacc);                   // h@W
    axpyH(hpoly, hacc, -15.f);
    __syncthreads();                           // Hs reads done before writeH
  }
  // (non-hrole: Ts has no prior readers -> no barrier needed; hrole is
  //  block-uniform so the conditional barrier is legal)
  writeT(Ts, acc, w, l, 1.f);
  if (hrole) writeH(Hs, hacc, w, l);
  __syncthreads();
  multAr(Ts, 0, bw, l, acc);                   // t2
  polyaxpy(poly, acc, 7.f);
  if (hrole){ multHr(Hs, bw, l, hacc); axpyH(hpoly, hacc, 7.f); }
  __syncthreads();
  writeT(Ts, acc, w, l, 1.f);
  if (hrole) writeH(Hs, hacc, w, l);
  __syncthreads();
  multAr(Ts, 0, bw, l, acc);                   // t3
  polyaxpy(poly, acc, -1.f);
  epi_poly(Wout + (long)batch*65536, slab*32, poly, w, l, 0.25f);
  if (hrole){
    multHr(Hs, bw, l, hacc);
    axpyH(hpoly, hacc, -1.f);
    epiH(hout + (long)batch*8192 + hr0*256, hpoly, w, l, 0.25f);
  }
}

// ---------------------------------------------------------------------------
// ktail2: fused {iteration 5 h-advance + tail} with W5 never materialized.
// ---------------------------------------------------------------------------
__global__ __launch_bounds__(512)
void ktail2(const u16* __restrict__ W4, const u16* __restrict__ h4,
            const u16* __restrict__ XT, const float* __restrict__ scal,
            u16* __restrict__ uT)
{
  __shared__ __align__(16) u16 Wf[65536];
  __shared__ __align__(16) u16 Ha[4096];
  __shared__ __align__(16) u16 Hb[4096];
  const int tid=threadIdx.x, w=tid>>6, l=tid&63;
  const int batch = blockIdx.x>>1, half = blockIdx.x&1;

  stage256(W4 + (long)batch*65536, Wf, w, l);
  stage16(h4 + (long)batch*8192 + half*4096, Ha, w, l);
  __syncthreads();

  s16x8 bw[2][8];
  loadBf(Wf, w, l, bw);
  __syncthreads();                              // all W4 reads from Wf done
  stage256(XT + (long)batch*65536, Wf, w, l);   // async; drained by later barriers

  f32x4 acc[2], poly[2], gpoly[2];

  // ---- h5 = 0.25(13h4 -15 h4W +7 h4W^2 - h4W^3) ----
  init13H(Ha, w, l, poly);
  multHr(Ha, bw, l, acc); axpyH(poly, acc, -15.f);
  writeH(Hb, acc, w, l); __syncthreads();
  multHr(Hb, bw, l, acc); axpyH(poly, acc, 7.f);
  writeH(Ha, acc, w, l); __syncthreads();
  multHr(Ha, bw, l, acc); axpyH(poly, acc, -1.f);
  zeroH(gpoly); axpyH(gpoly, poly, 3.25f);      // gpoly = 13*h5
  writeHsc(Hb, poly, w, l, 0.25f); __syncthreads();   // Hb = r(h5)

  // ---- a = (h5@W4)*Q(W4) ----
  multHr(Hb, bw, l, acc); zeroH(poly); axpyH(poly, acc, 13.f);
  writeH(Ha, acc, w, l); __syncthreads();
  multHr(Ha, bw, l, acc); axpyH(poly, acc, -15.f);
  writeH(Hb, acc, w, l); __syncthreads();
  multHr(Hb, bw, l, acc); axpyH(poly, acc, 7.f);
  writeH(Ha, acc, w, l); __syncthreads();
  multHr(Ha, bw, l, acc); axpyH(poly, acc, -1.f);
  axpyH(gpoly, poly, -3.75f);                   // gpoly += -15*a
  writeHsc(Hb, poly, w, l, 0.25f); __syncthreads();   // Hb = r(a)

  // ---- b = (a@W4)*Q(W4) ----
  multHr(Hb, bw, l, acc); zeroH(poly); axpyH(poly, acc, 13.f);
  writeH(Ha, acc, w, l); __syncthreads();
  multHr(Ha, bw, l, acc); axpyH(poly, acc, -15.f);
  writeH(Hb, acc, w, l); __syncthreads();
  multHr(Hb, bw, l, acc); axpyH(poly, acc, 7.f);
  writeH(Ha, acc, w, l); __syncthreads();
  multHr(Ha, bw, l, acc); axpyH(poly, acc, -1.f);
  axpyH(gpoly, poly, 1.75f);                    // gpoly += 7*b
  writeHsc(Hb, poly, w, l, 0.25f); __syncthreads();   // Hb = r(b)

  // ---- c = (b@W4)*Q(W4) ----
  multHr(Hb, bw, l, acc); zeroH(poly); axpyH(poly, acc, 13.f);
  writeH(Ha, acc, w, l); __syncthreads();
  multHr(Ha, bw, l, acc); axpyH(poly, acc, -15.f);
  writeH(Hb, acc, w, l); __syncthreads();
  multHr(Hb, bw, l, acc); axpyH(poly, acc, 7.f);
  writeH(Ha, acc, w, l); __syncthreads();
  multHr(Ha, bw, l, acc); axpyH(poly, acc, -1.f);
  axpyH(gpoly, poly, -0.25f);                   // gpoly += -c
  writeHsc(Hb, gpoly, w, l, 0.25f); __syncthreads();  // Hb = r(g1)

  // ---- u = s0 * g1 @ X  (B-frags from XT, now resident in Wf) ----
  loadBf(Wf, w, l, bw);
  multHr(Hb, bw, l, acc);
  epiH(uT + (long)batch*8192 + half*4096, acc, w, l, scal[0]);
}

// ---------------------------------------------------------------------------
// Merged attn2 + attn3v (independent; grid (16,32): x<8 attn2, x>=8 attn3v)
// ---------------------------------------------------------------------------
__global__ __launch_bounds__(256)
void kattn23(const u16* __restrict__ ql, const u16* __restrict__ kl,
             u16* __restrict__ X, u16* __restrict__ XT, float* __restrict__ cs_p,
             const u16* __restrict__ kk, const u16* __restrict__ vv,
             float* __restrict__ num_p, float* __restrict__ den_p)
{
  __shared__ __align__(16) u16 Pbuf[4][64][40];
  __shared__ __align__(16) u16 vT[32][40];
  __shared__ float qrow[32][33];
  __shared__ float psum[32][4];
  __shared__ float rsum[32];
  int bh = blockIdx.y;
  int tid = threadIdx.x, w = tid>>6, l = tid&63, q = l>>4, ln = l&15;

  if (blockIdx.x < 8){
    int r0 = blockIdx.x*32;
    int c = tid;
    #pragma unroll
    for (int i=0;i<4;i++){
      int e = c*4+i; int rr = e>>5, dd = e&31;
      qrow[rr][dd] = bf2f(ql[((long)bh*256 + r0+rr)*32 + dd]);
    }
    float kc[32];
    {
      const u16* kp = kl + ((long)bh*256 + c)*32;
      #pragma unroll
      for (int d=0;d<32;d++) kc[d] = bf2f(kp[d]);
    }
    __syncthreads();
    float er[32]; float colacc = 0.f;
    for (int r=0;r<32;r++){
      float s = 0.f;
      #pragma unroll
      for (int d=0;d<32;d++) s += qrow[r][d]*kc[d];
      float e = __expf(s);
      er[r] = e;
      float wsum = e;
      #pragma unroll
      for (int m=1;m<64;m<<=1) wsum += __shfl_xor(wsum, m);
      if (l==0) psum[r][w] = wsum;
    }
    __syncthreads();
    if (c<32) rsum[c] = psum[c][0]+psum[c][1]+psum[c][2]+psum[c][3];
    __syncthreads();
    for (int r=0;r<32;r++){
      float x = er[r]/rsum[r];
      u16 xb = f2bf(x);
      X [((long)bh*256 + r0+r)*256 + c] = xb;
      XT[((long)bh*256 + c)*256 + r0+r] = xb;
      colacc += x;
    }
    cs_p[(long)blockIdx.x*8192 + bh*256 + c] = colacc;
    return;
  }

  int chunk = blockIdx.x - 8;
  f32x4 z4; z4[0]=0.f; z4[1]=0.f; z4[2]=0.f; z4[3]=0.f;
  f32x4 acc[4][2]; f32x4 dacc[4];
  #pragma unroll
  for (int mt=0;mt<4;mt++){ dacc[mt]=z4; acc[mt][0]=z4; acc[mt][1]=z4; }
  const u16* qlb = ql + (long)bh*8192;
  const u16* kb  = kk + (long)bh*131072;
  const u16* vb  = vv + (long)bh*131072;
  int vn = tid>>3, vd = (tid&7)*4;
  for (int s=0;s<16;s++){
    int n0 = chunk*512 + s*32;
    ushort4 vx = *(const ushort4*)(vb + (long)(n0+vn)*32 + vd);
    vT[vd+0][vn]=vx.x; vT[vd+1][vn]=vx.y; vT[vd+2][vn]=vx.z; vT[vd+3][vn]=vx.w;
    __syncthreads();
    s16x8 bk[2];
    #pragma unroll
    for (int nt=0;nt<2;nt++) bk[nt] = *(const s16x8*)(kb + (long)(n0 + nt*16 + ln)*32 + q*8);
    #pragma unroll
    for (int mt=0;mt<4;mt++){
      s16x8 aq = *(const s16x8*)(qlb + (long)(w*64 + mt*16 + ln)*32 + q*8);
      #pragma unroll
      for (int nt=0;nt<2;nt++){
        f32x4 sf = MFMA16(aq, bk[nt], z4);
        f32x4 ef;
        #pragma unroll
        for (int r=0;r<4;r++) ef[r] = __expf(sf[r]);
        dacc[mt] += ef;
        #pragma unroll
        for (int r=0;r<4;r++) Pbuf[w][mt*16 + q*4 + r][nt*16 + ln] = f2bf(ef[r]);
      }
    }
    #pragma unroll
    for (int mt=0;mt<4;mt++){
      s16x8 ap = *(const s16x8*)&Pbuf[w][mt*16 + ln][q*8];
      #pragma unroll
      for (int nt=0;nt<2;nt++){
        s16x8 bv = *(const s16x8*)&vT[nt*16 + ln][q*8];
        acc[mt][nt] = MFMA16(ap, bv, acc[mt][nt]);
      }
    }
    __syncthreads();
  }
  #pragma unroll
  for (int mt=0;mt<4;mt++)
    #pragma unroll
    for (int r=0;r<4;r++){
      float x = dacc[mt][r];
      x += __shfl_xor(x,1); x += __shfl_xor(x,2); x += __shfl_xor(x,4); x += __shfl_xor(x,8);
      dacc[mt][r] = x;
    }
  long pbase = (long)(chunk*32 + bh);
  #pragma unroll
  for (int mt=0;mt<4;mt++)
    #pragma unroll
    for (int nt=0;nt<2;nt++)
      #pragma unroll
      for (int r=0;r<4;r++){
        int mg = w*64 + mt*16 + q*4 + r;
        num_p[pbase*8192 + (long)mg*32 + nt*16 + ln] = acc[mt][nt][r];
      }
  if (ln==0){
    #pragma unroll
    for (int mt=0;mt<4;mt++)
      #pragma unroll
      for (int r=0;r<4;r++)
        den_p[pbase*256 + w*64 + mt*16 + q*4 + r] = dacc[mt][r];
  }
}

// ---------------------------------------------------------------------------
// attn1 fused + depthwise residual conv
// ---------------------------------------------------------------------------
__global__ __launch_bounds__(256)
void kattn1u(const u16* __restrict__ qq, const u16* __restrict__ kl, const u16* __restrict__ uT,
             const u16* __restrict__ vv, const float* __restrict__ rw,
             u16* __restrict__ aoutb)
{
  int nch = blockIdx.x, bh = blockIdx.y;
  int b = bh>>3, h = bh&7;
  int tid = threadIdx.x, w = tid>>6, l = tid&63, q = l>>4, ln = l&15;
  __shared__ __align__(16) u16 Pbuf[4][32][40];
  __shared__ __align__(16) u16 vtile[160][36];
  int r0g = nch*128;
  const u16* vb = vv + (long)bh*131072;
  #pragma unroll
  for (int it=0; it<5; it++){
    int slot = tid + it*256;
    int rr = slot>>3, c = (slot&7)*4;
    int s = r0g - 16 + rr;
    ushort4 val; val.x=0; val.y=0; val.z=0; val.w=0;
    if (s>=0 && s<4096) val = *(const ushort4*)(vb + (long)s*32 + c);
    *(ushort4*)&vtile[rr][c] = val;
  }
  __syncthreads();

  f32x4 z4; z4[0]=0.f; z4[1]=0.f; z4[2]=0.f; z4[3]=0.f;
  f32x4 acc[2][2]; f32x4 dacc[2];
  #pragma unroll
  for (int mt=0;mt<2;mt++){ dacc[mt]=z4; acc[mt][0]=z4; acc[mt][1]=z4; }
  const u16* qb  = qq + (long)bh*131072;
  const u16* klb = kl + (long)bh*8192;
  const u16* ub  = uT + (long)bh*8192;
  int r0 = r0g + w*32;
  for (int s=0;s<8;s++){
    s16x8 bk[2];
    #pragma unroll
    for (int nt=0;nt<2;nt++) bk[nt] = *(const s16x8*)(klb + (long)(s*32 + nt*16 + ln)*32 + q*8);
    #pragma unroll
    for (int mt=0;mt<2;mt++){
      s16x8 aq = *(const s16x8*)(qb + (long)(r0 + mt*16 + ln)*32 + q*8);
      #pragma unroll
      for (int nt=0;nt<2;nt++){
        f32x4 sf = MFMA16(aq, bk[nt], z4);
        f32x4 ef;
        #pragma unroll
        for (int r=0;r<4;r++) ef[r] = __expf(sf[r]);
        dacc[mt] += ef;
        #pragma unroll
        for (int r=0;r<4;r++) Pbuf[w][mt*16 + q*4 + r][nt*16 + ln] = f2bf(ef[r]);
      }
    }
    #pragma unroll
    for (int mt=0;mt<2;mt++){
      s16x8 ap = *(const s16x8*)&Pbuf[w][mt*16 + ln][q*8];
      #pragma unroll
      for (int nt=0;nt<2;nt++){
        s16x8 bu = *(const s16x8*)(ub + (long)(nt*16 + ln)*256 + s*32 + q*8);
        acc[mt][nt] = MFMA16(ap, bu, acc[mt][nt]);
      }
    }
  }
  #pragma unroll
  for (int mt=0;mt<2;mt++)
    #pragma unroll
    for (int r=0;r<4;r++){
      float x = dacc[mt][r];
      x += __shfl_xor(x,1); x += __shfl_xor(x,2); x += __shfl_xor(x,4); x += __shfl_xor(x,8);
      dacc[mt][r] = x;
    }

  const float* wp = rw + h*33;
  float w_[33];
  #pragma unroll
  for (int j=0;j<33;j++) w_[j] = wp[j];

  #pragma unroll
  for (int mt=0;mt<2;mt++){
    int nl = w*32 + mt*16 + q*4;
    #pragma unroll
    for (int nt=0;nt<2;nt++){
      int d = nt*16 + ln;
      float vvv[36];
      #pragma unroll
      for (int j=0;j<36;j++) vvv[j] = bf2f(vtile[nl + j][d]);
      #pragma unroll
      for (int r=0;r<4;r++){
        float cv = 0.f;
        #pragma unroll
        for (int j=0;j<33;j++) cv += w_[j]*vvv[r+j];
        int n = r0 + mt*16 + q*4 + r;
        long oidx = ((long)b*4096 + n)*256 + h*32 + d;
        aoutb[oidx] = f2bf(acc[mt][nt][r]/dacc[mt][r] + cv);
      }
    }
  }
}

// ---------------------------------------------------------------------------
// Merged: LN(x) (blocks 0..4095) + weight transpose/cast (blocks 4096..5119)
// ---------------------------------------------------------------------------
__global__ __launch_bounds__(256)
void kcvtln(const float* __restrict__ xin, const float* __restrict__ lg, const float* __restrict__ lb,
            u16* __restrict__ xn,
            const float* __restrict__ wqkv, const float* __restrict__ wout,
            const float* __restrict__ w1, const float* __restrict__ w2,
            u16* __restrict__ wqkvT, u16* __restrict__ woutT,
            u16* __restrict__ w1T, u16* __restrict__ w2T)
{
  __shared__ float t[32][33];
  int z = blockIdx.x;
  if (z < 4096){
    int w = threadIdx.x>>6, l = threadIdx.x&63;
    long row = (long)z*4 + w;
    float4 v = ((const float4*)(xin + row*256))[l];
    float s = v.x+v.y+v.z+v.w;
    #pragma unroll
    for (int m=1;m<64;m<<=1) s += __shfl_xor(s, m);
    float mu = s*(1.0f/256.0f);
    float dx=v.x-mu, dy=v.y-mu, dz=v.z-mu, dw=v.w-mu;
    float s2 = dx*dx+dy*dy+dz*dz+dw*dw;
    #pragma unroll
    for (int m=1;m<64;m<<=1) s2 += __shfl_xor(s2, m);
    float rs = rsqrtf(s2*(1.0f/256.0f) + 1e-5f);
    float4 gg = ((const float4*)lg)[l];
    float4 bb = ((const float4*)lb)[l];
    ushort4 o;
    o.x = f2bf(dx*rs*gg.x + bb.x);
    o.y = f2bf(dy*rs*gg.y + bb.y);
    o.z = f2bf(dz*rs*gg.z + bb.z);
    o.w = f2bf(dw*rs*gg.w + bb.w);
    *(ushort4*)(xn + row*256 + l*4) = o;
    return;
  }
  z -= 4096;
  const float* src; u16* dst; int K, Nn, bx, by;
  if (z < 384){      int i=z/192, r=z%192; src=wqkv+(long)i*196608; dst=wqkvT+(long)i*196608; K=256; Nn=768; bx=r%24; by=r/24; }
  else if (z < 512){ int zz=z-384; int i=zz/64, r=zz%64; src=wout+(long)i*65536; dst=woutT+(long)i*65536; K=256; Nn=256; bx=r%8; by=r/8; }
  else if (z < 768){ int zz=z-512; int i=zz/128, r=zz%128; src=w1+(long)i*131072; dst=w1T+(long)i*131072; K=256; Nn=512; bx=r%16; by=r/16; }
  else {             int zz=z-768; int i=zz/128, r=zz%128; src=w2+(long)i*131072; dst=w2T+(long)i*131072; K=512; Nn=256; bx=r%8; by=r/8; }
  int n0 = bx*32, k0 = by*32;
  int tx = threadIdx.x&31, ty = threadIdx.x>>5;
  #pragma unroll
  for (int i=0;i<4;i++) t[ty+i*8][tx] = src[(long)(k0+ty+i*8)*Nn + n0+tx];
  __syncthreads();
  #pragma unroll
  for (int i=0;i<4;i++) dst[(long)(n0+ty+i*8)*K + k0+tx] = f2bf(t[tx][ty+i*8]);
}

// ---------------------------------------------------------------------------
extern "C" void kernel_launch(void* const* d_in, const int* in_sizes, int n_in,
                              void* d_out, int out_size, void* d_ws, size_t ws_size,
                              hipStream_t stream)
{
  const float* x    = (const float*)d_in[0];
  const float* ln1g = (const float*)d_in[1];
  const float* ln1b = (const float*)d_in[2];
  const float* wqkv = (const float*)d_in[3];
  const float* wout = (const float*)d_in[4];
  const float* bout = (const float*)d_in[5];
  const float* resw = (const float*)d_in[6];
  const float* ln2g = (const float*)d_in[7];
  const float* ln2b = (const float*)d_in[8];
  const float* w1   = (const float*)d_in[9];
  const float* b1   = (const float*)d_in[10];
  const float* w2   = (const float*)d_in[11];
  const float* b2   = (const float*)d_in[12];
  float* y = (float*)d_out;
  char* ws = (char*)d_ws;

  u16* xn    = (u16*)(ws + 0);
  u16* qb    = (u16*)(ws + 8388608);
  u16* kb    = (u16*)(ws + 16777216);
  u16* vb    = (u16*)(ws + 25165824);
  u16* ql    = (u16*)(ws + 33554432);
  u16* kl    = (u16*)(ws + 34078720);
  u16* X     = (u16*)(ws + 34603008);
  u16* XT    = (u16*)(ws + 38797312);     // X^T (B-operand of final U GEMM)
  u16* h0b   = (u16*)(ws + 42991616);     // h0 [32][32][256] bf16 (512 KB)
  // pinv work region
  u16* WA    = (u16*)(ws + 51380224);
  u16* WB    = (u16*)(ws + 55574528);
  u16* hA    = (u16*)(ws + 68157440);     // thin h buffers [32][32][256]
  u16* hB    = (u16*)(ws + 72351744);
  float* num_p = (float*)(ws + 76546048);  // 8 MB
  float* den_p = (float*)(ws + 84934656);
  float* cs_p  = (float*)(ws + 85196800);
  float* scal  = (float*)(ws + 85458944);
  u16* uT    = (u16*)(ws + 85459200);
  u16* aoutb = (u16*)(ws + 85983488);
  u16* wqkvT = (u16*)(ws + 94372096);
  u16* woutT = (u16*)(ws + 95158528);
  u16* w1T   = (u16*)(ws + 95420672);
  u16* w2T   = (u16*)(ws + 95944960);
  u16* hdn   = (u16*)(ws + 51380224);      // overlays WA/WB (dead by FFN)

  (void)in_sizes; (void)n_in; (void)out_size; (void)ws_size;

  // LN(x) + weight cvt in one launch
  kcvtln<<<5120,256,0,stream>>>(x, ln1g, ln1b, xn,
      wqkv, wout, w1, w2, wqkvT, woutT, w1T, w2T);

  for (int i=0;i<2;i++){
    // xn: i==0 from kcvtln; i==1 from previous FFN2's fused LN epilogue
    kgemm2<EPI_QKV><<<dim3(128,6),256,0,stream>>>(xn, wqkvT + (long)i*196608, 256, 256, 256,
        nullptr, nullptr, 0, qb,kb,vb, ql,kl);
    kattn23<<<dim3(16,32),256,0,stream>>>(ql, kl, X, XT, cs_p, kb, vb, num_p, den_p);

    // ---- pinv: kw0 (scal + W0 + h0) -> 4x kiter -> ktail2 (iter5-h + tail) ----
    kw0<<<256,512,0,stream>>>(cs_p, scal, num_p, den_p, X, WA, h0b);
    u16 *Wi = WA, *Wo = WB, *hi = h0b, *ho = hA;
    for (int it=0; it<4; it++){
      kiter<<<256,512,0,stream>>>(Wi, Wo, hi, ho);
      u16* t = Wi; Wi = Wo; Wo = t;
      hi = ho; ho = (ho == hA) ? hB : hA;
    }
    ktail2<<<64,512,0,stream>>>(Wi, hi, XT, scal, uT);

    kattn1u<<<dim3(32,32),256,0,stream>>>(qb, kl, uT, vb, resw + i*264, aoutb);
    // wout GEMM + residual + LN2 fused -> y (f32) + xn (bf16 for FFN1)
    kgemmLN<1><<<256,256,0,stream>>>(aoutb, woutT + (long)i*65536, 256,
        bout + i*256, i==0 ? x : y, y, ln2g + i*256, ln2b + i*256, xn);
    kgemm2<EPI_BIAS_GELU><<<dim3(128,4),256,0,stream>>>(xn, w1T + (long)i*131072, 256, 256, 256,
        b1 + i*512, hdn, 512, nullptr,nullptr,nullptr, nullptr,nullptr);
    // FFN2 GEMM + residual (+ LN1(next) only when consumed)
    if (i==0)
      kgemmLN<1><<<256,256,0,stream>>>(hdn, w2T + (long)i*131072, 512,
          b2 + i*256, y, y, ln1g + 256, ln1b + 256, xn);
    else
      kgemmLN<0><<<256,256,0,stream>>>(hdn, w2T + (long)i*131072, 512,
          b2 + i*256, y, y, ln1g + 256, ln1b + 256, xn);
  }
}

// Round 11
// 476.460 us; speedup vs baseline: 1.3033x; 1.0343x over previous
//
#include <hip/hip_runtime.h>
#include <math.h>

typedef float f32x4 __attribute__((ext_vector_type(4)));
typedef short s16x8 __attribute__((ext_vector_type(8)));
typedef unsigned short u16;
typedef unsigned int u32;

#define MFMA16(a,b,c) __builtin_amdgcn_mfma_f32_16x16x32_bf16((a),(b),(c),0,0,0)
#define AS1 __attribute__((address_space(1)))
#define AS3 __attribute__((address_space(3)))

__device__ __forceinline__ void dma16(const u16* g, u16* l){
  __builtin_amdgcn_global_load_lds((const AS1 u32*)g, (AS3 u32*)l, 16, 0, 0);
}

__device__ __forceinline__ float bf2f(u16 u){
  union { unsigned int i; float f; } v; v.i = ((unsigned int)u)<<16; return v.f;
}
__device__ __forceinline__ u16 f2bf(float f){
  union { float f; unsigned int i; } v; v.f = f;
  unsigned int x = v.i;
  return (u16)((x + 0x7fffu + ((x>>16)&1u))>>16);
}

enum { EPI_QKV=0, EPI_BIAS_GELU=3 };

// ---------------------------------------------------------------------------
// kgemm2: BM=128, BN=128, BK=32, 4x4 frags/wave; DMA staging + swizzle.
// ---------------------------------------------------------------------------
template<int EPI>
__global__ __launch_bounds__(256)
void kgemm2(const u16* __restrict__ A, const u16* __restrict__ BT, int K, int lda, int ldb,
            const float* __restrict__ bias, u16* __restrict__ outb, int ldc,
            u16* __restrict__ qo, u16* __restrict__ ko, u16* __restrict__ vo,
            u16* __restrict__ qlm, u16* __restrict__ klm)
{
  __shared__ __align__(16) u16 As[128*32];
  __shared__ __align__(16) u16 Bs[128*32];
  const int tid = threadIdx.x;
  const int w = tid>>6, wy = w>>1, wx = w&1, l = tid&63, q = l>>4, ln = l&15;
  const int m0 = blockIdx.x*128, n0 = blockIdx.y*128;
  const int lrow = l>>2, lch = l&3;

  f32x4 acc[4][4];
  #pragma unroll
  for (int i=0;i<4;i++)
    #pragma unroll
    for (int j=0;j<4;j++){ acc[i][j][0]=0.f; acc[i][j][1]=0.f; acc[i][j][2]=0.f; acc[i][j][3]=0.f; }

  for (int k0=0; k0<K; k0+=32){
    #pragma unroll
    for (int c=0;c<2;c++){
      int row = 32*w + 16*c + lrow;
      int gch = lch ^ ((row>>1)&3);
      dma16(A + (long)(m0+row)*lda + k0 + gch*8, &As[(32*w+16*c)*32]);
      dma16(BT + (long)(n0+row)*ldb + k0 + gch*8, &Bs[(32*w+16*c)*32]);
    }
    __syncthreads();
    s16x8 af[4], bfr[4];
    #pragma unroll
    for (int mt=0;mt<4;mt++){
      int row = wy*64 + mt*16 + ln;
      af[mt] = *(const s16x8*)&As[row*32 + ((q ^ ((row>>1)&3))<<3)];
    }
    #pragma unroll
    for (int nt=0;nt<4;nt++){
      int row = wx*64 + nt*16 + ln;
      bfr[nt] = *(const s16x8*)&Bs[row*32 + ((q ^ ((row>>1)&3))<<3)];
    }
    #pragma unroll
    for (int mt=0;mt<4;mt++)
      #pragma unroll
      for (int nt=0;nt<4;nt++)
        acc[mt][nt] = MFMA16(af[mt], bfr[nt], acc[mt][nt]);
    __syncthreads();
  }

  #pragma unroll
  for (int mt=0;mt<4;mt++)
  #pragma unroll
  for (int nt=0;nt<4;nt++){
    int ncol = n0 + wx*64 + nt*16 + ln;
    if (EPI==EPI_QKV){
      int sel = ncol>>8, hd = ncol&255, h = hd>>5, d = hd&31;
      u16* dst = sel==0 ? qo : (sel==1 ? ko : vo);
      float sc2 = (sel==0) ? 0.17677669529663689f : 1.f;   // dh^-0.5 on q
      float s = 0.f;
      #pragma unroll
      for (int r=0;r<4;r++){
        int mrow = m0 + wy*64 + mt*16 + q*4 + r;
        int b = mrow>>12, n = mrow&4095;
        float v = acc[mt][nt][r]*sc2;
        dst[(((long)(b*8+h)*4096 + n)<<5) + d] = f2bf(v);
        s += v;
      }
      if (sel < 2){
        s += __shfl_xor(s, 16);
        s += __shfl_xor(s, 32);
        if (q == 0){
          int mrow0 = m0 + wy*64 + mt*16;
          int b = mrow0>>12, grp = (mrow0&4095)>>4;
          u16* ldst = (sel==0) ? qlm : klm;
          ldst[(((long)(b*8+h)*256 + grp)<<5) + d] = f2bf(s*(1.0f/16.0f));
        }
      }
    } else { // EPI_BIAS_GELU
      #pragma unroll
      for (int r=0;r<4;r++){
        int mrow = m0 + wy*64 + mt*16 + q*4 + r;
        float x = acc[mt][nt][r] + bias[ncol];
        float g = 0.5f*x*(1.0f + erff(x*0.70710678118654752f));
        outb[(long)mrow*ldc + ncol] = f2bf(g);
      }
    }
  }
}

// ---------------------------------------------------------------------------
// kgemmLN: BM=64, BN=256 (full rows per block, 256 blocks = full GPU = 1/CU),
// BK=64 (half the stage/barrier roundtrips; LDS growth free at 1 block/CU),
// 4x4 frags/wave; residual+bias, then (if WXN) in-register LayerNorm with
// cross-wave combine -> writes y (f32) AND xn=LN(y) (bf16).
// Staging/frag addressing: proven pinv 8-chunk XOR (row stride 128B,
// ch ^ ((row>>1)&7)). Accumulation order over k unchanged -> bit-identical.
// ---------------------------------------------------------------------------
template<int WXN>
__global__ __launch_bounds__(256)
void kgemmLN(const u16* __restrict__ A, const u16* __restrict__ BT, int K,
             const float* __restrict__ bias, const float* __restrict__ base,
             float* __restrict__ yout,
             const float* __restrict__ lng, const float* __restrict__ lnb,
             u16* __restrict__ xnout)
{
  __shared__ __align__(16) u16 As[64*64];     // 8 KB
  __shared__ __align__(16) u16 Bs[256*64];    // 32 KB
  __shared__ float red[64][4];
  const int tid = threadIdx.x;
  const int w = tid>>6, l = tid&63, q = l>>4, ln = l&15;
  const int m0 = blockIdx.x*64;
  const int drow = l>>3, dch = l&7;

  f32x4 acc[4][4];   // row = mt*16+q*4+r, col = w*64+nt*16+ln
  #pragma unroll
  for (int i=0;i<4;i++)
    #pragma unroll
    for (int j=0;j<4;j++){ acc[i][j][0]=0.f; acc[i][j][1]=0.f; acc[i][j][2]=0.f; acc[i][j][3]=0.f; }

  for (int k0=0; k0<K; k0+=64){
    #pragma unroll
    for (int c=0;c<2;c++){
      int row = c*32 + w*8 + drow;
      int gch = dch ^ ((row>>1)&7);
      dma16(A + (long)(m0+row)*K + k0 + gch*8, &As[(c*32+w*8)*64]);
    }
    #pragma unroll
    for (int c=0;c<8;c++){
      int row = c*32 + w*8 + drow;
      int gch = dch ^ ((row>>1)&7);
      dma16(BT + (long)row*K + k0 + gch*8, &Bs[(c*32+w*8)*64]);
    }
    __syncthreads();
    #pragma unroll
    for (int kb=0;kb<2;kb++){
      s16x8 af[4], bfr[4];
      #pragma unroll
      for (int mt=0;mt<4;mt++){
        int row = mt*16 + ln;
        af[mt] = *(const s16x8*)&As[row*64 + (((kb*4+q) ^ ((row>>1)&7))<<3)];
      }
      #pragma unroll
      for (int nt=0;nt<4;nt++){
        int row = w*64 + nt*16 + ln;
        bfr[nt] = *(const s16x8*)&Bs[row*64 + (((kb*4+q) ^ ((row>>1)&7))<<3)];
      }
      #pragma unroll
      for (int mt=0;mt<4;mt++)
        #pragma unroll
        for (int nt=0;nt<4;nt++)
          acc[mt][nt] = MFMA16(af[mt], bfr[nt], acc[mt][nt]);
    }
    __syncthreads();
  }

  // residual + bias, write y
  float rb[4];
  #pragma unroll
  for (int nt=0;nt<4;nt++) rb[nt] = bias[w*64 + nt*16 + ln];
  #pragma unroll
  for (int mt=0;mt<4;mt++)
  #pragma unroll
  for (int r=0;r<4;r++){
    long rowb = (long)(m0 + mt*16 + q*4 + r)*256;
    #pragma unroll
    for (int nt=0;nt<4;nt++){
      int col = w*64 + nt*16 + ln;
      float v = base[rowb + col] + acc[mt][nt][r] + rb[nt];
      acc[mt][nt][r] = v;
      yout[rowb + col] = v;
    }
  }
  if (!WXN) return;
  // mean: per-lane over 4 nt, 16-lane shuffle, cross-wave via red
  #pragma unroll
  for (int mt=0;mt<4;mt++)
  #pragma unroll
  for (int r=0;r<4;r++){
    float s = acc[mt][0][r]+acc[mt][1][r]+acc[mt][2][r]+acc[mt][3][r];
    s += __shfl_xor(s,1); s += __shfl_xor(s,2); s += __shfl_xor(s,4); s += __shfl_xor(s,8);
    if (ln==0) red[mt*16+q*4+r][w] = s;
  }
  __syncthreads();
  float mu[4][4];
  #pragma unroll
  for (int mt=0;mt<4;mt++)
  #pragma unroll
  for (int r=0;r<4;r++){
    int row = mt*16+q*4+r;
    mu[mt][r] = (red[row][0]+red[row][1]+red[row][2]+red[row][3])*(1.0f/256.0f);
  }
  __syncthreads();
  #pragma unroll
  for (int mt=0;mt<4;mt++)
  #pragma unroll
  for (int r=0;r<4;r++){
    float vs = 0.f;
    #pragma unroll
    for (int nt=0;nt<4;nt++){ float d = acc[mt][nt][r]-mu[mt][r]; vs += d*d; }
    vs += __shfl_xor(vs,1); vs += __shfl_xor(vs,2); vs += __shfl_xor(vs,4); vs += __shfl_xor(vs,8);
    if (ln==0) red[mt*16+q*4+r][w] = vs;
  }
  __syncthreads();
  float rg[4], rbb[4];
  #pragma unroll
  for (int nt=0;nt<4;nt++){ int col = w*64+nt*16+ln; rg[nt]=lng[col]; rbb[nt]=lnb[col]; }
  #pragma unroll
  for (int mt=0;mt<4;mt++)
  #pragma unroll
  for (int r=0;r<4;r++){
    int row = mt*16+q*4+r;
    float rs = rsqrtf((red[row][0]+red[row][1]+red[row][2]+red[row][3])*(1.0f/256.0f) + 1e-5f);
    long rowb = (long)(m0 + row)*256;
    #pragma unroll
    for (int nt=0;nt<4;nt++){
      int col = w*64 + nt*16 + ln;
      float d = acc[mt][nt][r]-mu[mt][r];
      xnout[rowb + col] = f2bf(d*rs*rg[nt] + rbb[nt]);
    }
  }
}

// ---------------------------------------------------------------------------
// Fused pinv: full 256x256 W resident in LDS + reg-cached B frags.
// 512 threads (8 waves). W' = 0.25(13W -15W^2 +7W^3 -W^4) per 32-row slab;
// h rows split across slab0 (rows 0-15) and slab4 (rows 16-31).
// Iteration 5's W-update is dead (tail re-expressed via W4) -> ktail2.
// ---------------------------------------------------------------------------
__device__ __forceinline__ int swidx(int row, int col){
  int cc = col>>3;
  int sl = (cc&24)|((cc&7)^((row>>1)&7));
  return row*256 + sl*8 + (col&7);
}
__device__ __forceinline__ int slot8(int ca, int row){
  return ((ca&24)|((ca&7)^((row>>1)&7)))<<3;
}

// stage 256x256 bf16 (131072B), 8 waves
__device__ __forceinline__ void stage256(const u16* __restrict__ g, u16* lds, int w, int l){
  const int drow = l>>5, dch = l&31;
  #pragma unroll
  for (int c=0;c<16;c++){
    int base = (c*8 + w)*2;
    int row = base + drow;
    int gch = (dch&24) | ((dch&7) ^ ((row>>1)&7));
    dma16(g + (long)row*256 + gch*8, &lds[base*256]);
  }
}
// stage 16x256 (8KB), 8 waves (2 rows/wave)
__device__ __forceinline__ void stage16(const u16* __restrict__ g, u16* lds, int w, int l){
  const int drow = l>>5, dch = l&31;
  int row = w*2 + drow;
  int gch = (dch&24) | ((dch&7) ^ ((row>>1)&7));
  dma16(g + (long)row*256 + gch*8, &lds[(w*2)*256]);
}

// preload this wave's 32 B-columns (rows wn0..+31 of bL) across K into regs
__device__ __forceinline__ void loadBf(const u16* bL, int w, int l, s16x8 (&bw)[2][8]){
  const int q=l>>4, ln=l&15, wn0=w*32;
  #pragma unroll
  for (int nt=0;nt<2;nt++)
    #pragma unroll
    for (int kq=0;kq<8;kq++){
      int n = wn0 + nt*16 + ln, ca = kq*4+q;
      bw[nt][kq] = *(const s16x8*)&bL[n*256 + slot8(ca, n)];
    }
}

// acc = A(rows arow0..+31 of aL) @ B(regs), K=256
__device__ __forceinline__ void multAr(const u16* aL, int arow0, const s16x8 (&bw)[2][8],
                                       int l, f32x4 (&acc)[2][2]){
  const int q=l>>4, ln=l&15;
  #pragma unroll
  for (int mt=0;mt<2;mt++)
    #pragma unroll
    for (int nt=0;nt<2;nt++){ acc[mt][nt][0]=0.f; acc[mt][nt][1]=0.f; acc[mt][nt][2]=0.f; acc[mt][nt][3]=0.f; }
  #pragma unroll
  for (int kq=0;kq<8;kq++){
    int ca = kq*4+q;
    s16x8 af[2];
    #pragma unroll
    for (int mt=0;mt<2;mt++){
      int r = arow0 + mt*16 + ln;
      af[mt] = *(const s16x8*)&aL[r*256 + slot8(ca, r)];
    }
    #pragma unroll
    for (int mt=0;mt<2;mt++)
      #pragma unroll
      for (int nt=0;nt<2;nt++)
        acc[mt][nt] = MFMA16(af[mt], bw[nt][kq], acc[mt][nt]);
  }
}

// hacc = H(16 rows of hL) @ B(regs)
__device__ __forceinline__ void multHr(const u16* hL, const s16x8 (&bw)[2][8],
                                       int l, f32x4 (&hacc)[2]){
  const int q=l>>4, ln=l&15;
  hacc[0][0]=0.f; hacc[0][1]=0.f; hacc[0][2]=0.f; hacc[0][3]=0.f;
  hacc[1][0]=0.f; hacc[1][1]=0.f; hacc[1][2]=0.f; hacc[1][3]=0.f;
  #pragma unroll
  for (int kq=0;kq<8;kq++){
    int ca = kq*4+q;
    s16x8 af = *(const s16x8*)&hL[ln*256 + slot8(ca, ln)];
    hacc[0] = MFMA16(af, bw[0][kq], hacc[0]);
    hacc[1] = MFMA16(af, bw[1][kq], hacc[1]);
  }
}

__device__ __forceinline__ void polyinit13(const u16* aL, int arow0, int w, int l, f32x4 (&poly)[2][2]){
  const int q=l>>4, ln=l&15, wn0=w*32;
  #pragma unroll
  for (int mt=0;mt<2;mt++)
  #pragma unroll
  for (int nt=0;nt<2;nt++)
  #pragma unroll
  for (int r=0;r<4;r++){
    int row = arow0 + mt*16 + q*4 + r;
    int col = wn0 + nt*16 + ln;
    poly[mt][nt][r] = 13.f*bf2f(aL[swidx(row,col)]);
  }
}
__device__ __forceinline__ void init13H(const u16* hL, int w, int l, f32x4 (&hpoly)[2]){
  const int q=l>>4, ln=l&15, wn0=w*32;
  #pragma unroll
  for (int nt=0;nt<2;nt++)
  #pragma unroll
  for (int r=0;r<4;r++)
    hpoly[nt][r] = 13.f*bf2f(hL[swidx(q*4+r, wn0+nt*16+ln)]);
}
__device__ __forceinline__ void polyaxpy(f32x4 (&poly)[2][2], const f32x4 (&acc)[2][2], float sc){
  #pragma unroll
  for (int mt=0;mt<2;mt++)
    #pragma unroll
    for (int nt=0;nt<2;nt++)
      #pragma unroll
      for (int r=0;r<4;r++) poly[mt][nt][r] += sc*acc[mt][nt][r];
}
__device__ __forceinline__ void axpyH(f32x4 (&hpoly)[2], const f32x4 (&hacc)[2], float sc){
  #pragma unroll
  for (int nt=0;nt<2;nt++)
    #pragma unroll
    for (int r=0;r<4;r++) hpoly[nt][r] += sc*hacc[nt][r];
}
__device__ __forceinline__ void zeroH(f32x4 (&p)[2]){
  p[0][0]=0.f; p[0][1]=0.f; p[0][2]=0.f; p[0][3]=0.f;
  p[1][0]=0.f; p[1][1]=0.f; p[1][2]=0.f; p[1][3]=0.f;
}
__device__ __forceinline__ void writeT(u16* Ts, const f32x4 (&acc)[2][2], int w, int l, float sc){
  const int q=l>>4, ln=l&15, wn0=w*32;
  #pragma unroll
  for (int mt=0;mt<2;mt++)
  #pragma unroll
  for (int nt=0;nt<2;nt++)
  #pragma unroll
  for (int r=0;r<4;r++){
    int row = mt*16 + q*4 + r;
    int col = wn0 + nt*16 + ln;
    Ts[swidx(row,col)] = f2bf(sc*acc[mt][nt][r]);
  }
}
__device__ __forceinline__ void writeH(u16* Hs, const f32x4 (&hacc)[2], int w, int l){
  const int q=l>>4, ln=l&15, wn0=w*32;
  #pragma unroll
  for (int nt=0;nt<2;nt++)
  #pragma unroll
  for (int r=0;r<4;r++)
    Hs[swidx(q*4+r, wn0+nt*16+ln)] = f2bf(hacc[nt][r]);
}
__device__ __forceinline__ void writeHsc(u16* Hs, const f32x4 (&v)[2], int w, int l, float sc){
  const int q=l>>4, ln=l&15, wn0=w*32;
  #pragma unroll
  for (int nt=0;nt<2;nt++)
  #pragma unroll
  for (int r=0;r<4;r++)
    Hs[swidx(q*4+r, wn0+nt*16+ln)] = f2bf(sc*v[nt][r]);
}
__device__ __forceinline__ void epi_poly(u16* __restrict__ out, int rowbase,
                                         const f32x4 (&poly)[2][2], int w, int l, float sc){
  const int q=l>>4, ln=l&15, wn0=w*32;
  #pragma unroll
  for (int mt=0;mt<2;mt++)
  #pragma unroll
  for (int nt=0;nt<2;nt++)
  #pragma unroll
  for (int r=0;r<4;r++){
    int row = rowbase + mt*16 + q*4 + r;
    int col = wn0 + nt*16 + ln;
    out[(long)row*256 + col] = f2bf(sc*poly[mt][nt][r]);
  }
}
__device__ __forceinline__ void epiH(u16* __restrict__ out, const f32x4 (&hpoly)[2],
                                     int w, int l, float sc){
  const int q=l>>4, ln=l&15, wn0=w*32;
  #pragma unroll
  for (int nt=0;nt<2;nt++)
  #pragma unroll
  for (int r=0;r<4;r++)
    out[(long)(q*4+r)*256 + wn0+nt*16+ln] = f2bf(sc*hpoly[nt][r]);
}

// legacy LDS-B mult (kw0 only: single phase, preload is neutral)
__device__ __forceinline__ void mult32(const u16* aL, int arow0, const u16* bL,
                                       int w, int l, f32x4 (&acc)[2][2]){
  const int q=l>>4, ln=l&15, wn0=w*32;
  #pragma unroll
  for (int mt=0;mt<2;mt++)
    #pragma unroll
    for (int nt=0;nt<2;nt++){ acc[mt][nt][0]=0.f; acc[mt][nt][1]=0.f; acc[mt][nt][2]=0.f; acc[mt][nt][3]=0.f; }
  #pragma unroll
  for (int kq=0;kq<8;kq++){
    int ca = kq*4+q;
    s16x8 af[2];
    #pragma unroll
    for (int mt=0;mt<2;mt++){
      int r = arow0 + mt*16 + ln;
      af[mt] = *(const s16x8*)&aL[r*256 + slot8(ca,r)];
    }
    #pragma unroll
    for (int nt=0;nt<2;nt++){
      int n = wn0 + nt*16 + ln;
      s16x8 bfr = *(const s16x8*)&bL[n*256 + slot8(ca,n)];
      acc[0][nt] = MFMA16(af[0], bfr, acc[0][nt]);
      acc[1][nt] = MFMA16(af[1], bfr, acc[1][nt]);
    }
  }
}

// kw0: W0 = s0*X@X^T slab; self-computed s0 from cs_p; slab0 also preps h0
__global__ __launch_bounds__(512)
void kw0(const float* __restrict__ cs_p, float* __restrict__ scal,
         const float* __restrict__ num_p, const float* __restrict__ den_p,
         const u16* __restrict__ X, u16* __restrict__ W0, u16* __restrict__ h0)
{
  __shared__ __align__(16) u16 Wf[65536];
  __shared__ __align__(16) u16 Ts[8192];
  const int tid=threadIdx.x, w=tid>>6, l=tid&63;
  const int bid=blockIdx.x, xcd=bid&7, j=bid>>3;
  const int batch = xcd*4 + (j>>3), slab = j&7;

  stage256(X + (long)batch*65536, Wf, w, l);   // dma in flight during reduce

  float* red = (float*)Ts;
  float mx = 0.f;
  for (int i=tid;i<8192;i+=512){
    float s = 0.f;
    #pragma unroll
    for (int c=0;c<8;c++) s += cs_p[(long)c*8192 + i];
    mx = fmaxf(mx, s);
  }
  red[tid] = mx; __syncthreads();
  for (int s=256;s>0;s>>=1){ if (tid<s) red[tid] = fmaxf(red[tid], red[tid+s]); __syncthreads(); }
  float s0 = 1.0f/red[0];
  if (bid==0 && tid==0) scal[0] = s0;

  f32x4 acc[2][2];
  mult32(Wf, slab*32, Wf, w, l, acc);
  {
    const int q=l>>4, ln=l&15, wn0=w*32;
    u16* ob = W0 + (long)batch*65536;
    #pragma unroll
    for (int mt=0;mt<2;mt++)
    #pragma unroll
    for (int nt=0;nt<2;nt++)
    #pragma unroll
    for (int r=0;r<4;r++){
      int row = slab*32 + mt*16 + q*4 + r;
      int col = wn0 + nt*16 + ln;
      ob[(long)row*256 + col] = f2bf(acc[mt][nt][r]*s0);
    }
  }

  if (slab==0){
    __syncthreads();
    float (*lt)[257] = (float(*)[257])Wf;
    for (int i=tid;i<8192;i+=512){
      int m = i>>5, d = i&31;
      float sn = 0.f, sd = 0.f;
      #pragma unroll
      for (int c=0;c<8;c++){
        sn += num_p[((long)(c*32+batch))*8192 + i];
        sd += den_p[(c*32+batch)*256 + m];
      }
      lt[d][m] = sn/sd;
    }
    __syncthreads();
    u16* o = h0 + (long)batch*8192;
    for (int j2=tid;j2<8192;j2+=512){
      int d = j2>>8, m = j2&255;
      o[j2] = f2bf(lt[d][m]);
    }
  }
}

// kiter: one Newton iteration. 256 blocks x 512 thr; slab0/slab4 advance h halves.
__global__ __launch_bounds__(512)
void kiter(const u16* __restrict__ Win, u16* __restrict__ Wout,
           const u16* __restrict__ hin, u16* __restrict__ hout)
{
  __shared__ __align__(16) u16 Wf[65536];
  __shared__ __align__(16) u16 Ts[8192];
  __shared__ __align__(16) u16 Hs[4096];
  const int tid=threadIdx.x, w=tid>>6, l=tid&63;
  const int bid=blockIdx.x, xcd=bid&7, j=bid>>3;
  const int batch = xcd*4 + (j>>3), slab = j&7;
  const bool hrole = (slab&3)==0;              // slabs 0 and 4
  const int hr0 = (slab>>2)*16;

  stage256(Win + (long)batch*65536, Wf, w, l);
  if (hrole) stage16(hin + (long)batch*8192 + hr0*256, Hs, w, l);
  __syncthreads();

  s16x8 bw[2][8];
  loadBf(Wf, w, l, bw);

  f32x4 acc[2][2], poly[2][2];
  f32x4 hacc[2], hpoly[2];

  polyinit13(Wf, slab*32, w, l, poly);
  multAr(Wf, slab*32, bw, l, acc);             // t1 = Wslab@W
  polyaxpy(poly, acc, -15.f);
  if (hrole){
    init13H(Hs, w, l, hpoly);
    multHr(Hs, bw, l, hacc);                   // h@W
    axpyH(hpoly, hacc, -15.f);
    __syncthreads();                           // Hs reads done before writeH
  }
  // (non-hrole: Ts has no prior readers -> no barrier needed; hrole is
  //  block-uniform so the conditional barrier is legal)
  writeT(Ts, acc, w, l, 1.f);
  if (hrole) writeH(Hs, hacc, w, l);
  __syncthreads();
  multAr(Ts, 0, bw, l, acc);                   // t2
  polyaxpy(poly, acc, 7.f);
  if (hrole){ multHr(Hs, bw, l, hacc); axpyH(hpoly, hacc, 7.f); }
  __syncthreads();
  writeT(Ts, acc, w, l, 1.f);
  if (hrole) writeH(Hs, hacc, w, l);
  __syncthreads();
  multAr(Ts, 0, bw, l, acc);                   // t3
  polyaxpy(poly, acc, -1.f);
  epi_poly(Wout + (long)batch*65536, slab*32, poly, w, l, 0.25f);
  if (hrole){
    multHr(Hs, bw, l, hacc);
    axpyH(hpoly, hacc, -1.f);
    epiH(hout + (long)batch*8192 + hr0*256, hpoly, w, l, 0.25f);
  }
}

// ---------------------------------------------------------------------------
// ktail2: fused {iteration 5 h-advance + tail} with W5 never materialized.
// ---------------------------------------------------------------------------
__global__ __launch_bounds__(512)
void ktail2(const u16* __restrict__ W4, const u16* __restrict__ h4,
            const u16* __restrict__ XT, const float* __restrict__ scal,
            u16* __restrict__ uT)
{
  __shared__ __align__(16) u16 Wf[65536];
  __shared__ __align__(16) u16 Ha[4096];
  __shared__ __align__(16) u16 Hb[4096];
  const int tid=threadIdx.x, w=tid>>6, l=tid&63;
  const int batch = blockIdx.x>>1, half = blockIdx.x&1;

  stage256(W4 + (long)batch*65536, Wf, w, l);
  stage16(h4 + (long)batch*8192 + half*4096, Ha, w, l);
  __syncthreads();

  s16x8 bw[2][8];
  loadBf(Wf, w, l, bw);
  __syncthreads();                              // all W4 reads from Wf done
  stage256(XT + (long)batch*65536, Wf, w, l);   // async; drained by later barriers

  f32x4 acc[2], poly[2], gpoly[2];

  // ---- h5 = 0.25(13h4 -15 h4W +7 h4W^2 - h4W^3) ----
  init13H(Ha, w, l, poly);
  multHr(Ha, bw, l, acc); axpyH(poly, acc, -15.f);
  writeH(Hb, acc, w, l); __syncthreads();
  multHr(Hb, bw, l, acc); axpyH(poly, acc, 7.f);
  writeH(Ha, acc, w, l); __syncthreads();
  multHr(Ha, bw, l, acc); axpyH(poly, acc, -1.f);
  zeroH(gpoly); axpyH(gpoly, poly, 3.25f);      // gpoly = 13*h5
  writeHsc(Hb, poly, w, l, 0.25f); __syncthreads();   // Hb = r(h5)

  // ---- a = (h5@W4)*Q(W4) ----
  multHr(Hb, bw, l, acc); zeroH(poly); axpyH(poly, acc, 13.f);
  writeH(Ha, acc, w, l); __syncthreads();
  multHr(Ha, bw, l, acc); axpyH(poly, acc, -15.f);
  writeH(Hb, acc, w, l); __syncthreads();
  multHr(Hb, bw, l, acc); axpyH(poly, acc, 7.f);
  writeH(Ha, acc, w, l); __syncthreads();
  multHr(Ha, bw, l, acc); axpyH(poly, acc, -1.f);
  axpyH(gpoly, poly, -3.75f);                   // gpoly += -15*a
  writeHsc(Hb, poly, w, l, 0.25f); __syncthreads();   // Hb = r(a)

  // ---- b = (a@W4)*Q(W4) ----
  multHr(Hb, bw, l, acc); zeroH(poly); axpyH(poly, acc, 13.f);
  writeH(Ha, acc, w, l); __syncthreads();
  multHr(Ha, bw, l, acc); axpyH(poly, acc, -15.f);
  writeH(Hb, acc, w, l); __syncthreads();
  multHr(Hb, bw, l, acc); axpyH(poly, acc, 7.f);
  writeH(Ha, acc, w, l); __syncthreads();
  multHr(Ha, bw, l, acc); axpyH(poly, acc, -1.f);
  axpyH(gpoly, poly, 1.75f);                    // gpoly += 7*b
  writeHsc(Hb, poly, w, l, 0.25f); __syncthreads();   // Hb = r(b)

  // ---- c = (b@W4)*Q(W4) ----
  multHr(Hb, bw, l, acc); zeroH(poly); axpyH(poly, acc, 13.f);
  writeH(Ha, acc, w, l); __syncthreads();
  multHr(Ha, bw, l, acc); axpyH(poly, acc, -15.f);
  writeH(Hb, acc, w, l); __syncthreads();
  multHr(Hb, bw, l, acc); axpyH(poly, acc, 7.f);
  writeH(Ha, acc, w, l); __syncthreads();
  multHr(Ha, bw, l, acc); axpyH(poly, acc, -1.f);
  axpyH(gpoly, poly, -0.25f);                   // gpoly += -c
  writeHsc(Hb, gpoly, w, l, 0.25f); __syncthreads();  // Hb = r(g1)

  // ---- u = s0 * g1 @ X  (B-frags from XT, now resident in Wf) ----
  loadBf(Wf, w, l, bw);
  multHr(Hb, bw, l, acc);
  epiH(uT + (long)batch*8192 + half*4096, acc, w, l, scal[0]);
}

// ---------------------------------------------------------------------------
// Merged attn2 + attn3v (independent; grid (16,32): x<8 attn2, x>=8 attn3v)
// ---------------------------------------------------------------------------
__global__ __launch_bounds__(256)
void kattn23(const u16* __restrict__ ql, const u16* __restrict__ kl,
             u16* __restrict__ X, u16* __restrict__ XT, float* __restrict__ cs_p,
             const u16* __restrict__ kk, const u16* __restrict__ vv,
             float* __restrict__ num_p, float* __restrict__ den_p)
{
  __shared__ __align__(16) u16 Pbuf[4][64][40];
  __shared__ __align__(16) u16 vT[32][40];
  __shared__ float qrow[32][33];
  __shared__ float psum[32][4];
  __shared__ float rsum[32];
  int bh = blockIdx.y;
  int tid = threadIdx.x, w = tid>>6, l = tid&63, q = l>>4, ln = l&15;

  if (blockIdx.x < 8){
    int r0 = blockIdx.x*32;
    int c = tid;
    #pragma unroll
    for (int i=0;i<4;i++){
      int e = c*4+i; int rr = e>>5, dd = e&31;
      qrow[rr][dd] = bf2f(ql[((long)bh*256 + r0+rr)*32 + dd]);
    }
    float kc[32];
    {
      const u16* kp = kl + ((long)bh*256 + c)*32;
      #pragma unroll
      for (int d=0;d<32;d++) kc[d] = bf2f(kp[d]);
    }
    __syncthreads();
    float er[32]; float colacc = 0.f;
    for (int r=0;r<32;r++){
      float s = 0.f;
      #pragma unroll
      for (int d=0;d<32;d++) s += qrow[r][d]*kc[d];
      float e = __expf(s);
      er[r] = e;
      float wsum = e;
      #pragma unroll
      for (int m=1;m<64;m<<=1) wsum += __shfl_xor(wsum, m);
      if (l==0) psum[r][w] = wsum;
    }
    __syncthreads();
    if (c<32) rsum[c] = psum[c][0]+psum[c][1]+psum[c][2]+psum[c][3];
    __syncthreads();
    for (int r=0;r<32;r++){
      float x = er[r]/rsum[r];
      u16 xb = f2bf(x);
      X [((long)bh*256 + r0+r)*256 + c] = xb;
      XT[((long)bh*256 + c)*256 + r0+r] = xb;
      colacc += x;
    }
    cs_p[(long)blockIdx.x*8192 + bh*256 + c] = colacc;
    return;
  }

  int chunk = blockIdx.x - 8;
  f32x4 z4; z4[0]=0.f; z4[1]=0.f; z4[2]=0.f; z4[3]=0.f;
  f32x4 acc[4][2]; f32x4 dacc[4];
  #pragma unroll
  for (int mt=0;mt<4;mt++){ dacc[mt]=z4; acc[mt][0]=z4; acc[mt][1]=z4; }
  const u16* qlb = ql + (long)bh*8192;
  const u16* kb  = kk + (long)bh*131072;
  const u16* vb  = vv + (long)bh*131072;
  int vn = tid>>3, vd = (tid&7)*4;
  for (int s=0;s<16;s++){
    int n0 = chunk*512 + s*32;
    ushort4 vx = *(const ushort4*)(vb + (long)(n0+vn)*32 + vd);
    vT[vd+0][vn]=vx.x; vT[vd+1][vn]=vx.y; vT[vd+2][vn]=vx.z; vT[vd+3][vn]=vx.w;
    __syncthreads();
    s16x8 bk[2];
    #pragma unroll
    for (int nt=0;nt<2;nt++) bk[nt] = *(const s16x8*)(kb + (long)(n0 + nt*16 + ln)*32 + q*8);
    #pragma unroll
    for (int mt=0;mt<4;mt++){
      s16x8 aq = *(const s16x8*)(qlb + (long)(w*64 + mt*16 + ln)*32 + q*8);
      #pragma unroll
      for (int nt=0;nt<2;nt++){
        f32x4 sf = MFMA16(aq, bk[nt], z4);
        f32x4 ef;
        #pragma unroll
        for (int r=0;r<4;r++) ef[r] = __expf(sf[r]);
        dacc[mt] += ef;
        #pragma unroll
        for (int r=0;r<4;r++) Pbuf[w][mt*16 + q*4 + r][nt*16 + ln] = f2bf(ef[r]);
      }
    }
    #pragma unroll
    for (int mt=0;mt<4;mt++){
      s16x8 ap = *(const s16x8*)&Pbuf[w][mt*16 + ln][q*8];
      #pragma unroll
      for (int nt=0;nt<2;nt++){
        s16x8 bv = *(const s16x8*)&vT[nt*16 + ln][q*8];
        acc[mt][nt] = MFMA16(ap, bv, acc[mt][nt]);
      }
    }
    __syncthreads();
  }
  #pragma unroll
  for (int mt=0;mt<4;mt++)
    #pragma unroll
    for (int r=0;r<4;r++){
      float x = dacc[mt][r];
      x += __shfl_xor(x,1); x += __shfl_xor(x,2); x += __shfl_xor(x,4); x += __shfl_xor(x,8);
      dacc[mt][r] = x;
    }
  long pbase = (long)(chunk*32 + bh);
  #pragma unroll
  for (int mt=0;mt<4;mt++)
    #pragma unroll
    for (int nt=0;nt<2;nt++)
      #pragma unroll
      for (int r=0;r<4;r++){
        int mg = w*64 + mt*16 + q*4 + r;
        num_p[pbase*8192 + (long)mg*32 + nt*16 + ln] = acc[mt][nt][r];
      }
  if (ln==0){
    #pragma unroll
    for (int mt=0;mt<4;mt++)
      #pragma unroll
      for (int r=0;r<4;r++)
        den_p[pbase*256 + w*64 + mt*16 + q*4 + r] = dacc[mt][r];
  }
}

// ---------------------------------------------------------------------------
// attn1 fused + depthwise residual conv
// ---------------------------------------------------------------------------
__global__ __launch_bounds__(256)
void kattn1u(const u16* __restrict__ qq, const u16* __restrict__ kl, const u16* __restrict__ uT,
             const u16* __restrict__ vv, const float* __restrict__ rw,
             u16* __restrict__ aoutb)
{
  int nch = blockIdx.x, bh = blockIdx.y;
  int b = bh>>3, h = bh&7;
  int tid = threadIdx.x, w = tid>>6, l = tid&63, q = l>>4, ln = l&15;
  __shared__ __align__(16) u16 Pbuf[4][32][40];
  __shared__ __align__(16) u16 vtile[160][36];
  int r0g = nch*128;
  const u16* vb = vv + (long)bh*131072;
  #pragma unroll
  for (int it=0; it<5; it++){
    int slot = tid + it*256;
    int rr = slot>>3, c = (slot&7)*4;
    int s = r0g - 16 + rr;
    ushort4 val; val.x=0; val.y=0; val.z=0; val.w=0;
    if (s>=0 && s<4096) val = *(const ushort4*)(vb + (long)s*32 + c);
    *(ushort4*)&vtile[rr][c] = val;
  }
  __syncthreads();

  f32x4 z4; z4[0]=0.f; z4[1]=0.f; z4[2]=0.f; z4[3]=0.f;
  f32x4 acc[2][2]; f32x4 dacc[2];
  #pragma unroll
  for (int mt=0;mt<2;mt++){ dacc[mt]=z4; acc[mt][0]=z4; acc[mt][1]=z4; }
  const u16* qb  = qq + (long)bh*131072;
  const u16* klb = kl + (long)bh*8192;
  const u16* ub  = uT + (long)bh*8192;
  int r0 = r0g + w*32;
  for (int s=0;s<8;s++){
    s16x8 bk[2];
    #pragma unroll
    for (int nt=0;nt<2;nt++) bk[nt] = *(const s16x8*)(klb + (long)(s*32 + nt*16 + ln)*32 + q*8);
    #pragma unroll
    for (int mt=0;mt<2;mt++){
      s16x8 aq = *(const s16x8*)(qb + (long)(r0 + mt*16 + ln)*32 + q*8);
      #pragma unroll
      for (int nt=0;nt<2;nt++){
        f32x4 sf = MFMA16(aq, bk[nt], z4);
        f32x4 ef;
        #pragma unroll
        for (int r=0;r<4;r++) ef[r] = __expf(sf[r]);
        dacc[mt] += ef;
        #pragma unroll
        for (int r=0;r<4;r++) Pbuf[w][mt*16 + q*4 + r][nt*16 + ln] = f2bf(ef[r]);
      }
    }
    #pragma unroll
    for (int mt=0;mt<2;mt++){
      s16x8 ap = *(const s16x8*)&Pbuf[w][mt*16 + ln][q*8];
      #pragma unroll
      for (int nt=0;nt<2;nt++){
        s16x8 bu = *(const s16x8*)(ub + (long)(nt*16 + ln)*256 + s*32 + q*8);
        acc[mt][nt] = MFMA16(ap, bu, acc[mt][nt]);
      }
    }
  }
  #pragma unroll
  for (int mt=0;mt<2;mt++)
    #pragma unroll
    for (int r=0;r<4;r++){
      float x = dacc[mt][r];
      x += __shfl_xor(x,1); x += __shfl_xor(x,2); x += __shfl_xor(x,4); x += __shfl_xor(x,8);
      dacc[mt][r] = x;
    }

  const float* wp = rw + h*33;
  float w_[33];
  #pragma unroll
  for (int j=0;j<33;j++) w_[j] = wp[j];

  #pragma unroll
  for (int mt=0;mt<2;mt++){
    int nl = w*32 + mt*16 + q*4;
    #pragma unroll
    for (int nt=0;nt<2;nt++){
      int d = nt*16 + ln;
      float vvv[36];
      #pragma unroll
      for (int j=0;j<36;j++) vvv[j] = bf2f(vtile[nl + j][d]);
      #pragma unroll
      for (int r=0;r<4;r++){
        float cv = 0.f;
        #pragma unroll
        for (int j=0;j<33;j++) cv += w_[j]*vvv[r+j];
        int n = r0 + mt*16 + q*4 + r;
        long oidx = ((long)b*4096 + n)*256 + h*32 + d;
        aoutb[oidx] = f2bf(acc[mt][nt][r]/dacc[mt][r] + cv);
      }
    }
  }
}

// ---------------------------------------------------------------------------
// Merged: LN(x) (blocks 0..4095) + weight transpose/cast (blocks 4096..5119)
// ---------------------------------------------------------------------------
__global__ __launch_bounds__(256)
void kcvtln(const float* __restrict__ xin, const float* __restrict__ lg, const float* __restrict__ lb,
            u16* __restrict__ xn,
            const float* __restrict__ wqkv, const float* __restrict__ wout,
            const float* __restrict__ w1, const float* __restrict__ w2,
            u16* __restrict__ wqkvT, u16* __restrict__ woutT,
            u16* __restrict__ w1T, u16* __restrict__ w2T)
{
  __shared__ float t[32][33];
  int z = blockIdx.x;
  if (z < 4096){
    int w = threadIdx.x>>6, l = threadIdx.x&63;
    long row = (long)z*4 + w;
    float4 v = ((const float4*)(xin + row*256))[l];
    float s = v.x+v.y+v.z+v.w;
    #pragma unroll
    for (int m=1;m<64;m<<=1) s += __shfl_xor(s, m);
    float mu = s*(1.0f/256.0f);
    float dx=v.x-mu, dy=v.y-mu, dz=v.z-mu, dw=v.w-mu;
    float s2 = dx*dx+dy*dy+dz*dz+dw*dw;
    #pragma unroll
    for (int m=1;m<64;m<<=1) s2 += __shfl_xor(s2, m);
    float rs = rsqrtf(s2*(1.0f/256.0f) + 1e-5f);
    float4 gg = ((const float4*)lg)[l];
    float4 bb = ((const float4*)lb)[l];
    ushort4 o;
    o.x = f2bf(dx*rs*gg.x + bb.x);
    o.y = f2bf(dy*rs*gg.y + bb.y);
    o.z = f2bf(dz*rs*gg.z + bb.z);
    o.w = f2bf(dw*rs*gg.w + bb.w);
    *(ushort4*)(xn + row*256 + l*4) = o;
    return;
  }
  z -= 4096;
  const float* src; u16* dst; int K, Nn, bx, by;
  if (z < 384){      int i=z/192, r=z%192; src=wqkv+(long)i*196608; dst=wqkvT+(long)i*196608; K=256; Nn=768; bx=r%24; by=r/24; }
  else if (z < 512){ int zz=z-384; int i=zz/64, r=zz%64; src=wout+(long)i*65536; dst=woutT+(long)i*65536; K=256; Nn=256; bx=r%8; by=r/8; }
  else if (z < 768){ int zz=z-512; int i=zz/128, r=zz%128; src=w1+(long)i*131072; dst=w1T+(long)i*131072; K=256; Nn=512; bx=r%16; by=r/16; }
  else {             int zz=z-768; int i=zz/128, r=zz%128; src=w2+(long)i*131072; dst=w2T+(long)i*131072; K=512; Nn=256; bx=r%8; by=r/8; }
  int n0 = bx*32, k0 = by*32;
  int tx = threadIdx.x&31, ty = threadIdx.x>>5;
  #pragma unroll
  for (int i=0;i<4;i++) t[ty+i*8][tx] = src[(long)(k0+ty+i*8)*Nn + n0+tx];
  __syncthreads();
  #pragma unroll
  for (int i=0;i<4;i++) dst[(long)(n0+ty+i*8)*K + k0+tx] = f2bf(t[tx][ty+i*8]);
}

// ---------------------------------------------------------------------------
extern "C" void kernel_launch(void* const* d_in, const int* in_sizes, int n_in,
                              void* d_out, int out_size, void* d_ws, size_t ws_size,
                              hipStream_t stream)
{
  const float* x    = (const float*)d_in[0];
  const float* ln1g = (const float*)d_in[1];
  const float* ln1b = (const float*)d_in[2];
  const float* wqkv = (const float*)d_in[3];
  const float* wout = (const float*)d_in[4];
  const float* bout = (const float*)d_in[5];
  const float* resw = (const float*)d_in[6];
  const float* ln2g = (const float*)d_in[7];
  const float* ln2b = (const float*)d_in[8];
  const float* w1   = (const float*)d_in[9];
  const float* b1   = (const float*)d_in[10];
  const float* w2   = (const float*)d_in[11];
  const float* b2   = (const float*)d_in[12];
  float* y = (float*)d_out;
  char* ws = (char*)d_ws;

  u16* xn    = (u16*)(ws + 0);
  u16* qb    = (u16*)(ws + 8388608);
  u16* kb    = (u16*)(ws + 16777216);
  u16* vb    = (u16*)(ws + 25165824);
  u16* ql    = (u16*)(ws + 33554432);
  u16* kl    = (u16*)(ws + 34078720);
  u16* X     = (u16*)(ws + 34603008);
  u16* XT    = (u16*)(ws + 38797312);     // X^T (B-operand of final U GEMM)
  u16* h0b   = (u16*)(ws + 42991616);     // h0 [32][32][256] bf16 (512 KB)
  // pinv work region
  u16* WA    = (u16*)(ws + 51380224);
  u16* WB    = (u16*)(ws + 55574528);
  u16* hA    = (u16*)(ws + 68157440);     // thin h buffers [32][32][256]
  u16* hB    = (u16*)(ws + 72351744);
  float* num_p = (float*)(ws + 76546048);  // 8 MB
  float* den_p = (float*)(ws + 84934656);
  float* cs_p  = (float*)(ws + 85196800);
  float* scal  = (float*)(ws + 85458944);
  u16* uT    = (u16*)(ws + 85459200);
  u16* aoutb = (u16*)(ws + 85983488);
  u16* wqkvT = (u16*)(ws + 94372096);
  u16* woutT = (u16*)(ws + 95158528);
  u16* w1T   = (u16*)(ws + 95420672);
  u16* w2T   = (u16*)(ws + 95944960);
  u16* hdn   = (u16*)(ws + 51380224);      // overlays WA/WB (dead by FFN)

  (void)in_sizes; (void)n_in; (void)out_size; (void)ws_size;

  // LN(x) + weight cvt in one launch
  kcvtln<<<5120,256,0,stream>>>(x, ln1g, ln1b, xn,
      wqkv, wout, w1, w2, wqkvT, woutT, w1T, w2T);

  for (int i=0;i<2;i++){
    // xn: i==0 from kcvtln; i==1 from previous FFN2's fused LN epilogue
    kgemm2<EPI_QKV><<<dim3(128,6),256,0,stream>>>(xn, wqkvT + (long)i*196608, 256, 256, 256,
        nullptr, nullptr, 0, qb,kb,vb, ql,kl);
    kattn23<<<dim3(16,32),256,0,stream>>>(ql, kl, X, XT, cs_p, kb, vb, num_p, den_p);

    // ---- pinv: kw0 (scal + W0 + h0) -> 4x kiter -> ktail2 (iter5-h + tail) ----
    kw0<<<256,512,0,stream>>>(cs_p, scal, num_p, den_p, X, WA, h0b);
    u16 *Wi = WA, *Wo = WB, *hi = h0b, *ho = hA;
    for (int it=0; it<4; it++){
      kiter<<<256,512,0,stream>>>(Wi, Wo, hi, ho);
      u16* t = Wi; Wi = Wo; Wo = t;
      hi = ho; ho = (ho == hA) ? hB : hA;
    }
    ktail2<<<64,512,0,stream>>>(Wi, hi, XT, scal, uT);

    kattn1u<<<dim3(32,32),256,0,stream>>>(qb, kl, uT, vb, resw + i*264, aoutb);
    // wout GEMM + residual + LN2 fused -> y (f32) + xn (bf16 for FFN1)
    kgemmLN<1><<<256,256,0,stream>>>(aoutb, woutT + (long)i*65536, 256,
        bout + i*256, i==0 ? x : y, y, ln2g + i*256, ln2b + i*256, xn);
    kgemm2<EPI_BIAS_GELU><<<dim3(128,4),256,0,stream>>>(xn, w1T + (long)i*131072, 256, 256, 256,
        b1 + i*512, hdn, 512, nullptr,nullptr,nullptr, nullptr,nullptr);
    // FFN2 GEMM + residual (+ LN1(next) only when consumed)
    if (i==0)
      kgemmLN<1><<<256,256,0,stream>>>(hdn, w2T + (long)i*131072, 512,
          b2 + i*256, y, y, ln1g + 256, ln1b + 256, xn);
    else
      kgemmLN<0><<<256,256,0,stream>>>(hdn, w2T + (long)i*131072, 512,
          b2 + i*256, y, y, ln1g + 256, ln1b + 256, xn);
  }
}